// Round 9
// baseline (1477.058 us; speedup 1.0000x reference)
//
#include <hip/hip_runtime.h>
#include <cstdint>
#include <cstddef>

static constexpr int Bb = 8;
static constexpr int Nn = 2048;
static constexpr int Kn = 20;
static constexpr float EPSV = 1e-5f;

// ---------------------------------------------------------------- utilities

// blocks 0..63: xx[i] = ||x_i||^2 ; blocks 64..191: zero 32K floats of zp
__global__ void sqnorm_zero_kernel(const float* __restrict__ x, float* __restrict__ xx, int C,
                                   float* __restrict__ zp) {
    int blk = blockIdx.x;
    if (blk < 64) {
        int i = blk * 256 + threadIdx.x;
        const float* xr = x + (size_t)i * C;
        float s = 0.f;
        for (int c = 0; c < C; ++c) { float v = xr[c]; s += v * v; }
        xx[i] = s;
    } else {
        zp[(blk - 64) * 256 + threadIdx.x] = 0.f;
    }
}

// all weight transposes in one launch: out[c*R + r] = in[r*Cc + c]
struct TransJobs {
    const float* in[6];
    float* out[6];
    int R[6];
    int Cc[6];
};

__global__ void transpose_all_kernel(TransJobs tj) {
    int m = blockIdx.y;
    int i = blockIdx.x * 256 + threadIdx.x;
    int total = tj.R[m] * tj.Cc[m];
    if (i < total) {
        int r = i / tj.Cc[m], c = i % tj.Cc[m];
        tj.out[m][(size_t)c * tj.R[m] + r] = tj.in[m][i];
    }
}

// ------------------------------------------------ pairwise sq-dist (tiled gram)
// SYMMETRIC: only the 136 upper-triangular 128x128 block-pairs are computed;
// off-diagonal blocks emit the mirrored tile through a 16-row LDS transpose
// buffer (bitwise-identical values).
// DOUBLE-BUFFERED LDS staging (R8: VALUBusy 38%, occ 21% -> latency-bound on
// the per-tile staging barrier): tile k+1's global loads are issued before
// FMA(k), regs->LDS lands in the other buffer after FMA, ONE barrier/tile.
// launch_bounds(256,2): 256-reg budget/wave — acc[64] in AGPRs + 16 prefetch
// VGPRs, zero spill. (256,3)/(256,4) spill the accumulator to scratch
// (R5: 18x traffic; R6: +270 MB writes). DO NOT raise min-waves above 2.

template<int C>
__global__ __launch_bounds__(256, 2)
void gram_dist_kernel(const float* __restrict__ x, const float* __restrict__ xx,
                      float* __restrict__ dist, int b0, size_t dstride) {
    constexpr int CT = (C < 16) ? C : 16;
    constexpr int NT = (C + CT - 1) / CT;       // k-tiles
    constexpr int NB = (NT > 1) ? 2 : 1;        // LDS buffers
    const int b = b0 + blockIdx.z;
    // decode upper-tri pair index -> (rblk, cblk), rblk <= cblk, 16x16 tiles
    int p = blockIdx.x, rblk = 0;
    while (p >= 16 - rblk) { p -= 16 - rblk; ++rblk; }
    const int cblk = rblk + p;
    const int i0 = rblk * 128, j0 = cblk * 128;
    const int tid = threadIdx.x;
    const int tx = tid & 15, ty = tid >> 4;
    __shared__ float As[NB][CT][136];
    __shared__ float BsA[NB][CT][68];
    __shared__ float BsB[NB][CT][68];
    __shared__ float T[16][132];
    float acc[8][8] = {};
    const float* xb = x + (size_t)b * Nn * C;

    const int si = tid & 127;         // staging row
    const int half = tid >> 7;        // 0..1
    const int bidx = ((si >> 3) << 2) | (si & 3);
    const bool useB = (si & 4) != 0;

    if constexpr (CT == 16) {
        const float* ra = xb + (size_t)(i0 + si) * C + half * 8;
        const float* rb = xb + (size_t)(j0 + si) * C + half * 8;
        const int cb = half * 8;

        auto stage = [&](int buf, const float4& a0, const float4& a1,
                         const float4& q0, const float4& q1) {
            As[buf][cb + 0][si] = a0.x; As[buf][cb + 1][si] = a0.y;
            As[buf][cb + 2][si] = a0.z; As[buf][cb + 3][si] = a0.w;
            As[buf][cb + 4][si] = a1.x; As[buf][cb + 5][si] = a1.y;
            As[buf][cb + 6][si] = a1.z; As[buf][cb + 7][si] = a1.w;
            float* bb = (useB ? &BsB[buf][0][0] : &BsA[buf][0][0]) + bidx;
            bb[(cb + 0) * 68] = q0.x; bb[(cb + 1) * 68] = q0.y;
            bb[(cb + 2) * 68] = q0.z; bb[(cb + 3) * 68] = q0.w;
            bb[(cb + 4) * 68] = q1.x; bb[(cb + 5) * 68] = q1.y;
            bb[(cb + 6) * 68] = q1.z; bb[(cb + 7) * 68] = q1.w;
        };

        float4 pa0 = *(const float4*)ra;
        float4 pa1 = *(const float4*)(ra + 4);
        float4 pb0 = *(const float4*)rb;
        float4 pb1 = *(const float4*)(rb + 4);
        stage(0, pa0, pa1, pb0, pb1);
        __syncthreads();
        if constexpr (NT > 1) {
            pa0 = *(const float4*)(ra + 16);
            pa1 = *(const float4*)(ra + 20);
            pb0 = *(const float4*)(rb + 16);
            pb1 = *(const float4*)(rb + 20);
        }

        for (int k = 0; k < NT; ++k) {
            const int buf = k & (NB - 1);
#pragma unroll
            for (int cc = 0; cc < CT; ++cc) {
                float a[8], bv[8];
                *(float4*)&a[0]  = *(const float4*)&As[buf][cc][ty * 8];
                *(float4*)&a[4]  = *(const float4*)&As[buf][cc][ty * 8 + 4];
                *(float4*)&bv[0] = *(const float4*)&BsA[buf][cc][tx * 4];
                *(float4*)&bv[4] = *(const float4*)&BsB[buf][cc][tx * 4];
#pragma unroll
                for (int u = 0; u < 8; ++u)
#pragma unroll
                    for (int v = 0; v < 8; ++v)
                        acc[u][v] = fmaf(a[u], bv[v], acc[u][v]);
            }
            if (k + 1 < NT) {
                stage((k + 1) & (NB - 1), pa0, pa1, pb0, pb1);   // vmcnt waits here, after FMA
                if (k + 2 < NT) {
                    const int off = (k + 2) * 16;
                    pa0 = *(const float4*)(ra + off);
                    pa1 = *(const float4*)(ra + off + 4);
                    pb0 = *(const float4*)(rb + off);
                    pb1 = *(const float4*)(rb + off + 4);
                }
            }
            __syncthreads();
        }
    } else {
        // C < 16: single tile, scalar staging
        if (half == 0) {
            const float* r0 = xb + (size_t)(i0 + si) * C;
#pragma unroll
            for (int c = 0; c < CT; ++c) As[0][c][si] = r0[c];
        } else {
            const float* r1 = xb + (size_t)(j0 + si) * C;
            float* bb = (useB ? &BsB[0][0][0] : &BsA[0][0][0]) + bidx;
#pragma unroll
            for (int c = 0; c < CT; ++c) bb[c * 68] = r1[c];
        }
        __syncthreads();
#pragma unroll
        for (int cc = 0; cc < CT; ++cc) {
            float a[8], bv[8];
            *(float4*)&a[0]  = *(const float4*)&As[0][cc][ty * 8];
            *(float4*)&a[4]  = *(const float4*)&As[0][cc][ty * 8 + 4];
            *(float4*)&bv[0] = *(const float4*)&BsA[0][cc][tx * 4];
            *(float4*)&bv[4] = *(const float4*)&BsB[0][cc][tx * 4];
#pragma unroll
            for (int u = 0; u < 8; ++u)
#pragma unroll
                for (int v = 0; v < 8; ++v)
                    acc[u][v] = fmaf(a[u], bv[v], acc[u][v]);
        }
        __syncthreads();
    }

    const float* xxb = xx + (size_t)b * Nn;
    float xi[8], xj[8];
#pragma unroll
    for (int u = 0; u < 8; ++u) xi[u] = xxb[i0 + ty * 8 + u];
#pragma unroll
    for (int v = 0; v < 8; ++v) xj[v] = xxb[j0 + tx * 8 + v];
    float* db = dist + (size_t)blockIdx.z * dstride;
#pragma unroll
    for (int u = 0; u < 8; ++u) {
        float* row = db + (size_t)(i0 + ty * 8 + u) * Nn + (j0 + tx * 8);
        float4 o0, o1;
        o0.x = xi[u] + xj[0] - 2.f * acc[u][0];
        o0.y = xi[u] + xj[1] - 2.f * acc[u][1];
        o0.z = xi[u] + xj[2] - 2.f * acc[u][2];
        o0.w = xi[u] + xj[3] - 2.f * acc[u][3];
        o1.x = xi[u] + xj[4] - 2.f * acc[u][4];
        o1.y = xi[u] + xj[5] - 2.f * acc[u][5];
        o1.z = xi[u] + xj[6] - 2.f * acc[u][6];
        o1.w = xi[u] + xj[7] - 2.f * acc[u][7];
        *(float4*)row = o0;
        *(float4*)(row + 4) = o1;
    }

    if (cblk > rblk) {
        // mirror tile (j0.., i0..): value(row=j0+tx*8+v, col=i0+ty*8+u)
        //   = xj[v] + xi[u] - 2*acc[u][v]  (bitwise equal to main tile)
        const int rr = tid >> 4;            // 0..15 row within 16-row chunk
        const int cc0 = (tid & 15) * 8;     // col base
#pragma unroll 1
        for (int m = 0; m < 8; ++m) {
            if ((tx >> 1) == m) {
                const int lr = (tx & 1) * 8;
#pragma unroll
                for (int v = 0; v < 8; ++v)
#pragma unroll
                    for (int u = 0; u < 8; ++u)
                        T[lr + v][ty * 8 + u] = xj[v] + xi[u] - 2.f * acc[u][v];
            }
            __syncthreads();
            float4 w0 = *(const float4*)&T[rr][cc0];
            float4 w1 = *(const float4*)&T[rr][cc0 + 4];
            float* orow = db + (size_t)(j0 + m * 16 + rr) * Nn + (i0 + cc0);
            *(float4*)orow = w0;
            *(float4*)(orow + 4) = w1;
            __syncthreads();
        }
    }
}

// ------------------------------------------------------- top-k (k=20 smallest)

__device__ __forceinline__ bool lex_less(float v1, int j1, float v2, int j2) {
    return v1 < v2 || (v1 == v2 && j1 < j2);
}

__device__ __forceinline__ void top4_build(const float4* __restrict__ dr4, int lane,
                                           unsigned xmask,
                                           float& tv0, int& tj0, int& ts0,
                                           float& tv1, int& tj1, int& ts1,
                                           float& tv2, int& tj2, int& ts2,
                                           float& tv3, int& tj3, int& ts3) {
    tv0 = tv1 = tv2 = tv3 = 3e38f;
    tj0 = tj1 = tj2 = tj3 = 1 << 30;
    ts0 = ts1 = ts2 = ts3 = 0;
#pragma unroll
    for (int q = 0; q < 8; ++q) {
        float4 f = dr4[q * 64 + lane];
        float vv[4] = {f.x, f.y, f.z, f.w};
#pragma unroll
        for (int c = 0; c < 4; ++c) {
            int s = q * 4 + c;
            if ((xmask >> s) & 1u) continue;
            int j = (q * 64 + lane) * 4 + c;
            float v = vv[c];
            if (lex_less(v, j, tv3, tj3)) {
                tv3 = v; tj3 = j; ts3 = s;
                if (lex_less(tv3, tj3, tv2, tj2)) {
                    float fv = tv2; int fj = tj2, fs = ts2;
                    tv2 = tv3; tj2 = tj3; ts2 = ts3; tv3 = fv; tj3 = fj; ts3 = fs;
                }
                if (lex_less(tv2, tj2, tv1, tj1)) {
                    float fv = tv1; int fj = tj1, fs = ts1;
                    tv1 = tv2; tj1 = tj2; ts1 = ts2; tv2 = fv; tj2 = fj; ts2 = fs;
                }
                if (lex_less(tv1, tj1, tv0, tj0)) {
                    float fv = tv0; int fj = tj0, fs = ts0;
                    tv0 = tv1; tj0 = tj1; ts0 = ts1; tv1 = fv; tj1 = fj; ts1 = fs;
                }
            }
        }
    }
}

__global__ void topk_kernel(const float* __restrict__ dist, int* __restrict__ idxo,
                            int b0, size_t dstride, int rows_per_batch_only) {
    const int w = threadIdx.x >> 6;
    const int lane = threadIdx.x & 63;
    const int lin = blockIdx.x * 4 + w;
    int bz, i;
    if (rows_per_batch_only) { bz = 0; i = lin; }
    else { bz = lin >> 11; i = lin & (Nn - 1); }
    const int b = b0 + bz;
    const float4* dr4 = (const float4*)(dist + (size_t)bz * dstride + (size_t)i * Nn);

    float tv0, tv1, tv2, tv3;
    int tj0, tj1, tj2, tj3, ts0, ts1, ts2, ts3;
    unsigned xmask = 0;
    top4_build(dr4, lane, 0u, tv0, tj0, ts0, tv1, tj1, ts1, tv2, tj2, ts2, tv3, tj3, ts3);
    int cnt = 0;

    int* orow = idxo + ((size_t)b * Nn + i) * Kn;
    for (int t = 0; t < Kn; ++t) {
        float bv = tv0; int bj = tj0;
#pragma unroll
        for (int off = 1; off < 64; off <<= 1) {
            float ov = __shfl_xor(bv, off);
            int oj = __shfl_xor(bj, off);
            if (lex_less(ov, oj, bv, bj)) { bv = ov; bj = oj; }
        }
        if (lane == 0) orow[t] = bj;
        if (tj0 == bj) {
            xmask |= 1u << ts0;
            tv0 = tv1; tj0 = tj1; ts0 = ts1;
            tv1 = tv2; tj1 = tj2; ts1 = ts2;
            tv2 = tv3; tj2 = tj3; ts2 = ts3;
            tv3 = 3e38f; tj3 = 1 << 30; ts3 = 0;
            if (++cnt == 4) {
                top4_build(dr4, lane, xmask, tv0, tj0, ts0, tv1, tj1, ts1,
                           tv2, tj2, ts2, tv3, tj3, ts3);
                cnt = 0;
            }
        }
    }
}

// ------------------------------------- per-point projections Z1=X Wl^T, Z2=X Wr^T

template<int C, int O>
__global__ void z_kernel(const float* __restrict__ x, const float* __restrict__ wt,
                         float* __restrict__ z1, float* __restrict__ z2) {
    constexpr int TP = 16;
    constexpr int G = 256 / O;
    constexpr int PP = TP / G;
    const int p0 = blockIdx.x * TP;
    const int tid = threadIdx.x;
    const int oo = tid % O;
    const int g = tid / O;
    __shared__ float xs[TP][(C < 4) ? 4 : C];
    for (int e = tid; e < TP * C; e += 256) {
        int p = e / C, c = e % C;
        xs[p][c] = x[(size_t)(p0 + p) * C + c];
    }
    __syncthreads();
    float a1[PP], a2[PP];
#pragma unroll
    for (int p = 0; p < PP; ++p) { a1[p] = 0.f; a2[p] = 0.f; }
    if constexpr (C % 4 == 0) {
        for (int c = 0; c < C; c += 4) {
            float w1[4], w2[4];
#pragma unroll
            for (int q = 0; q < 4; ++q) {
                w1[q] = wt[(size_t)(c + q) * O + oo];
                w2[q] = wt[(size_t)(C + c + q) * O + oo];
            }
#pragma unroll
            for (int p = 0; p < PP; ++p) {
                const float4 xv = *(const float4*)(&xs[g * PP + p][c]);
                a1[p] = fmaf(xv.w, w1[3], fmaf(xv.z, w1[2], fmaf(xv.y, w1[1], fmaf(xv.x, w1[0], a1[p]))));
                a2[p] = fmaf(xv.w, w2[3], fmaf(xv.z, w2[2], fmaf(xv.y, w2[1], fmaf(xv.x, w2[0], a2[p]))));
            }
        }
    } else {
        for (int c = 0; c < C; ++c) {
            float w1 = wt[(size_t)c * O + oo];
            float w2 = wt[(size_t)(C + c) * O + oo];
#pragma unroll
            for (int p = 0; p < PP; ++p) {
                float xv = xs[g * PP + p][c];
                a1[p] = fmaf(xv, w1, a1[p]);
                a2[p] = fmaf(xv, w2, a2[p]);
            }
        }
    }
#pragma unroll
    for (int p = 0; p < PP; ++p) {
        size_t row = (size_t)(p0 + g * PP + p) * O + oo;
        z1[row] = a1[p];
        z2[row] = a2[p];
    }
}

// -------------------- gather edges, max/min over k + BN partial sums
// float4 per thread; each gathered row = one coalesced wave transaction.

template<int O>
__global__ void edge_stats_kernel(const float* __restrict__ z1, const float* __restrict__ z2,
                                  const int* __restrict__ idx,
                                  float* __restrict__ vmax, float* __restrict__ vmin,
                                  float* __restrict__ ssum, float* __restrict__ ssq) {
    constexpr int TPP = O / 4;           // threads per point
    constexpr int PPB = 256 / TPP;       // points per block
    const int p0 = blockIdx.x * PPB;
    const int tid = threadIdx.x;
    const int q = tid % TPP;
    const int p = tid / TPP;
    const int oo = q * 4;
    __shared__ int jl[PPB][Kn];
    for (int e = tid; e < PPB * Kn; e += 256)
        jl[e / Kn][e % Kn] = idx[(size_t)(p0 + e / Kn) * Kn + (e % Kn)];
    __syncthreads();
    const int bi = p0 + p;
    const int b = bi >> 11;
    const float4 zi1 = *(const float4*)(z1 + (size_t)bi * O + oo);
    const float4 zi2 = *(const float4*)(z2 + (size_t)bi * O + oo);
    float ax = zi2.x - zi1.x, ay = zi2.y - zi1.y, az = zi2.z - zi1.z, aw = zi2.w - zi1.w;
    float mxx = -3e38f, mxy = -3e38f, mxz = -3e38f, mxw = -3e38f;
    float mnx = 3e38f, mny = 3e38f, mnz = 3e38f, mnw = 3e38f;
    float sx = 0.f, sy = 0.f, sz = 0.f, sw = 0.f;
    float qx = 0.f, qy = 0.f, qz = 0.f, qw = 0.f;
    const float* zbase = z1 + ((size_t)b * Nn) * O + oo;
#pragma unroll
    for (int kk = 0; kk < Kn; ++kk) {
        int j = jl[p][kk];
        float4 v = *(const float4*)(zbase + (size_t)j * O);
        v.x += ax; v.y += ay; v.z += az; v.w += aw;
        mxx = fmaxf(mxx, v.x); mxy = fmaxf(mxy, v.y); mxz = fmaxf(mxz, v.z); mxw = fmaxf(mxw, v.w);
        mnx = fminf(mnx, v.x); mny = fminf(mny, v.y); mnz = fminf(mnz, v.z); mnw = fminf(mnw, v.w);
        sx += v.x; sy += v.y; sz += v.z; sw += v.w;
        qx = fmaf(v.x, v.x, qx); qy = fmaf(v.y, v.y, qy);
        qz = fmaf(v.z, v.z, qz); qw = fmaf(v.w, v.w, qw);
    }
    float4 mx4 = make_float4(mxx, mxy, mxz, mxw);
    float4 mn4 = make_float4(mnx, mny, mnz, mnw);
    *(float4*)(vmax + (size_t)bi * O + oo) = mx4;
    *(float4*)(vmin + (size_t)bi * O + oo) = mn4;
    __shared__ float4 ssm[256], sqq[256];
    ssm[tid] = make_float4(sx, sy, sz, sw);
    sqq[tid] = make_float4(qx, qy, qz, qw);
    __syncthreads();
    if (p == 0) {
#pragma unroll 4
        for (int pp = 1; pp < PPB; ++pp) {
            float4 s4 = ssm[pp * TPP + q];
            float4 q4 = sqq[pp * TPP + q];
            sx += s4.x; sy += s4.y; sz += s4.z; sw += s4.w;
            qx += q4.x; qy += q4.y; qz += q4.z; qw += q4.w;
        }
        int slot = blockIdx.x & 63;
        atomicAdd(&ssum[slot * O + oo + 0], sx);
        atomicAdd(&ssum[slot * O + oo + 1], sy);
        atomicAdd(&ssum[slot * O + oo + 2], sz);
        atomicAdd(&ssum[slot * O + oo + 3], sw);
        atomicAdd(&ssq[slot * O + oo + 0], qx);
        atomicAdd(&ssq[slot * O + oo + 1], qy);
        atomicAdd(&ssq[slot * O + oo + 2], qz);
        atomicAdd(&ssq[slot * O + oo + 3], qw);
    }
}

__global__ void bn_finalize_kernel(const float* __restrict__ ssum, const float* __restrict__ ssq,
                                   const float* __restrict__ gamma, const float* __restrict__ beta,
                                   float* __restrict__ scale, float* __restrict__ shift, int O) {
    int o = threadIdx.x;
    if (o >= O) return;
    float s = 0.f, q = 0.f;
    for (int sl = 0; sl < 64; ++sl) { s += ssum[sl * O + o]; q += ssq[sl * O + o]; }
    const float cnt = (float)Bb * (float)Nn * (float)Kn;
    float mu = s / cnt;
    float var = q / cnt - mu * mu;
    float sc = gamma[o] / sqrtf(var + EPSV);
    scale[o] = sc;
    shift[o] = beta[o] - mu * sc;
}

// ---------------- BN-apply + relu + per-chunk pooling partials (float4)

template<int O>
__global__ void apply_pool_kernel(const float* __restrict__ vmax, const float* __restrict__ vmin,
                                  const float* __restrict__ scale, const float* __restrict__ shift,
                                  float* __restrict__ xout,
                                  float* __restrict__ pmax, float* __restrict__ psum, int obase) {
    constexpr int TPP = O / 4;
    constexpr int PP2 = 256 / TPP;      // points concurrent
    constexpr int S = 128 / PP2;        // iterations
    const int chunk = blockIdx.x;
    const int b = blockIdx.y;
    const int tid = threadIdx.x;
    const int q = tid % TPP;
    const int g = tid / TPP;
    const int oo = q * 4;
    const float4 sc = *(const float4*)(scale + oo);
    const float4 sh = *(const float4*)(shift + oo);
    float pmx = -3e38f, pmy = -3e38f, pmz = -3e38f, pmw = -3e38f;
    float psx = 0.f, psy = 0.f, psz = 0.f, psw = 0.f;
    const int n0 = chunk * 128;
    for (int s = 0; s < S; ++s) {
        int n = n0 + g + s * PP2;
        size_t ix = ((size_t)b * Nn + n) * O + oo;
        float4 vx = *(const float4*)(vmax + ix);
        float4 vn = *(const float4*)(vmin + ix);
        float4 r;
        r.x = fmaxf(fmaf(sc.x >= 0.f ? vx.x : vn.x, sc.x, sh.x), 0.f);
        r.y = fmaxf(fmaf(sc.y >= 0.f ? vx.y : vn.y, sc.y, sh.y), 0.f);
        r.z = fmaxf(fmaf(sc.z >= 0.f ? vx.z : vn.z, sc.z, sh.z), 0.f);
        r.w = fmaxf(fmaf(sc.w >= 0.f ? vx.w : vn.w, sc.w, sh.w), 0.f);
        *(float4*)(xout + ix) = r;
        pmx = fmaxf(pmx, r.x); pmy = fmaxf(pmy, r.y);
        pmz = fmaxf(pmz, r.z); pmw = fmaxf(pmw, r.w);
        psx += r.x; psy += r.y; psz += r.z; psw += r.w;
    }
    __shared__ float4 sm[256], ss2[256];
    sm[tid] = make_float4(pmx, pmy, pmz, pmw);
    ss2[tid] = make_float4(psx, psy, psz, psw);
    __syncthreads();
    if (g == 0) {
#pragma unroll 4
        for (int gg = 1; gg < PP2; ++gg) {
            float4 m4 = sm[gg * TPP + q];
            float4 s4 = ss2[gg * TPP + q];
            pmx = fmaxf(pmx, m4.x); pmy = fmaxf(pmy, m4.y);
            pmz = fmaxf(pmz, m4.z); pmw = fmaxf(pmw, m4.w);
            psx += s4.x; psy += s4.y; psz += s4.z; psw += s4.w;
        }
        size_t pb = ((size_t)b * 16 + chunk) * 512 + obase + oo;
        *(float4*)(pmax + pb) = make_float4(pmx, pmy, pmz, pmw);
        *(float4*)(psum + pb) = make_float4(psx, psy, psz, psw);
    }
}

__global__ void pool_finalize_kernel(const float* __restrict__ pmax, const float* __restrict__ psum,
                                     float* __restrict__ gv) {
    const int b = blockIdx.x;
    const int c = threadIdx.x;          // 512 threads
    float mx = -3e38f, s = 0.f;
    for (int ch = 0; ch < 16; ++ch) {
        size_t p = ((size_t)b * 16 + ch) * 512 + c;
        mx = fmaxf(mx, pmax[p]);
        s += psum[p];
    }
    gv[b * 1024 + c] = mx;
    gv[b * 1024 + 512 + c] = s * (1.f / (float)Nn);
}

// ------------------------------------------------------------------- MLP head

__global__ void head_kernel(const float* __restrict__ gv,
                            const float* __restrict__ fct1, const float* __restrict__ fc1b,
                            const float* __restrict__ ln1g, const float* __restrict__ ln1b,
                            const float* __restrict__ fct2, const float* __restrict__ fc2b,
                            const float* __restrict__ ln2g, const float* __restrict__ ln2b,
                            float* __restrict__ out) {
    const int b = blockIdx.x;
    const int tid = threadIdx.x;
    __shared__ float gx[1024];
    __shared__ float hh[512];
    __shared__ float red[256];
    for (int e = tid; e < 1024; e += 256) gx[e] = gv[b * 1024 + e];
    __syncthreads();
    float h0 = fc1b[tid], h1 = fc1b[tid + 256];
    for (int c = 0; c < 1024; ++c) {
        float gc = gx[c];
        h0 = fmaf(gc, fct1[(size_t)c * 512 + tid], h0);
        h1 = fmaf(gc, fct1[(size_t)c * 512 + tid + 256], h1);
    }
    red[tid] = h0 + h1;
    __syncthreads();
    for (int st = 128; st > 0; st >>= 1) { if (tid < st) red[tid] += red[tid + st]; __syncthreads(); }
    float mu = red[0] * (1.f / 512.f);
    __syncthreads();
    float d0 = h0 - mu, d1 = h1 - mu;
    red[tid] = d0 * d0 + d1 * d1;
    __syncthreads();
    for (int st = 128; st > 0; st >>= 1) { if (tid < st) red[tid] += red[tid + st]; __syncthreads(); }
    float rs = 1.f / sqrtf(red[0] * (1.f / 512.f) + EPSV);
    __syncthreads();
    hh[tid]       = fmaxf(d0 * rs * ln1g[tid] + ln1b[tid], 0.f);
    hh[tid + 256] = fmaxf(d1 * rs * ln1g[tid + 256] + ln1b[tid + 256], 0.f);
    __syncthreads();
    float z = fc2b[tid];
    for (int c = 0; c < 512; ++c) z = fmaf(hh[c], fct2[(size_t)c * 256 + tid], z);
    red[tid] = z;
    __syncthreads();
    for (int st = 128; st > 0; st >>= 1) { if (tid < st) red[tid] += red[tid + st]; __syncthreads(); }
    float mu2 = red[0] * (1.f / 256.f);
    __syncthreads();
    float dz = z - mu2;
    red[tid] = dz * dz;
    __syncthreads();
    for (int st = 128; st > 0; st >>= 1) { if (tid < st) red[tid] += red[tid + st]; __syncthreads(); }
    float rs2 = 1.f / sqrtf(red[0] * (1.f / 256.f) + EPSV);
    out[b * 256 + tid] = dz * rs2 * ln2g[tid] + ln2b[tid];
}

// --------------------------------------------------------------- layer driver

template<int C, int O>
static void run_layer(const float* x, const float* gamma, const float* beta,
                      float* xout, float* DIST, float* XX, int* IDX, float* Z1, float* Z2,
                      float* VMX, float* VMN, float* SSUM, float* SSQ, float* BNS, float* BNB,
                      const float* WT, float* PMAX, float* PSUM, int obase, bool big,
                      hipStream_t stream) {
    sqnorm_zero_kernel<<<192, 256, 0, stream>>>(x, XX, C, SSUM);  // SSUM+SSQ contiguous 32K
    z_kernel<C, O><<<Bb * Nn / 16, 256, 0, stream>>>(x, WT, Z1, Z2);
    if (big) {
        gram_dist_kernel<C><<<dim3(136, 1, Bb), 256, 0, stream>>>(x, XX, DIST, 0, (size_t)Nn * Nn);
        topk_kernel<<<Bb * Nn / 4, 256, 0, stream>>>(DIST, IDX, 0, (size_t)Nn * Nn, 0);
    } else {
        for (int b = 0; b < Bb; ++b) {
            gram_dist_kernel<C><<<dim3(136, 1, 1), 256, 0, stream>>>(x, XX, DIST, b, 0);
            topk_kernel<<<Nn / 4, 256, 0, stream>>>(DIST, IDX, b, 0, 1);
        }
    }
    edge_stats_kernel<O><<<Bb * Nn / (1024 / O), 256, 0, stream>>>(Z1, Z2, IDX, VMX, VMN, SSUM, SSQ);
    bn_finalize_kernel<<<1, 256, 0, stream>>>(SSUM, SSQ, gamma, beta, BNS, BNB, O);
    apply_pool_kernel<O><<<dim3(16, 8), 256, 0, stream>>>(VMX, VMN, BNS, BNB, xout, PMAX, PSUM, obase);
}

extern "C" void kernel_launch(void* const* d_in, const int* in_sizes, int n_in,
                              void* d_out, int out_size, void* d_ws, size_t ws_size,
                              hipStream_t stream) {
    const float* points = (const float*)d_in[0];
    const float* W1 = (const float*)d_in[1];
    const float* g1 = (const float*)d_in[2];
    const float* b1 = (const float*)d_in[3];
    const float* W2 = (const float*)d_in[4];
    const float* g2 = (const float*)d_in[5];
    const float* b2 = (const float*)d_in[6];
    const float* W3 = (const float*)d_in[7];
    const float* g3 = (const float*)d_in[8];
    const float* b3 = (const float*)d_in[9];
    const float* W4 = (const float*)d_in[10];
    const float* g4 = (const float*)d_in[11];
    const float* b4 = (const float*)d_in[12];
    const float* fc1_w = (const float*)d_in[13];
    const float* fc1_b = (const float*)d_in[14];
    const float* ln1g = (const float*)d_in[15];
    const float* ln1b = (const float*)d_in[16];
    const float* fc2_w = (const float*)d_in[17];
    const float* fc2_b = (const float*)d_in[18];
    const float* ln2g = (const float*)d_in[19];
    const float* ln2b = (const float*)d_in[20];

    float* ws = (float*)d_ws;
    const size_t BN = (size_t)Bb * Nn;
    const bool big = ws_size >= (size_t)59826688 * 4;

    size_t off = 0;
    auto take = [&](size_t n) { size_t o = off; off += n; return o; };
    float* DIST = ws + take(big ? (size_t)Bb * Nn * Nn : (size_t)Nn * Nn);
    float* XX   = ws + take(BN);
    int*   IDX  = (int*)(ws + take(BN * Kn));
    float* Z1   = ws + take(BN * 256);
    float* Z2   = ws + take(BN * 256);
    float* VMX  = ws + take(BN * 256);
    float* VMN  = ws + take(BN * 256);
    float* SSUM = ws + take(64 * 256);
    float* SSQ  = ws + take(64 * 256);
    float* BNS  = ws + take(256);
    float* BNB  = ws + take(256);
    float* WT1  = ws + take(384);
    float* WT2  = ws + take(8192);
    float* WT3  = ws + take(16384);
    float* WT4  = ws + take(65536);
    float* FCT1 = ws + take(524288);
    float* FCT2 = ws + take(131072);
    float* X1   = ws + take(BN * 64);
    float* X2   = ws + take(BN * 64);
    float* X3   = ws + take(BN * 128);
    float* X4   = ws + take(BN * 256);
    float* GV   = ws + take((size_t)Bb * 1024);
    float* PMAX = ws + take((size_t)Bb * 16 * 512);
    float* PSUM = ws + take((size_t)Bb * 16 * 512);

    // All weight transposes in one launch (independent of layer outputs).
    TransJobs tj;
    tj.in[0] = W1;    tj.out[0] = WT1;  tj.R[0] = 64;  tj.Cc[0] = 6;
    tj.in[1] = W2;    tj.out[1] = WT2;  tj.R[1] = 64;  tj.Cc[1] = 128;
    tj.in[2] = W3;    tj.out[2] = WT3;  tj.R[2] = 128; tj.Cc[2] = 128;
    tj.in[3] = W4;    tj.out[3] = WT4;  tj.R[3] = 256; tj.Cc[3] = 256;
    tj.in[4] = fc1_w; tj.out[4] = FCT1; tj.R[4] = 512; tj.Cc[4] = 1024;
    tj.in[5] = fc2_w; tj.out[5] = FCT2; tj.R[5] = 256; tj.Cc[5] = 512;
    transpose_all_kernel<<<dim3(2048, 6), 256, 0, stream>>>(tj);

    run_layer<3, 64>(points, g1, b1, X1, DIST, XX, IDX, Z1, Z2, VMX, VMN, SSUM, SSQ, BNS, BNB, WT1, PMAX, PSUM, 0, big, stream);
    run_layer<64, 64>(X1, g2, b2, X2, DIST, XX, IDX, Z1, Z2, VMX, VMN, SSUM, SSQ, BNS, BNB, WT2, PMAX, PSUM, 64, big, stream);
    run_layer<64, 128>(X2, g3, b3, X3, DIST, XX, IDX, Z1, Z2, VMX, VMN, SSUM, SSQ, BNS, BNB, WT3, PMAX, PSUM, 128, big, stream);
    run_layer<128, 256>(X3, g4, b4, X4, DIST, XX, IDX, Z1, Z2, VMX, VMN, SSUM, SSQ, BNS, BNB, WT4, PMAX, PSUM, 256, big, stream);

    pool_finalize_kernel<<<Bb, 512, 0, stream>>>(PMAX, PSUM, GV);
    head_kernel<<<Bb, 256, 0, stream>>>(GV, FCT1, fc1_b, ln1g, ln1b, FCT2, fc2_b, ln2g, ln2b,
                                        (float*)d_out);
}

// Round 10
// 912.898 us; speedup vs baseline: 1.6180x; 1.6180x over previous
//
#include <hip/hip_runtime.h>
#include <cstdint>
#include <cstddef>

static constexpr int Bb = 8;
static constexpr int Nn = 2048;
static constexpr int Kn = 20;
static constexpr float EPSV = 1e-5f;

// ---------------------------------------------------------------- utilities

// blocks 0..63: xx[i] = ||x_i||^2 ; blocks 64..191: zero 32K floats of zp
__global__ void sqnorm_zero_kernel(const float* __restrict__ x, float* __restrict__ xx, int C,
                                   float* __restrict__ zp) {
    int blk = blockIdx.x;
    if (blk < 64) {
        int i = blk * 256 + threadIdx.x;
        const float* xr = x + (size_t)i * C;
        float s = 0.f;
        for (int c = 0; c < C; ++c) { float v = xr[c]; s += v * v; }
        xx[i] = s;
    } else {
        zp[(blk - 64) * 256 + threadIdx.x] = 0.f;
    }
}

// all weight transposes in one launch: out[c*R + r] = in[r*Cc + c]
struct TransJobs {
    const float* in[6];
    float* out[6];
    int R[6];
    int Cc[6];
};

__global__ void transpose_all_kernel(TransJobs tj) {
    int m = blockIdx.y;
    int i = blockIdx.x * 256 + threadIdx.x;
    int total = tj.R[m] * tj.Cc[m];
    if (i < total) {
        int r = i / tj.Cc[m], c = i % tj.Cc[m];
        tj.out[m][(size_t)c * tj.R[m] + r] = tj.in[m][i];
    }
}

// ------------------------------------------------ pairwise sq-dist (tiled gram)
// SYMMETRIC: only the 136 upper-triangular 128x128 block-pairs are computed;
// off-diagonal blocks emit the mirrored tile through a 32-row LDS transpose
// buffer (bitwise-identical values; 4 chunks x 2 barriers).
// Main loop is the R8 single-buffer form — FROZEN. History:
//   (256,3)/(256,4)  -> accumulator spills to scratch (R5 18x traffic, R6 +270MB)
//   reg prefetch     -> +32 VGPR, occupancy 27->20%, net loss (R7)
//   LDS double-buffer-> VGPR 128, spill, 1.49 GB traffic, 350 us (R9)
// launch_bounds(256,2), plain k-loop, VGPR~68, WRITE exactly 131 MB is the
// verified spill-free optimum. DO NOT add register pressure to this loop.

template<int C>
__global__ __launch_bounds__(256, 2)
void gram_dist_kernel(const float* __restrict__ x, const float* __restrict__ xx,
                      float* __restrict__ dist, int b0, size_t dstride) {
    constexpr int CT = (C < 16) ? C : 16;
    const int b = b0 + blockIdx.z;
    // decode upper-tri pair index -> (rblk, cblk), rblk <= cblk, 16x16 tiles
    int p = blockIdx.x, rblk = 0;
    while (p >= 16 - rblk) { p -= 16 - rblk; ++rblk; }
    const int cblk = rblk + p;
    const int i0 = rblk * 128, j0 = cblk * 128;
    const int tid = threadIdx.x;
    const int tx = tid & 15, ty = tid >> 4;
    __shared__ float As[CT][136];
    __shared__ float BsA[CT][68];
    __shared__ float BsB[CT][68];
    __shared__ float T[32][136];
    float acc[8][8] = {};
    const float* xb = x + (size_t)b * Nn * C;

    const int si = tid & 127;         // staging row
    const int half = tid >> 7;        // 0..1
    float* bbase = ((si & 4) ? &BsB[0][0] : &BsA[0][0]) + (((si >> 3) << 2) | (si & 3));

    for (int c0 = 0; c0 < C; c0 += CT) {
        if constexpr (CT == 16) {
            const float* ra = xb + (size_t)(i0 + si) * C + c0 + half * 8;
            const float* rb = xb + (size_t)(j0 + si) * C + c0 + half * 8;
            float4 a0 = *(const float4*)ra;
            float4 a1 = *(const float4*)(ra + 4);
            float4 bq0 = *(const float4*)rb;
            float4 bq1 = *(const float4*)(rb + 4);
            const int cb = half * 8;
            As[cb + 0][si] = a0.x; As[cb + 1][si] = a0.y;
            As[cb + 2][si] = a0.z; As[cb + 3][si] = a0.w;
            As[cb + 4][si] = a1.x; As[cb + 5][si] = a1.y;
            As[cb + 6][si] = a1.z; As[cb + 7][si] = a1.w;
            bbase[(cb + 0) * 68] = bq0.x; bbase[(cb + 1) * 68] = bq0.y;
            bbase[(cb + 2) * 68] = bq0.z; bbase[(cb + 3) * 68] = bq0.w;
            bbase[(cb + 4) * 68] = bq1.x; bbase[(cb + 5) * 68] = bq1.y;
            bbase[(cb + 6) * 68] = bq1.z; bbase[(cb + 7) * 68] = bq1.w;
        } else {
            if (half == 0) {
                const float* r0 = xb + (size_t)(i0 + si) * C + c0;
#pragma unroll
                for (int c = 0; c < CT; ++c) As[c][si] = r0[c];
            } else {
                const float* r1 = xb + (size_t)(j0 + si) * C + c0;
#pragma unroll
                for (int c = 0; c < CT; ++c) bbase[c * 68] = r1[c];
            }
        }
        __syncthreads();
#pragma unroll
        for (int cc = 0; cc < CT; ++cc) {
            float a[8], bv[8];
            *(float4*)&a[0]  = *(const float4*)&As[cc][ty * 8];
            *(float4*)&a[4]  = *(const float4*)&As[cc][ty * 8 + 4];
            *(float4*)&bv[0] = *(const float4*)&BsA[cc][tx * 4];
            *(float4*)&bv[4] = *(const float4*)&BsB[cc][tx * 4];
#pragma unroll
            for (int u = 0; u < 8; ++u)
#pragma unroll
                for (int v = 0; v < 8; ++v)
                    acc[u][v] = fmaf(a[u], bv[v], acc[u][v]);
        }
        __syncthreads();
    }

    const float* xxb = xx + (size_t)b * Nn;
    float xi[8], xj[8];
#pragma unroll
    for (int u = 0; u < 8; ++u) xi[u] = xxb[i0 + ty * 8 + u];
#pragma unroll
    for (int v = 0; v < 8; ++v) xj[v] = xxb[j0 + tx * 8 + v];
    float* db = dist + (size_t)blockIdx.z * dstride;
#pragma unroll
    for (int u = 0; u < 8; ++u) {
        float* row = db + (size_t)(i0 + ty * 8 + u) * Nn + (j0 + tx * 8);
        float4 o0, o1;
        o0.x = xi[u] + xj[0] - 2.f * acc[u][0];
        o0.y = xi[u] + xj[1] - 2.f * acc[u][1];
        o0.z = xi[u] + xj[2] - 2.f * acc[u][2];
        o0.w = xi[u] + xj[3] - 2.f * acc[u][3];
        o1.x = xi[u] + xj[4] - 2.f * acc[u][4];
        o1.y = xi[u] + xj[5] - 2.f * acc[u][5];
        o1.z = xi[u] + xj[6] - 2.f * acc[u][6];
        o1.w = xi[u] + xj[7] - 2.f * acc[u][7];
        *(float4*)row = o0;
        *(float4*)(row + 4) = o1;
    }

    if (cblk > rblk) {
        // mirror tile (j0.., i0..): value(row=j0+tx*8+v, col=i0+ty*8+u)
        //   = xj[v] + xi[u] - 2*acc[u][v]  (bitwise equal to main tile)
        // 4 chunks of 32 rows; 64 writer-threads per chunk, 8 barriers total.
        const int rr = tid >> 3;            // 0..31 row within 32-row chunk
        const int c4 = (tid & 7) * 4;       // col base (float4 granularity)
#pragma unroll 1
        for (int m = 0; m < 4; ++m) {
            if ((tx >> 2) == m) {
                const int lr = (tx & 3) * 8;
#pragma unroll
                for (int v = 0; v < 8; ++v)
#pragma unroll
                    for (int u = 0; u < 8; ++u)
                        T[lr + v][ty * 8 + u] = xj[v] + xi[u] - 2.f * acc[u][v];
            }
            __syncthreads();
            float* orow = db + (size_t)(j0 + m * 32 + rr) * Nn + i0;
#pragma unroll
            for (int s = 0; s < 4; ++s)
                *(float4*)(orow + c4 + s * 32) = *(const float4*)&T[rr][c4 + s * 32];
            __syncthreads();
        }
    }
}

// ------------------------------------------------------- top-k (k=20 smallest)

__device__ __forceinline__ bool lex_less(float v1, int j1, float v2, int j2) {
    return v1 < v2 || (v1 == v2 && j1 < j2);
}

__device__ __forceinline__ void top4_build(const float4* __restrict__ dr4, int lane,
                                           unsigned xmask,
                                           float& tv0, int& tj0, int& ts0,
                                           float& tv1, int& tj1, int& ts1,
                                           float& tv2, int& tj2, int& ts2,
                                           float& tv3, int& tj3, int& ts3) {
    tv0 = tv1 = tv2 = tv3 = 3e38f;
    tj0 = tj1 = tj2 = tj3 = 1 << 30;
    ts0 = ts1 = ts2 = ts3 = 0;
#pragma unroll
    for (int q = 0; q < 8; ++q) {
        float4 f = dr4[q * 64 + lane];
        float vv[4] = {f.x, f.y, f.z, f.w};
#pragma unroll
        for (int c = 0; c < 4; ++c) {
            int s = q * 4 + c;
            if ((xmask >> s) & 1u) continue;
            int j = (q * 64 + lane) * 4 + c;
            float v = vv[c];
            if (lex_less(v, j, tv3, tj3)) {
                tv3 = v; tj3 = j; ts3 = s;
                if (lex_less(tv3, tj3, tv2, tj2)) {
                    float fv = tv2; int fj = tj2, fs = ts2;
                    tv2 = tv3; tj2 = tj3; ts2 = ts3; tv3 = fv; tj3 = fj; ts3 = fs;
                }
                if (lex_less(tv2, tj2, tv1, tj1)) {
                    float fv = tv1; int fj = tj1, fs = ts1;
                    tv1 = tv2; tj1 = tj2; ts1 = ts2; tv2 = fv; tj2 = fj; ts2 = fs;
                }
                if (lex_less(tv1, tj1, tv0, tj0)) {
                    float fv = tv0; int fj = tj0, fs = ts0;
                    tv0 = tv1; tj0 = tj1; ts0 = ts1; tv1 = fv; tj1 = fj; ts1 = fs;
                }
            }
        }
    }
}

__global__ void topk_kernel(const float* __restrict__ dist, int* __restrict__ idxo,
                            int b0, size_t dstride, int rows_per_batch_only) {
    const int w = threadIdx.x >> 6;
    const int lane = threadIdx.x & 63;
    const int lin = blockIdx.x * 4 + w;
    int bz, i;
    if (rows_per_batch_only) { bz = 0; i = lin; }
    else { bz = lin >> 11; i = lin & (Nn - 1); }
    const int b = b0 + bz;
    const float4* dr4 = (const float4*)(dist + (size_t)bz * dstride + (size_t)i * Nn);

    float tv0, tv1, tv2, tv3;
    int tj0, tj1, tj2, tj3, ts0, ts1, ts2, ts3;
    unsigned xmask = 0;
    top4_build(dr4, lane, 0u, tv0, tj0, ts0, tv1, tj1, ts1, tv2, tj2, ts2, tv3, tj3, ts3);
    int cnt = 0;

    int* orow = idxo + ((size_t)b * Nn + i) * Kn;
    for (int t = 0; t < Kn; ++t) {
        float bv = tv0; int bj = tj0;
#pragma unroll
        for (int off = 1; off < 64; off <<= 1) {
            float ov = __shfl_xor(bv, off);
            int oj = __shfl_xor(bj, off);
            if (lex_less(ov, oj, bv, bj)) { bv = ov; bj = oj; }
        }
        if (lane == 0) orow[t] = bj;
        if (tj0 == bj) {
            xmask |= 1u << ts0;
            tv0 = tv1; tj0 = tj1; ts0 = ts1;
            tv1 = tv2; tj1 = tj2; ts1 = ts2;
            tv2 = tv3; tj2 = tj3; ts2 = ts3;
            tv3 = 3e38f; tj3 = 1 << 30; ts3 = 0;
            if (++cnt == 4) {
                top4_build(dr4, lane, xmask, tv0, tj0, ts0, tv1, tj1, ts1,
                           tv2, tj2, ts2, tv3, tj3, ts3);
                cnt = 0;
            }
        }
    }
}

// ------------------------------------- per-point projections Z1=X Wl^T, Z2=X Wr^T

template<int C, int O>
__global__ void z_kernel(const float* __restrict__ x, const float* __restrict__ wt,
                         float* __restrict__ z1, float* __restrict__ z2) {
    constexpr int TP = 16;
    constexpr int G = 256 / O;
    constexpr int PP = TP / G;
    const int p0 = blockIdx.x * TP;
    const int tid = threadIdx.x;
    const int oo = tid % O;
    const int g = tid / O;
    __shared__ float xs[TP][(C < 4) ? 4 : C];
    for (int e = tid; e < TP * C; e += 256) {
        int p = e / C, c = e % C;
        xs[p][c] = x[(size_t)(p0 + p) * C + c];
    }
    __syncthreads();
    float a1[PP], a2[PP];
#pragma unroll
    for (int p = 0; p < PP; ++p) { a1[p] = 0.f; a2[p] = 0.f; }
    if constexpr (C % 4 == 0) {
        for (int c = 0; c < C; c += 4) {
            float w1[4], w2[4];
#pragma unroll
            for (int q = 0; q < 4; ++q) {
                w1[q] = wt[(size_t)(c + q) * O + oo];
                w2[q] = wt[(size_t)(C + c + q) * O + oo];
            }
#pragma unroll
            for (int p = 0; p < PP; ++p) {
                const float4 xv = *(const float4*)(&xs[g * PP + p][c]);
                a1[p] = fmaf(xv.w, w1[3], fmaf(xv.z, w1[2], fmaf(xv.y, w1[1], fmaf(xv.x, w1[0], a1[p]))));
                a2[p] = fmaf(xv.w, w2[3], fmaf(xv.z, w2[2], fmaf(xv.y, w2[1], fmaf(xv.x, w2[0], a2[p]))));
            }
        }
    } else {
        for (int c = 0; c < C; ++c) {
            float w1 = wt[(size_t)c * O + oo];
            float w2 = wt[(size_t)(C + c) * O + oo];
#pragma unroll
            for (int p = 0; p < PP; ++p) {
                float xv = xs[g * PP + p][c];
                a1[p] = fmaf(xv, w1, a1[p]);
                a2[p] = fmaf(xv, w2, a2[p]);
            }
        }
    }
#pragma unroll
    for (int p = 0; p < PP; ++p) {
        size_t row = (size_t)(p0 + g * PP + p) * O + oo;
        z1[row] = a1[p];
        z2[row] = a2[p];
    }
}

// -------------------- gather edges, max/min over k + BN partial sums
// float4 per thread; each gathered row = one coalesced wave transaction.

template<int O>
__global__ void edge_stats_kernel(const float* __restrict__ z1, const float* __restrict__ z2,
                                  const int* __restrict__ idx,
                                  float* __restrict__ vmax, float* __restrict__ vmin,
                                  float* __restrict__ ssum, float* __restrict__ ssq) {
    constexpr int TPP = O / 4;           // threads per point
    constexpr int PPB = 256 / TPP;       // points per block
    const int p0 = blockIdx.x * PPB;
    const int tid = threadIdx.x;
    const int q = tid % TPP;
    const int p = tid / TPP;
    const int oo = q * 4;
    __shared__ int jl[PPB][Kn];
    for (int e = tid; e < PPB * Kn; e += 256)
        jl[e / Kn][e % Kn] = idx[(size_t)(p0 + e / Kn) * Kn + (e % Kn)];
    __syncthreads();
    const int bi = p0 + p;
    const int b = bi >> 11;
    const float4 zi1 = *(const float4*)(z1 + (size_t)bi * O + oo);
    const float4 zi2 = *(const float4*)(z2 + (size_t)bi * O + oo);
    float ax = zi2.x - zi1.x, ay = zi2.y - zi1.y, az = zi2.z - zi1.z, aw = zi2.w - zi1.w;
    float mxx = -3e38f, mxy = -3e38f, mxz = -3e38f, mxw = -3e38f;
    float mnx = 3e38f, mny = 3e38f, mnz = 3e38f, mnw = 3e38f;
    float sx = 0.f, sy = 0.f, sz = 0.f, sw = 0.f;
    float qx = 0.f, qy = 0.f, qz = 0.f, qw = 0.f;
    const float* zbase = z1 + ((size_t)b * Nn) * O + oo;
#pragma unroll
    for (int kk = 0; kk < Kn; ++kk) {
        int j = jl[p][kk];
        float4 v = *(const float4*)(zbase + (size_t)j * O);
        v.x += ax; v.y += ay; v.z += az; v.w += aw;
        mxx = fmaxf(mxx, v.x); mxy = fmaxf(mxy, v.y); mxz = fmaxf(mxz, v.z); mxw = fmaxf(mxw, v.w);
        mnx = fminf(mnx, v.x); mny = fminf(mny, v.y); mnz = fminf(mnz, v.z); mnw = fminf(mnw, v.w);
        sx += v.x; sy += v.y; sz += v.z; sw += v.w;
        qx = fmaf(v.x, v.x, qx); qy = fmaf(v.y, v.y, qy);
        qz = fmaf(v.z, v.z, qz); qw = fmaf(v.w, v.w, qw);
    }
    float4 mx4 = make_float4(mxx, mxy, mxz, mxw);
    float4 mn4 = make_float4(mnx, mny, mnz, mnw);
    *(float4*)(vmax + (size_t)bi * O + oo) = mx4;
    *(float4*)(vmin + (size_t)bi * O + oo) = mn4;
    __shared__ float4 ssm[256], sqq[256];
    ssm[tid] = make_float4(sx, sy, sz, sw);
    sqq[tid] = make_float4(qx, qy, qz, qw);
    __syncthreads();
    if (p == 0) {
#pragma unroll 4
        for (int pp = 1; pp < PPB; ++pp) {
            float4 s4 = ssm[pp * TPP + q];
            float4 q4 = sqq[pp * TPP + q];
            sx += s4.x; sy += s4.y; sz += s4.z; sw += s4.w;
            qx += q4.x; qy += q4.y; qz += q4.z; qw += q4.w;
        }
        int slot = blockIdx.x & 63;
        atomicAdd(&ssum[slot * O + oo + 0], sx);
        atomicAdd(&ssum[slot * O + oo + 1], sy);
        atomicAdd(&ssum[slot * O + oo + 2], sz);
        atomicAdd(&ssum[slot * O + oo + 3], sw);
        atomicAdd(&ssq[slot * O + oo + 0], qx);
        atomicAdd(&ssq[slot * O + oo + 1], qy);
        atomicAdd(&ssq[slot * O + oo + 2], qz);
        atomicAdd(&ssq[slot * O + oo + 3], qw);
    }
}

__global__ void bn_finalize_kernel(const float* __restrict__ ssum, const float* __restrict__ ssq,
                                   const float* __restrict__ gamma, const float* __restrict__ beta,
                                   float* __restrict__ scale, float* __restrict__ shift, int O) {
    int o = threadIdx.x;
    if (o >= O) return;
    float s = 0.f, q = 0.f;
    for (int sl = 0; sl < 64; ++sl) { s += ssum[sl * O + o]; q += ssq[sl * O + o]; }
    const float cnt = (float)Bb * (float)Nn * (float)Kn;
    float mu = s / cnt;
    float var = q / cnt - mu * mu;
    float sc = gamma[o] / sqrtf(var + EPSV);
    scale[o] = sc;
    shift[o] = beta[o] - mu * sc;
}

// ---------------- BN-apply + relu + per-chunk pooling partials (float4)

template<int O>
__global__ void apply_pool_kernel(const float* __restrict__ vmax, const float* __restrict__ vmin,
                                  const float* __restrict__ scale, const float* __restrict__ shift,
                                  float* __restrict__ xout,
                                  float* __restrict__ pmax, float* __restrict__ psum, int obase) {
    constexpr int TPP = O / 4;
    constexpr int PP2 = 256 / TPP;      // points concurrent
    constexpr int S = 128 / PP2;        // iterations
    const int chunk = blockIdx.x;
    const int b = blockIdx.y;
    const int tid = threadIdx.x;
    const int q = tid % TPP;
    const int g = tid / TPP;
    const int oo = q * 4;
    const float4 sc = *(const float4*)(scale + oo);
    const float4 sh = *(const float4*)(shift + oo);
    float pmx = -3e38f, pmy = -3e38f, pmz = -3e38f, pmw = -3e38f;
    float psx = 0.f, psy = 0.f, psz = 0.f, psw = 0.f;
    const int n0 = chunk * 128;
    for (int s = 0; s < S; ++s) {
        int n = n0 + g + s * PP2;
        size_t ix = ((size_t)b * Nn + n) * O + oo;
        float4 vx = *(const float4*)(vmax + ix);
        float4 vn = *(const float4*)(vmin + ix);
        float4 r;
        r.x = fmaxf(fmaf(sc.x >= 0.f ? vx.x : vn.x, sc.x, sh.x), 0.f);
        r.y = fmaxf(fmaf(sc.y >= 0.f ? vx.y : vn.y, sc.y, sh.y), 0.f);
        r.z = fmaxf(fmaf(sc.z >= 0.f ? vx.z : vn.z, sc.z, sh.z), 0.f);
        r.w = fmaxf(fmaf(sc.w >= 0.f ? vx.w : vn.w, sc.w, sh.w), 0.f);
        *(float4*)(xout + ix) = r;
        pmx = fmaxf(pmx, r.x); pmy = fmaxf(pmy, r.y);
        pmz = fmaxf(pmz, r.z); pmw = fmaxf(pmw, r.w);
        psx += r.x; psy += r.y; psz += r.z; psw += r.w;
    }
    __shared__ float4 sm[256], ss2[256];
    sm[tid] = make_float4(pmx, pmy, pmz, pmw);
    ss2[tid] = make_float4(psx, psy, psz, psw);
    __syncthreads();
    if (g == 0) {
#pragma unroll 4
        for (int gg = 1; gg < PP2; ++gg) {
            float4 m4 = sm[gg * TPP + q];
            float4 s4 = ss2[gg * TPP + q];
            pmx = fmaxf(pmx, m4.x); pmy = fmaxf(pmy, m4.y);
            pmz = fmaxf(pmz, m4.z); pmw = fmaxf(pmw, m4.w);
            psx += s4.x; psy += s4.y; psz += s4.z; psw += s4.w;
        }
        size_t pb = ((size_t)b * 16 + chunk) * 512 + obase + oo;
        *(float4*)(pmax + pb) = make_float4(pmx, pmy, pmz, pmw);
        *(float4*)(psum + pb) = make_float4(psx, psy, psz, psw);
    }
}

__global__ void pool_finalize_kernel(const float* __restrict__ pmax, const float* __restrict__ psum,
                                     float* __restrict__ gv) {
    const int b = blockIdx.x;
    const int c = threadIdx.x;          // 512 threads
    float mx = -3e38f, s = 0.f;
    for (int ch = 0; ch < 16; ++ch) {
        size_t p = ((size_t)b * 16 + ch) * 512 + c;
        mx = fmaxf(mx, pmax[p]);
        s += psum[p];
    }
    gv[b * 1024 + c] = mx;
    gv[b * 1024 + 512 + c] = s * (1.f / (float)Nn);
}

// ------------------------------------------------------------------- MLP head

__global__ void head_kernel(const float* __restrict__ gv,
                            const float* __restrict__ fct1, const float* __restrict__ fc1b,
                            const float* __restrict__ ln1g, const float* __restrict__ ln1b,
                            const float* __restrict__ fct2, const float* __restrict__ fc2b,
                            const float* __restrict__ ln2g, const float* __restrict__ ln2b,
                            float* __restrict__ out) {
    const int b = blockIdx.x;
    const int tid = threadIdx.x;
    __shared__ float gx[1024];
    __shared__ float hh[512];
    __shared__ float red[256];
    for (int e = tid; e < 1024; e += 256) gx[e] = gv[b * 1024 + e];
    __syncthreads();
    float h0 = fc1b[tid], h1 = fc1b[tid + 256];
    for (int c = 0; c < 1024; ++c) {
        float gc = gx[c];
        h0 = fmaf(gc, fct1[(size_t)c * 512 + tid], h0);
        h1 = fmaf(gc, fct1[(size_t)c * 512 + tid + 256], h1);
    }
    red[tid] = h0 + h1;
    __syncthreads();
    for (int st = 128; st > 0; st >>= 1) { if (tid < st) red[tid] += red[tid + st]; __syncthreads(); }
    float mu = red[0] * (1.f / 512.f);
    __syncthreads();
    float d0 = h0 - mu, d1 = h1 - mu;
    red[tid] = d0 * d0 + d1 * d1;
    __syncthreads();
    for (int st = 128; st > 0; st >>= 1) { if (tid < st) red[tid] += red[tid + st]; __syncthreads(); }
    float rs = 1.f / sqrtf(red[0] * (1.f / 512.f) + EPSV);
    __syncthreads();
    hh[tid]       = fmaxf(d0 * rs * ln1g[tid] + ln1b[tid], 0.f);
    hh[tid + 256] = fmaxf(d1 * rs * ln1g[tid + 256] + ln1b[tid + 256], 0.f);
    __syncthreads();
    float z = fc2b[tid];
    for (int c = 0; c < 512; ++c) z = fmaf(hh[c], fct2[(size_t)c * 256 + tid], z);
    red[tid] = z;
    __syncthreads();
    for (int st = 128; st > 0; st >>= 1) { if (tid < st) red[tid] += red[tid + st]; __syncthreads(); }
    float mu2 = red[0] * (1.f / 256.f);
    __syncthreads();
    float dz = z - mu2;
    red[tid] = dz * dz;
    __syncthreads();
    for (int st = 128; st > 0; st >>= 1) { if (tid < st) red[tid] += red[tid + st]; __syncthreads(); }
    float rs2 = 1.f / sqrtf(red[0] * (1.f / 256.f) + EPSV);
    out[b * 256 + tid] = dz * rs2 * ln2g[tid] + ln2b[tid];
}

// --------------------------------------------------------------- layer driver

template<int C, int O>
static void run_layer(const float* x, const float* gamma, const float* beta,
                      float* xout, float* DIST, float* XX, int* IDX, float* Z1, float* Z2,
                      float* VMX, float* VMN, float* SSUM, float* SSQ, float* BNS, float* BNB,
                      const float* WT, float* PMAX, float* PSUM, int obase, bool big,
                      hipStream_t stream) {
    sqnorm_zero_kernel<<<192, 256, 0, stream>>>(x, XX, C, SSUM);  // SSUM+SSQ contiguous 32K
    z_kernel<C, O><<<Bb * Nn / 16, 256, 0, stream>>>(x, WT, Z1, Z2);
    if (big) {
        gram_dist_kernel<C><<<dim3(136, 1, Bb), 256, 0, stream>>>(x, XX, DIST, 0, (size_t)Nn * Nn);
        topk_kernel<<<Bb * Nn / 4, 256, 0, stream>>>(DIST, IDX, 0, (size_t)Nn * Nn, 0);
    } else {
        for (int b = 0; b < Bb; ++b) {
            gram_dist_kernel<C><<<dim3(136, 1, 1), 256, 0, stream>>>(x, XX, DIST, b, 0);
            topk_kernel<<<Nn / 4, 256, 0, stream>>>(DIST, IDX, b, 0, 1);
        }
    }
    edge_stats_kernel<O><<<Bb * Nn / (1024 / O), 256, 0, stream>>>(Z1, Z2, IDX, VMX, VMN, SSUM, SSQ);
    bn_finalize_kernel<<<1, 256, 0, stream>>>(SSUM, SSQ, gamma, beta, BNS, BNB, O);
    apply_pool_kernel<O><<<dim3(16, 8), 256, 0, stream>>>(VMX, VMN, BNS, BNB, xout, PMAX, PSUM, obase);
}

extern "C" void kernel_launch(void* const* d_in, const int* in_sizes, int n_in,
                              void* d_out, int out_size, void* d_ws, size_t ws_size,
                              hipStream_t stream) {
    const float* points = (const float*)d_in[0];
    const float* W1 = (const float*)d_in[1];
    const float* g1 = (const float*)d_in[2];
    const float* b1 = (const float*)d_in[3];
    const float* W2 = (const float*)d_in[4];
    const float* g2 = (const float*)d_in[5];
    const float* b2 = (const float*)d_in[6];
    const float* W3 = (const float*)d_in[7];
    const float* g3 = (const float*)d_in[8];
    const float* b3 = (const float*)d_in[9];
    const float* W4 = (const float*)d_in[10];
    const float* g4 = (const float*)d_in[11];
    const float* b4 = (const float*)d_in[12];
    const float* fc1_w = (const float*)d_in[13];
    const float* fc1_b = (const float*)d_in[14];
    const float* ln1g = (const float*)d_in[15];
    const float* ln1b = (const float*)d_in[16];
    const float* fc2_w = (const float*)d_in[17];
    const float* fc2_b = (const float*)d_in[18];
    const float* ln2g = (const float*)d_in[19];
    const float* ln2b = (const float*)d_in[20];

    float* ws = (float*)d_ws;
    const size_t BN = (size_t)Bb * Nn;
    const bool big = ws_size >= (size_t)59826688 * 4;

    size_t off = 0;
    auto take = [&](size_t n) { size_t o = off; off += n; return o; };
    float* DIST = ws + take(big ? (size_t)Bb * Nn * Nn : (size_t)Nn * Nn);
    float* XX   = ws + take(BN);
    int*   IDX  = (int*)(ws + take(BN * Kn));
    float* Z1   = ws + take(BN * 256);
    float* Z2   = ws + take(BN * 256);
    float* VMX  = ws + take(BN * 256);
    float* VMN  = ws + take(BN * 256);
    float* SSUM = ws + take(64 * 256);
    float* SSQ  = ws + take(64 * 256);
    float* BNS  = ws + take(256);
    float* BNB  = ws + take(256);
    float* WT1  = ws + take(384);
    float* WT2  = ws + take(8192);
    float* WT3  = ws + take(16384);
    float* WT4  = ws + take(65536);
    float* FCT1 = ws + take(524288);
    float* FCT2 = ws + take(131072);
    float* X1   = ws + take(BN * 64);
    float* X2   = ws + take(BN * 64);
    float* X3   = ws + take(BN * 128);
    float* X4   = ws + take(BN * 256);
    float* GV   = ws + take((size_t)Bb * 1024);
    float* PMAX = ws + take((size_t)Bb * 16 * 512);
    float* PSUM = ws + take((size_t)Bb * 16 * 512);

    // All weight transposes in one launch (independent of layer outputs).
    TransJobs tj;
    tj.in[0] = W1;    tj.out[0] = WT1;  tj.R[0] = 64;  tj.Cc[0] = 6;
    tj.in[1] = W2;    tj.out[1] = WT2;  tj.R[1] = 64;  tj.Cc[1] = 128;
    tj.in[2] = W3;    tj.out[2] = WT3;  tj.R[2] = 128; tj.Cc[2] = 128;
    tj.in[3] = W4;    tj.out[3] = WT4;  tj.R[3] = 256; tj.Cc[3] = 256;
    tj.in[4] = fc1_w; tj.out[4] = FCT1; tj.R[4] = 512; tj.Cc[4] = 1024;
    tj.in[5] = fc2_w; tj.out[5] = FCT2; tj.R[5] = 256; tj.Cc[5] = 512;
    transpose_all_kernel<<<dim3(2048, 6), 256, 0, stream>>>(tj);

    run_layer<3, 64>(points, g1, b1, X1, DIST, XX, IDX, Z1, Z2, VMX, VMN, SSUM, SSQ, BNS, BNB, WT1, PMAX, PSUM, 0, big, stream);
    run_layer<64, 64>(X1, g2, b2, X2, DIST, XX, IDX, Z1, Z2, VMX, VMN, SSUM, SSQ, BNS, BNB, WT2, PMAX, PSUM, 64, big, stream);
    run_layer<64, 128>(X2, g3, b3, X3, DIST, XX, IDX, Z1, Z2, VMX, VMN, SSUM, SSQ, BNS, BNB, WT3, PMAX, PSUM, 128, big, stream);
    run_layer<128, 256>(X3, g4, b4, X4, DIST, XX, IDX, Z1, Z2, VMX, VMN, SSUM, SSQ, BNS, BNB, WT4, PMAX, PSUM, 256, big, stream);

    pool_finalize_kernel<<<Bb, 512, 0, stream>>>(PMAX, PSUM, GV);
    head_kernel<<<Bb, 256, 0, stream>>>(GV, FCT1, fc1_b, ln1g, ln1b, FCT2, fc2_b, ln2g, ln2b,
                                        (float*)d_out);
}

// Round 11
// 904.446 us; speedup vs baseline: 1.6331x; 1.0093x over previous
//
#include <hip/hip_runtime.h>
#include <cstdint>
#include <cstddef>

static constexpr int Bb = 8;
static constexpr int Nn = 2048;
static constexpr int Kn = 20;
static constexpr float EPSV = 1e-5f;

// ---------------------------------------------------------------- utilities

// blocks 0..63: xx[i] = ||x_i||^2 ; blocks 64..191: zero 32K floats of zp
__global__ void sqnorm_zero_kernel(const float* __restrict__ x, float* __restrict__ xx, int C,
                                   float* __restrict__ zp) {
    int blk = blockIdx.x;
    if (blk < 64) {
        int i = blk * 256 + threadIdx.x;
        const float* xr = x + (size_t)i * C;
        float s = 0.f;
        for (int c = 0; c < C; ++c) { float v = xr[c]; s += v * v; }
        xx[i] = s;
    } else {
        zp[(blk - 64) * 256 + threadIdx.x] = 0.f;
    }
}

// all weight transposes in one launch: out[c*R + r] = in[r*Cc + c]
struct TransJobs {
    const float* in[6];
    float* out[6];
    int R[6];
    int Cc[6];
};

__global__ void transpose_all_kernel(TransJobs tj) {
    int m = blockIdx.y;
    int i = blockIdx.x * 256 + threadIdx.x;
    int total = tj.R[m] * tj.Cc[m];
    if (i < total) {
        int r = i / tj.Cc[m], c = i % tj.Cc[m];
        tj.out[m][(size_t)c * tj.R[m] + r] = tj.in[m][i];
    }
}

// ------------------------------------------------ pairwise sq-dist (tiled gram)
// SYMMETRIC: only the 136 upper-triangular 128x128 block-pairs are computed;
// off-diagonal blocks emit the mirrored tile through a 32-row LDS transpose
// buffer (bitwise-identical values; 4 chunks x 2 barriers).
// LDS UNION (R11): staging (CT*272 floats) and the T mirror buffer (32*136)
// are never live at the same time (T first written after the K-loop's final
// barrier) -> one 17.4 KB buffer instead of 34.8 KB => 3 blocks/CU.
// Main loop is the R8 single-buffer form — FROZEN. History:
//   (256,3)/(256,4)  -> accumulator spills to scratch (R5 18x traffic, R6 +270MB)
//   reg prefetch     -> +32 VGPR, occupancy 27->20%, net loss (R7)
//   LDS double-buffer-> VGPR 128, spill, 1.49 GB traffic, 350 us (R9)
// launch_bounds(256,2), plain k-loop, VGPR~68, WRITE exactly 131 MB is the
// verified spill-free optimum. DO NOT add register pressure to this loop.

template<int C>
__global__ __launch_bounds__(256, 2)
void gram_dist_kernel(const float* __restrict__ x, const float* __restrict__ xx,
                      float* __restrict__ dist, int b0, size_t dstride) {
    constexpr int CT = (C < 16) ? C : 16;
    constexpr int SM_FLOATS = (CT * 272 > 32 * 136) ? CT * 272 : 32 * 136;
    const int b = b0 + blockIdx.z;
    // decode upper-tri pair index -> (rblk, cblk), rblk <= cblk, 16x16 tiles
    int p = blockIdx.x, rblk = 0;
    while (p >= 16 - rblk) { p -= 16 - rblk; ++rblk; }
    const int cblk = rblk + p;
    const int i0 = rblk * 128, j0 = cblk * 128;
    const int tid = threadIdx.x;
    const int tx = tid & 15, ty = tid >> 4;
    __shared__ float smem[SM_FLOATS];
    float (*As)[136] = (float (*)[136])smem;
    float (*BsA)[68] = (float (*)[68])(smem + (size_t)CT * 136);
    float (*BsB)[68] = (float (*)[68])(smem + (size_t)CT * 136 + (size_t)CT * 68);
    float (*T)[136]  = (float (*)[136])smem;   // aliases staging; used post-loop only
    float acc[8][8] = {};
    const float* xb = x + (size_t)b * Nn * C;

    const int si = tid & 127;         // staging row
    const int half = tid >> 7;        // 0..1
    float* bbase = ((si & 4) ? &BsB[0][0] : &BsA[0][0]) + (((si >> 3) << 2) | (si & 3));

    for (int c0 = 0; c0 < C; c0 += CT) {
        if constexpr (CT == 16) {
            const float* ra = xb + (size_t)(i0 + si) * C + c0 + half * 8;
            const float* rb = xb + (size_t)(j0 + si) * C + c0 + half * 8;
            float4 a0 = *(const float4*)ra;
            float4 a1 = *(const float4*)(ra + 4);
            float4 bq0 = *(const float4*)rb;
            float4 bq1 = *(const float4*)(rb + 4);
            const int cb = half * 8;
            As[cb + 0][si] = a0.x; As[cb + 1][si] = a0.y;
            As[cb + 2][si] = a0.z; As[cb + 3][si] = a0.w;
            As[cb + 4][si] = a1.x; As[cb + 5][si] = a1.y;
            As[cb + 6][si] = a1.z; As[cb + 7][si] = a1.w;
            bbase[(cb + 0) * 68] = bq0.x; bbase[(cb + 1) * 68] = bq0.y;
            bbase[(cb + 2) * 68] = bq0.z; bbase[(cb + 3) * 68] = bq0.w;
            bbase[(cb + 4) * 68] = bq1.x; bbase[(cb + 5) * 68] = bq1.y;
            bbase[(cb + 6) * 68] = bq1.z; bbase[(cb + 7) * 68] = bq1.w;
        } else {
            if (half == 0) {
                const float* r0 = xb + (size_t)(i0 + si) * C + c0;
#pragma unroll
                for (int c = 0; c < CT; ++c) As[c][si] = r0[c];
            } else {
                const float* r1 = xb + (size_t)(j0 + si) * C + c0;
#pragma unroll
                for (int c = 0; c < CT; ++c) bbase[c * 68] = r1[c];
            }
        }
        __syncthreads();
#pragma unroll
        for (int cc = 0; cc < CT; ++cc) {
            float a[8], bv[8];
            *(float4*)&a[0]  = *(const float4*)&As[cc][ty * 8];
            *(float4*)&a[4]  = *(const float4*)&As[cc][ty * 8 + 4];
            *(float4*)&bv[0] = *(const float4*)&BsA[cc][tx * 4];
            *(float4*)&bv[4] = *(const float4*)&BsB[cc][tx * 4];
#pragma unroll
            for (int u = 0; u < 8; ++u)
#pragma unroll
                for (int v = 0; v < 8; ++v)
                    acc[u][v] = fmaf(a[u], bv[v], acc[u][v]);
        }
        __syncthreads();
    }

    const float* xxb = xx + (size_t)b * Nn;
    float xi[8], xj[8];
#pragma unroll
    for (int u = 0; u < 8; ++u) xi[u] = xxb[i0 + ty * 8 + u];
#pragma unroll
    for (int v = 0; v < 8; ++v) xj[v] = xxb[j0 + tx * 8 + v];
    float* db = dist + (size_t)blockIdx.z * dstride;
#pragma unroll
    for (int u = 0; u < 8; ++u) {
        float* row = db + (size_t)(i0 + ty * 8 + u) * Nn + (j0 + tx * 8);
        float4 o0, o1;
        o0.x = xi[u] + xj[0] - 2.f * acc[u][0];
        o0.y = xi[u] + xj[1] - 2.f * acc[u][1];
        o0.z = xi[u] + xj[2] - 2.f * acc[u][2];
        o0.w = xi[u] + xj[3] - 2.f * acc[u][3];
        o1.x = xi[u] + xj[4] - 2.f * acc[u][4];
        o1.y = xi[u] + xj[5] - 2.f * acc[u][5];
        o1.z = xi[u] + xj[6] - 2.f * acc[u][6];
        o1.w = xi[u] + xj[7] - 2.f * acc[u][7];
        *(float4*)row = o0;
        *(float4*)(row + 4) = o1;
    }

    if (cblk > rblk) {
        // mirror tile (j0.., i0..): value(row=j0+tx*8+v, col=i0+ty*8+u)
        //   = xj[v] + xi[u] - 2*acc[u][v]  (bitwise equal to main tile)
        // 4 chunks of 32 rows; 64 writer-threads per chunk, 8 barriers total.
        const int rr = tid >> 3;            // 0..31 row within 32-row chunk
        const int c4 = (tid & 7) * 4;       // col base (float4 granularity)
#pragma unroll 1
        for (int m = 0; m < 4; ++m) {
            if ((tx >> 2) == m) {
                const int lr = (tx & 3) * 8;
#pragma unroll
                for (int v = 0; v < 8; ++v)
#pragma unroll
                    for (int u = 0; u < 8; ++u)
                        T[lr + v][ty * 8 + u] = xj[v] + xi[u] - 2.f * acc[u][v];
            }
            __syncthreads();
            float* orow = db + (size_t)(j0 + m * 32 + rr) * Nn + i0;
#pragma unroll
            for (int s = 0; s < 4; ++s)
                *(float4*)(orow + c4 + s * 32) = *(const float4*)&T[rr][c4 + s * 32];
            __syncthreads();
        }
    }
}

// ------------------------------------------------------- top-k (k=20 smallest)

__device__ __forceinline__ bool lex_less(float v1, int j1, float v2, int j2) {
    return v1 < v2 || (v1 == v2 && j1 < j2);
}

#define TOP4_INSERT(v, j, s)                                                      \
    if (lex_less(v, j, tv3, tj3)) {                                               \
        tv3 = v; tj3 = j; ts3 = s;                                                \
        if (lex_less(tv3, tj3, tv2, tj2)) {                                       \
            float fv = tv2; int fj = tj2, fs = ts2;                               \
            tv2 = tv3; tj2 = tj3; ts2 = ts3; tv3 = fv; tj3 = fj; ts3 = fs;        \
        }                                                                         \
        if (lex_less(tv2, tj2, tv1, tj1)) {                                       \
            float fv = tv1; int fj = tj1, fs = ts1;                               \
            tv1 = tv2; tj1 = tj2; ts1 = ts2; tv2 = fv; tj2 = fj; ts2 = fs;        \
        }                                                                         \
        if (lex_less(tv1, tj1, tv0, tj0)) {                                       \
            float fv = tv0; int fj = tj0, fs = ts0;                               \
            tv0 = tv1; tj0 = tj1; ts0 = ts1; tv1 = fv; tj1 = fj; ts1 = fs;        \
        }                                                                         \
    }

__device__ __forceinline__ void top4_build(const float4* __restrict__ dr4, int lane,
                                           unsigned xmask,
                                           float& tv0, int& tj0, int& ts0,
                                           float& tv1, int& tj1, int& ts1,
                                           float& tv2, int& tj2, int& ts2,
                                           float& tv3, int& tj3, int& ts3) {
    tv0 = tv1 = tv2 = tv3 = 3e38f;
    tj0 = tj1 = tj2 = tj3 = 1 << 30;
    ts0 = ts1 = ts2 = ts3 = 0;
#pragma unroll
    for (int q = 0; q < 8; ++q) {
        float4 f = dr4[q * 64 + lane];
        float vv[4] = {f.x, f.y, f.z, f.w};
#pragma unroll
        for (int c = 0; c < 4; ++c) {
            int s = q * 4 + c;
            if ((xmask >> s) & 1u) continue;
            int j = (q * 64 + lane) * 4 + c;
            float v = vv[c];
            TOP4_INSERT(v, j, s)
        }
    }
}

__global__ void topk_kernel(const float* __restrict__ dist, int* __restrict__ idxo,
                            int b0, size_t dstride, int rows_per_batch_only) {
    const int w = threadIdx.x >> 6;
    const int lane = threadIdx.x & 63;
    const int lin = blockIdx.x * 4 + w;
    int bz, i;
    if (rows_per_batch_only) { bz = 0; i = lin; }
    else { bz = lin >> 11; i = lin & (Nn - 1); }
    const int b = b0 + bz;
    const float4* dr4 = (const float4*)(dist + (size_t)bz * dstride + (size_t)i * Nn);

    float tv0, tv1, tv2, tv3;
    int tj0, tj1, tj2, tj3, ts0, ts1, ts2, ts3;
    unsigned xmask = 0;
    top4_build(dr4, lane, 0u, tv0, tj0, ts0, tv1, tj1, ts1, tv2, tj2, ts2, tv3, tj3, ts3);
    int cnt = 0;

    int* orow = idxo + ((size_t)b * Nn + i) * Kn;
    for (int t = 0; t < Kn; ++t) {
        float bv = tv0; int bj = tj0;
#pragma unroll
        for (int off = 1; off < 64; off <<= 1) {
            float ov = __shfl_xor(bv, off);
            int oj = __shfl_xor(bj, off);
            if (lex_less(ov, oj, bv, bj)) { bv = ov; bj = oj; }
        }
        if (lane == 0) orow[t] = bj;
        if (tj0 == bj) {
            xmask |= 1u << ts0;
            tv0 = tv1; tj0 = tj1; ts0 = ts1;
            tv1 = tv2; tj1 = tj2; ts1 = ts2;
            tv2 = tv3; tj2 = tj3; ts2 = ts3;
            tv3 = 3e38f; tj3 = 1 << 30; ts3 = 0;
            if (++cnt == 4) {
                top4_build(dr4, lane, xmask, tv0, tj0, ts0, tv1, tj1, ts1,
                           tv2, tj2, ts2, tv3, tj3, ts3);
                cnt = 0;
            }
        }
    }
}

// -------- layer-1 fused top-k: dist computed inline (C=3, X is L1-resident).
// FMA chain shape matches gram's CT=3 path exactly (acc=fmaf(a,b,acc) over
// increasing c, then xx_i + xx_j - 2.f*acc) -> same values, same selection.

__device__ __forceinline__ void top4_build_c3(const float* __restrict__ xb,
                                              const float* __restrict__ xxb,
                                              float xi0, float xi1, float xi2, float xxi,
                                              int lane, unsigned xmask,
                                              float& tv0, int& tj0, int& ts0,
                                              float& tv1, int& tj1, int& ts1,
                                              float& tv2, int& tj2, int& ts2,
                                              float& tv3, int& tj3, int& ts3) {
    tv0 = tv1 = tv2 = tv3 = 3e38f;
    tj0 = tj1 = tj2 = tj3 = 1 << 30;
    ts0 = ts1 = ts2 = ts3 = 0;
#pragma unroll
    for (int q = 0; q < 8; ++q) {
#pragma unroll
        for (int c = 0; c < 4; ++c) {
            int s = q * 4 + c;
            if ((xmask >> s) & 1u) continue;
            int j = (q * 64 + lane) * 4 + c;
            const float* xr = xb + (size_t)j * 3;
            float acc = 0.f;
            acc = fmaf(xi0, xr[0], acc);
            acc = fmaf(xi1, xr[1], acc);
            acc = fmaf(xi2, xr[2], acc);
            float v = xxi + xxb[j] - 2.f * acc;
            TOP4_INSERT(v, j, s)
        }
    }
}

__global__ void topk_c3_kernel(const float* __restrict__ x, const float* __restrict__ xx,
                               int* __restrict__ idxo, int b0, int rows_per_batch_only) {
    const int w = threadIdx.x >> 6;
    const int lane = threadIdx.x & 63;
    const int lin = blockIdx.x * 4 + w;
    int bz, i;
    if (rows_per_batch_only) { bz = 0; i = lin; }
    else { bz = lin >> 11; i = lin & (Nn - 1); }
    const int b = b0 + bz;
    const float* xb = x + (size_t)b * Nn * 3;
    const float* xxb = xx + (size_t)b * Nn;
    const float xi0 = xb[(size_t)i * 3];
    const float xi1 = xb[(size_t)i * 3 + 1];
    const float xi2 = xb[(size_t)i * 3 + 2];
    const float xxi = xxb[i];

    float tv0, tv1, tv2, tv3;
    int tj0, tj1, tj2, tj3, ts0, ts1, ts2, ts3;
    unsigned xmask = 0;
    top4_build_c3(xb, xxb, xi0, xi1, xi2, xxi, lane, 0u,
                  tv0, tj0, ts0, tv1, tj1, ts1, tv2, tj2, ts2, tv3, tj3, ts3);
    int cnt = 0;

    int* orow = idxo + ((size_t)b * Nn + i) * Kn;
    for (int t = 0; t < Kn; ++t) {
        float bv = tv0; int bj = tj0;
#pragma unroll
        for (int off = 1; off < 64; off <<= 1) {
            float ov = __shfl_xor(bv, off);
            int oj = __shfl_xor(bj, off);
            if (lex_less(ov, oj, bv, bj)) { bv = ov; bj = oj; }
        }
        if (lane == 0) orow[t] = bj;
        if (tj0 == bj) {
            xmask |= 1u << ts0;
            tv0 = tv1; tj0 = tj1; ts0 = ts1;
            tv1 = tv2; tj1 = tj2; ts1 = ts2;
            tv2 = tv3; tj2 = tj3; ts2 = ts3;
            tv3 = 3e38f; tj3 = 1 << 30; ts3 = 0;
            if (++cnt == 4) {
                top4_build_c3(xb, xxb, xi0, xi1, xi2, xxi, lane, xmask,
                              tv0, tj0, ts0, tv1, tj1, ts1, tv2, tj2, ts2, tv3, tj3, ts3);
                cnt = 0;
            }
        }
    }
}

// ------------------------------------- per-point projections Z1=X Wl^T, Z2=X Wr^T

template<int C, int O>
__global__ void z_kernel(const float* __restrict__ x, const float* __restrict__ wt,
                         float* __restrict__ z1, float* __restrict__ z2) {
    constexpr int TP = 16;
    constexpr int G = 256 / O;
    constexpr int PP = TP / G;
    const int p0 = blockIdx.x * TP;
    const int tid = threadIdx.x;
    const int oo = tid % O;
    const int g = tid / O;
    __shared__ float xs[TP][(C < 4) ? 4 : C];
    for (int e = tid; e < TP * C; e += 256) {
        int p = e / C, c = e % C;
        xs[p][c] = x[(size_t)(p0 + p) * C + c];
    }
    __syncthreads();
    float a1[PP], a2[PP];
#pragma unroll
    for (int p = 0; p < PP; ++p) { a1[p] = 0.f; a2[p] = 0.f; }
    if constexpr (C % 4 == 0) {
        for (int c = 0; c < C; c += 4) {
            float w1[4], w2[4];
#pragma unroll
            for (int q = 0; q < 4; ++q) {
                w1[q] = wt[(size_t)(c + q) * O + oo];
                w2[q] = wt[(size_t)(C + c + q) * O + oo];
            }
#pragma unroll
            for (int p = 0; p < PP; ++p) {
                const float4 xv = *(const float4*)(&xs[g * PP + p][c]);
                a1[p] = fmaf(xv.w, w1[3], fmaf(xv.z, w1[2], fmaf(xv.y, w1[1], fmaf(xv.x, w1[0], a1[p]))));
                a2[p] = fmaf(xv.w, w2[3], fmaf(xv.z, w2[2], fmaf(xv.y, w2[1], fmaf(xv.x, w2[0], a2[p]))));
            }
        }
    } else {
        for (int c = 0; c < C; ++c) {
            float w1 = wt[(size_t)c * O + oo];
            float w2 = wt[(size_t)(C + c) * O + oo];
#pragma unroll
            for (int p = 0; p < PP; ++p) {
                float xv = xs[g * PP + p][c];
                a1[p] = fmaf(xv, w1, a1[p]);
                a2[p] = fmaf(xv, w2, a2[p]);
            }
        }
    }
#pragma unroll
    for (int p = 0; p < PP; ++p) {
        size_t row = (size_t)(p0 + g * PP + p) * O + oo;
        z1[row] = a1[p];
        z2[row] = a2[p];
    }
}

// -------------------- gather edges, max/min over k + BN partial sums
// float4 per thread; each gathered row = one coalesced wave transaction.

template<int O>
__global__ void edge_stats_kernel(const float* __restrict__ z1, const float* __restrict__ z2,
                                  const int* __restrict__ idx,
                                  float* __restrict__ vmax, float* __restrict__ vmin,
                                  float* __restrict__ ssum, float* __restrict__ ssq) {
    constexpr int TPP = O / 4;           // threads per point
    constexpr int PPB = 256 / TPP;       // points per block
    const int p0 = blockIdx.x * PPB;
    const int tid = threadIdx.x;
    const int q = tid % TPP;
    const int p = tid / TPP;
    const int oo = q * 4;
    __shared__ int jl[PPB][Kn];
    for (int e = tid; e < PPB * Kn; e += 256)
        jl[e / Kn][e % Kn] = idx[(size_t)(p0 + e / Kn) * Kn + (e % Kn)];
    __syncthreads();
    const int bi = p0 + p;
    const int b = bi >> 11;
    const float4 zi1 = *(const float4*)(z1 + (size_t)bi * O + oo);
    const float4 zi2 = *(const float4*)(z2 + (size_t)bi * O + oo);
    float ax = zi2.x - zi1.x, ay = zi2.y - zi1.y, az = zi2.z - zi1.z, aw = zi2.w - zi1.w;
    float mxx = -3e38f, mxy = -3e38f, mxz = -3e38f, mxw = -3e38f;
    float mnx = 3e38f, mny = 3e38f, mnz = 3e38f, mnw = 3e38f;
    float sx = 0.f, sy = 0.f, sz = 0.f, sw = 0.f;
    float qx = 0.f, qy = 0.f, qz = 0.f, qw = 0.f;
    const float* zbase = z1 + ((size_t)b * Nn) * O + oo;
#pragma unroll
    for (int kk = 0; kk < Kn; ++kk) {
        int j = jl[p][kk];
        float4 v = *(const float4*)(zbase + (size_t)j * O);
        v.x += ax; v.y += ay; v.z += az; v.w += aw;
        mxx = fmaxf(mxx, v.x); mxy = fmaxf(mxy, v.y); mxz = fmaxf(mxz, v.z); mxw = fmaxf(mxw, v.w);
        mnx = fminf(mnx, v.x); mny = fminf(mny, v.y); mnz = fminf(mnz, v.z); mnw = fminf(mnw, v.w);
        sx += v.x; sy += v.y; sz += v.z; sw += v.w;
        qx = fmaf(v.x, v.x, qx); qy = fmaf(v.y, v.y, qy);
        qz = fmaf(v.z, v.z, qz); qw = fmaf(v.w, v.w, qw);
    }
    float4 mx4 = make_float4(mxx, mxy, mxz, mxw);
    float4 mn4 = make_float4(mnx, mny, mnz, mnw);
    *(float4*)(vmax + (size_t)bi * O + oo) = mx4;
    *(float4*)(vmin + (size_t)bi * O + oo) = mn4;
    __shared__ float4 ssm[256], sqq[256];
    ssm[tid] = make_float4(sx, sy, sz, sw);
    sqq[tid] = make_float4(qx, qy, qz, qw);
    __syncthreads();
    if (p == 0) {
#pragma unroll 4
        for (int pp = 1; pp < PPB; ++pp) {
            float4 s4 = ssm[pp * TPP + q];
            float4 q4 = sqq[pp * TPP + q];
            sx += s4.x; sy += s4.y; sz += s4.z; sw += s4.w;
            qx += q4.x; qy += q4.y; qz += q4.z; qw += q4.w;
        }
        int slot = blockIdx.x & 63;
        atomicAdd(&ssum[slot * O + oo + 0], sx);
        atomicAdd(&ssum[slot * O + oo + 1], sy);
        atomicAdd(&ssum[slot * O + oo + 2], sz);
        atomicAdd(&ssum[slot * O + oo + 3], sw);
        atomicAdd(&ssq[slot * O + oo + 0], qx);
        atomicAdd(&ssq[slot * O + oo + 1], qy);
        atomicAdd(&ssq[slot * O + oo + 2], qz);
        atomicAdd(&ssq[slot * O + oo + 3], qw);
    }
}

__global__ void bn_finalize_kernel(const float* __restrict__ ssum, const float* __restrict__ ssq,
                                   const float* __restrict__ gamma, const float* __restrict__ beta,
                                   float* __restrict__ scale, float* __restrict__ shift, int O) {
    int o = threadIdx.x;
    if (o >= O) return;
    float s = 0.f, q = 0.f;
    for (int sl = 0; sl < 64; ++sl) { s += ssum[sl * O + o]; q += ssq[sl * O + o]; }
    const float cnt = (float)Bb * (float)Nn * (float)Kn;
    float mu = s / cnt;
    float var = q / cnt - mu * mu;
    float sc = gamma[o] / sqrtf(var + EPSV);
    scale[o] = sc;
    shift[o] = beta[o] - mu * sc;
}

// ---------------- BN-apply + relu + per-chunk pooling partials (float4)

template<int O>
__global__ void apply_pool_kernel(const float* __restrict__ vmax, const float* __restrict__ vmin,
                                  const float* __restrict__ scale, const float* __restrict__ shift,
                                  float* __restrict__ xout,
                                  float* __restrict__ pmax, float* __restrict__ psum, int obase) {
    constexpr int TPP = O / 4;
    constexpr int PP2 = 256 / TPP;      // points concurrent
    constexpr int S = 128 / PP2;        // iterations
    const int chunk = blockIdx.x;
    const int b = blockIdx.y;
    const int tid = threadIdx.x;
    const int q = tid % TPP;
    const int g = tid / TPP;
    const int oo = q * 4;
    const float4 sc = *(const float4*)(scale + oo);
    const float4 sh = *(const float4*)(shift + oo);
    float pmx = -3e38f, pmy = -3e38f, pmz = -3e38f, pmw = -3e38f;
    float psx = 0.f, psy = 0.f, psz = 0.f, psw = 0.f;
    const int n0 = chunk * 128;
    for (int s = 0; s < S; ++s) {
        int n = n0 + g + s * PP2;
        size_t ix = ((size_t)b * Nn + n) * O + oo;
        float4 vx = *(const float4*)(vmax + ix);
        float4 vn = *(const float4*)(vmin + ix);
        float4 r;
        r.x = fmaxf(fmaf(sc.x >= 0.f ? vx.x : vn.x, sc.x, sh.x), 0.f);
        r.y = fmaxf(fmaf(sc.y >= 0.f ? vx.y : vn.y, sc.y, sh.y), 0.f);
        r.z = fmaxf(fmaf(sc.z >= 0.f ? vx.z : vn.z, sc.z, sh.z), 0.f);
        r.w = fmaxf(fmaf(sc.w >= 0.f ? vx.w : vn.w, sc.w, sh.w), 0.f);
        *(float4*)(xout + ix) = r;
        pmx = fmaxf(pmx, r.x); pmy = fmaxf(pmy, r.y);
        pmz = fmaxf(pmz, r.z); pmw = fmaxf(pmw, r.w);
        psx += r.x; psy += r.y; psz += r.z; psw += r.w;
    }
    __shared__ float4 sm[256], ss2[256];
    sm[tid] = make_float4(pmx, pmy, pmz, pmw);
    ss2[tid] = make_float4(psx, psy, psz, psw);
    __syncthreads();
    if (g == 0) {
#pragma unroll 4
        for (int gg = 1; gg < PP2; ++gg) {
            float4 m4 = sm[gg * TPP + q];
            float4 s4 = ss2[gg * TPP + q];
            pmx = fmaxf(pmx, m4.x); pmy = fmaxf(pmy, m4.y);
            pmz = fmaxf(pmz, m4.z); pmw = fmaxf(pmw, m4.w);
            psx += s4.x; psy += s4.y; psz += s4.z; psw += s4.w;
        }
        size_t pb = ((size_t)b * 16 + chunk) * 512 + obase + oo;
        *(float4*)(pmax + pb) = make_float4(pmx, pmy, pmz, pmw);
        *(float4*)(psum + pb) = make_float4(psx, psy, psz, psw);
    }
}

__global__ void pool_finalize_kernel(const float* __restrict__ pmax, const float* __restrict__ psum,
                                     float* __restrict__ gv) {
    const int b = blockIdx.x;
    const int c = threadIdx.x;          // 512 threads
    float mx = -3e38f, s = 0.f;
    for (int ch = 0; ch < 16; ++ch) {
        size_t p = ((size_t)b * 16 + ch) * 512 + c;
        mx = fmaxf(mx, pmax[p]);
        s += psum[p];
    }
    gv[b * 1024 + c] = mx;
    gv[b * 1024 + 512 + c] = s * (1.f / (float)Nn);
}

// ------------------------------------------------------------------- MLP head

__global__ void head_kernel(const float* __restrict__ gv,
                            const float* __restrict__ fct1, const float* __restrict__ fc1b,
                            const float* __restrict__ ln1g, const float* __restrict__ ln1b,
                            const float* __restrict__ fct2, const float* __restrict__ fc2b,
                            const float* __restrict__ ln2g, const float* __restrict__ ln2b,
                            float* __restrict__ out) {
    const int b = blockIdx.x;
    const int tid = threadIdx.x;
    __shared__ float gx[1024];
    __shared__ float hh[512];
    __shared__ float red[256];
    for (int e = tid; e < 1024; e += 256) gx[e] = gv[b * 1024 + e];
    __syncthreads();
    float h0 = fc1b[tid], h1 = fc1b[tid + 256];
    for (int c = 0; c < 1024; ++c) {
        float gc = gx[c];
        h0 = fmaf(gc, fct1[(size_t)c * 512 + tid], h0);
        h1 = fmaf(gc, fct1[(size_t)c * 512 + tid + 256], h1);
    }
    red[tid] = h0 + h1;
    __syncthreads();
    for (int st = 128; st > 0; st >>= 1) { if (tid < st) red[tid] += red[tid + st]; __syncthreads(); }
    float mu = red[0] * (1.f / 512.f);
    __syncthreads();
    float d0 = h0 - mu, d1 = h1 - mu;
    red[tid] = d0 * d0 + d1 * d1;
    __syncthreads();
    for (int st = 128; st > 0; st >>= 1) { if (tid < st) red[tid] += red[tid + st]; __syncthreads(); }
    float rs = 1.f / sqrtf(red[0] * (1.f / 512.f) + EPSV);
    __syncthreads();
    hh[tid]       = fmaxf(d0 * rs * ln1g[tid] + ln1b[tid], 0.f);
    hh[tid + 256] = fmaxf(d1 * rs * ln1g[tid + 256] + ln1b[tid + 256], 0.f);
    __syncthreads();
    float z = fc2b[tid];
    for (int c = 0; c < 512; ++c) z = fmaf(hh[c], fct2[(size_t)c * 256 + tid], z);
    red[tid] = z;
    __syncthreads();
    for (int st = 128; st > 0; st >>= 1) { if (tid < st) red[tid] += red[tid + st]; __syncthreads(); }
    float mu2 = red[0] * (1.f / 256.f);
    __syncthreads();
    float dz = z - mu2;
    red[tid] = dz * dz;
    __syncthreads();
    for (int st = 128; st > 0; st >>= 1) { if (tid < st) red[tid] += red[tid + st]; __syncthreads(); }
    float rs2 = 1.f / sqrtf(red[0] * (1.f / 256.f) + EPSV);
    out[b * 256 + tid] = dz * rs2 * ln2g[tid] + ln2b[tid];
}

// --------------------------------------------------------------- layer driver

template<int C, int O>
static void run_layer(const float* x, const float* gamma, const float* beta,
                      float* xout, float* DIST, float* XX, int* IDX, float* Z1, float* Z2,
                      float* VMX, float* VMN, float* SSUM, float* SSQ, float* BNS, float* BNB,
                      const float* WT, float* PMAX, float* PSUM, int obase, bool big,
                      hipStream_t stream) {
    sqnorm_zero_kernel<<<192, 256, 0, stream>>>(x, XX, C, SSUM);  // SSUM+SSQ contiguous 32K
    z_kernel<C, O><<<Bb * Nn / 16, 256, 0, stream>>>(x, WT, Z1, Z2);
    if constexpr (C == 3) {
        // layer 1: X is L1-resident (24 KB/batch) -> fused inline-dist top-k,
        // no gram dispatch, no DIST write+read.
        if (big) {
            topk_c3_kernel<<<Bb * Nn / 4, 256, 0, stream>>>(x, XX, IDX, 0, 0);
        } else {
            for (int b = 0; b < Bb; ++b)
                topk_c3_kernel<<<Nn / 4, 256, 0, stream>>>(x, XX, IDX, b, 1);
        }
    } else {
        if (big) {
            gram_dist_kernel<C><<<dim3(136, 1, Bb), 256, 0, stream>>>(x, XX, DIST, 0, (size_t)Nn * Nn);
            topk_kernel<<<Bb * Nn / 4, 256, 0, stream>>>(DIST, IDX, 0, (size_t)Nn * Nn, 0);
        } else {
            for (int b = 0; b < Bb; ++b) {
                gram_dist_kernel<C><<<dim3(136, 1, 1), 256, 0, stream>>>(x, XX, DIST, b, 0);
                topk_kernel<<<Nn / 4, 256, 0, stream>>>(DIST, IDX, b, 0, 1);
            }
        }
    }
    edge_stats_kernel<O><<<Bb * Nn / (1024 / O), 256, 0, stream>>>(Z1, Z2, IDX, VMX, VMN, SSUM, SSQ);
    bn_finalize_kernel<<<1, 256, 0, stream>>>(SSUM, SSQ, gamma, beta, BNS, BNB, O);
    apply_pool_kernel<O><<<dim3(16, 8), 256, 0, stream>>>(VMX, VMN, BNS, BNB, xout, PMAX, PSUM, obase);
}

extern "C" void kernel_launch(void* const* d_in, const int* in_sizes, int n_in,
                              void* d_out, int out_size, void* d_ws, size_t ws_size,
                              hipStream_t stream) {
    const float* points = (const float*)d_in[0];
    const float* W1 = (const float*)d_in[1];
    const float* g1 = (const float*)d_in[2];
    const float* b1 = (const float*)d_in[3];
    const float* W2 = (const float*)d_in[4];
    const float* g2 = (const float*)d_in[5];
    const float* b2 = (const float*)d_in[6];
    const float* W3 = (const float*)d_in[7];
    const float* g3 = (const float*)d_in[8];
    const float* b3 = (const float*)d_in[9];
    const float* W4 = (const float*)d_in[10];
    const float* g4 = (const float*)d_in[11];
    const float* b4 = (const float*)d_in[12];
    const float* fc1_w = (const float*)d_in[13];
    const float* fc1_b = (const float*)d_in[14];
    const float* ln1g = (const float*)d_in[15];
    const float* ln1b = (const float*)d_in[16];
    const float* fc2_w = (const float*)d_in[17];
    const float* fc2_b = (const float*)d_in[18];
    const float* ln2g = (const float*)d_in[19];
    const float* ln2b = (const float*)d_in[20];

    float* ws = (float*)d_ws;
    const size_t BN = (size_t)Bb * Nn;
    const bool big = ws_size >= (size_t)59826688 * 4;

    size_t off = 0;
    auto take = [&](size_t n) { size_t o = off; off += n; return o; };
    float* DIST = ws + take(big ? (size_t)Bb * Nn * Nn : (size_t)Nn * Nn);
    float* XX   = ws + take(BN);
    int*   IDX  = (int*)(ws + take(BN * Kn));
    float* Z1   = ws + take(BN * 256);
    float* Z2   = ws + take(BN * 256);
    float* VMX  = ws + take(BN * 256);
    float* VMN  = ws + take(BN * 256);
    float* SSUM = ws + take(64 * 256);
    float* SSQ  = ws + take(64 * 256);
    float* BNS  = ws + take(256);
    float* BNB  = ws + take(256);
    float* WT1  = ws + take(384);
    float* WT2  = ws + take(8192);
    float* WT3  = ws + take(16384);
    float* WT4  = ws + take(65536);
    float* FCT1 = ws + take(524288);
    float* FCT2 = ws + take(131072);
    float* X1   = ws + take(BN * 64);
    float* X2   = ws + take(BN * 64);
    float* X3   = ws + take(BN * 128);
    float* X4   = ws + take(BN * 256);
    float* GV   = ws + take((size_t)Bb * 1024);
    float* PMAX = ws + take((size_t)Bb * 16 * 512);
    float* PSUM = ws + take((size_t)Bb * 16 * 512);

    // All weight transposes in one launch (independent of layer outputs).
    TransJobs tj;
    tj.in[0] = W1;    tj.out[0] = WT1;  tj.R[0] = 64;  tj.Cc[0] = 6;
    tj.in[1] = W2;    tj.out[1] = WT2;  tj.R[1] = 64;  tj.Cc[1] = 128;
    tj.in[2] = W3;    tj.out[2] = WT3;  tj.R[2] = 128; tj.Cc[2] = 128;
    tj.in[3] = W4;    tj.out[3] = WT4;  tj.R[3] = 256; tj.Cc[3] = 256;
    tj.in[4] = fc1_w; tj.out[4] = FCT1; tj.R[4] = 512; tj.Cc[4] = 1024;
    tj.in[5] = fc2_w; tj.out[5] = FCT2; tj.R[5] = 256; tj.Cc[5] = 512;
    transpose_all_kernel<<<dim3(2048, 6), 256, 0, stream>>>(tj);

    run_layer<3, 64>(points, g1, b1, X1, DIST, XX, IDX, Z1, Z2, VMX, VMN, SSUM, SSQ, BNS, BNB, WT1, PMAX, PSUM, 0, big, stream);
    run_layer<64, 64>(X1, g2, b2, X2, DIST, XX, IDX, Z1, Z2, VMX, VMN, SSUM, SSQ, BNS, BNB, WT2, PMAX, PSUM, 64, big, stream);
    run_layer<64, 128>(X2, g3, b3, X3, DIST, XX, IDX, Z1, Z2, VMX, VMN, SSUM, SSQ, BNS, BNB, WT3, PMAX, PSUM, 128, big, stream);
    run_layer<128, 256>(X3, g4, b4, X4, DIST, XX, IDX, Z1, Z2, VMX, VMN, SSUM, SSQ, BNS, BNB, WT4, PMAX, PSUM, 256, big, stream);

    pool_finalize_kernel<<<Bb, 512, 0, stream>>>(PMAX, PSUM, GV);
    head_kernel<<<Bb, 256, 0, stream>>>(GV, FCT1, fc1_b, ln1g, ln1b, FCT2, fc2_b, ln2g, ln2b,
                                        (float*)d_out);
}

// Round 12
// 885.461 us; speedup vs baseline: 1.6681x; 1.0214x over previous
//
#include <hip/hip_runtime.h>
#include <cstdint>
#include <cstddef>

static constexpr int Bb = 8;
static constexpr int Nn = 2048;
static constexpr int Kn = 20;
static constexpr float EPSV = 1e-5f;

// ---------------------------------------------------------------- utilities

// blocks 0..63: xx[i] = ||x_i||^2 (and packed (x,xx) float4 if xp != null);
// blocks 64..191: zero 32K floats of zp
__global__ void sqnorm_zero_kernel(const float* __restrict__ x, float* __restrict__ xx, int C,
                                   float* __restrict__ zp, float4* __restrict__ xp) {
    int blk = blockIdx.x;
    if (blk < 64) {
        int i = blk * 256 + threadIdx.x;
        const float* xr = x + (size_t)i * C;
        float s = 0.f;
        for (int c = 0; c < C; ++c) { float v = xr[c]; s += v * v; }
        xx[i] = s;
        if (xp) xp[i] = make_float4(xr[0], xr[1], xr[2], s);   // only used for C==3
    } else {
        zp[(blk - 64) * 256 + threadIdx.x] = 0.f;
    }
}

// all weight transposes in one launch: out[c*R + r] = in[r*Cc + c]
struct TransJobs {
    const float* in[6];
    float* out[6];
    int R[6];
    int Cc[6];
};

__global__ void transpose_all_kernel(TransJobs tj) {
    int m = blockIdx.y;
    int i = blockIdx.x * 256 + threadIdx.x;
    int total = tj.R[m] * tj.Cc[m];
    if (i < total) {
        int r = i / tj.Cc[m], c = i % tj.Cc[m];
        tj.out[m][(size_t)c * tj.R[m] + r] = tj.in[m][i];
    }
}

// ------------------------------------------------ pairwise sq-dist (tiled gram)
// SYMMETRIC: only the 136 upper-triangular 128x128 block-pairs are computed;
// off-diagonal blocks emit the mirrored tile through a 32-row LDS transpose
// buffer (bitwise-identical values; 4 chunks x 2 barriers).
// LDS UNION: staging (CT*272 floats) and the T mirror buffer (32*136) are
// never live at the same time -> one 17.4 KB buffer.
// Main loop is the R8 single-buffer form — FROZEN. History:
//   (256,3)/(256,4)  -> accumulator spills to scratch (R5 18x traffic, R6 +270MB)
//   reg prefetch     -> +32 VGPR, occupancy 27->20%, net loss (R7)
//   LDS double-buffer-> VGPR 128, spill, 1.49 GB traffic, 350 us (R9)
// launch_bounds(256,2), plain k-loop, VGPR~68, WRITE exactly 131 MB is the
// verified spill-free optimum. DO NOT add register pressure to this loop.

template<int C>
__global__ __launch_bounds__(256, 2)
void gram_dist_kernel(const float* __restrict__ x, const float* __restrict__ xx,
                      float* __restrict__ dist, int b0, size_t dstride) {
    constexpr int CT = (C < 16) ? C : 16;
    constexpr int SM_FLOATS = (CT * 272 > 32 * 136) ? CT * 272 : 32 * 136;
    const int b = b0 + blockIdx.z;
    // decode upper-tri pair index -> (rblk, cblk), rblk <= cblk, 16x16 tiles
    int p = blockIdx.x, rblk = 0;
    while (p >= 16 - rblk) { p -= 16 - rblk; ++rblk; }
    const int cblk = rblk + p;
    const int i0 = rblk * 128, j0 = cblk * 128;
    const int tid = threadIdx.x;
    const int tx = tid & 15, ty = tid >> 4;
    __shared__ float smem[SM_FLOATS];
    float (*As)[136] = (float (*)[136])smem;
    float (*BsA)[68] = (float (*)[68])(smem + (size_t)CT * 136);
    float (*BsB)[68] = (float (*)[68])(smem + (size_t)CT * 136 + (size_t)CT * 68);
    float (*T)[136]  = (float (*)[136])smem;   // aliases staging; used post-loop only
    float acc[8][8] = {};
    const float* xb = x + (size_t)b * Nn * C;

    const int si = tid & 127;         // staging row
    const int half = tid >> 7;        // 0..1
    float* bbase = ((si & 4) ? &BsB[0][0] : &BsA[0][0]) + (((si >> 3) << 2) | (si & 3));

    for (int c0 = 0; c0 < C; c0 += CT) {
        if constexpr (CT == 16) {
            const float* ra = xb + (size_t)(i0 + si) * C + c0 + half * 8;
            const float* rb = xb + (size_t)(j0 + si) * C + c0 + half * 8;
            float4 a0 = *(const float4*)ra;
            float4 a1 = *(const float4*)(ra + 4);
            float4 bq0 = *(const float4*)rb;
            float4 bq1 = *(const float4*)(rb + 4);
            const int cb = half * 8;
            As[cb + 0][si] = a0.x; As[cb + 1][si] = a0.y;
            As[cb + 2][si] = a0.z; As[cb + 3][si] = a0.w;
            As[cb + 4][si] = a1.x; As[cb + 5][si] = a1.y;
            As[cb + 6][si] = a1.z; As[cb + 7][si] = a1.w;
            bbase[(cb + 0) * 68] = bq0.x; bbase[(cb + 1) * 68] = bq0.y;
            bbase[(cb + 2) * 68] = bq0.z; bbase[(cb + 3) * 68] = bq0.w;
            bbase[(cb + 4) * 68] = bq1.x; bbase[(cb + 5) * 68] = bq1.y;
            bbase[(cb + 6) * 68] = bq1.z; bbase[(cb + 7) * 68] = bq1.w;
        } else {
            if (half == 0) {
                const float* r0 = xb + (size_t)(i0 + si) * C + c0;
#pragma unroll
                for (int c = 0; c < CT; ++c) As[c][si] = r0[c];
            } else {
                const float* r1 = xb + (size_t)(j0 + si) * C + c0;
#pragma unroll
                for (int c = 0; c < CT; ++c) bbase[c * 68] = r1[c];
            }
        }
        __syncthreads();
#pragma unroll
        for (int cc = 0; cc < CT; ++cc) {
            float a[8], bv[8];
            *(float4*)&a[0]  = *(const float4*)&As[cc][ty * 8];
            *(float4*)&a[4]  = *(const float4*)&As[cc][ty * 8 + 4];
            *(float4*)&bv[0] = *(const float4*)&BsA[cc][tx * 4];
            *(float4*)&bv[4] = *(const float4*)&BsB[cc][tx * 4];
#pragma unroll
            for (int u = 0; u < 8; ++u)
#pragma unroll
                for (int v = 0; v < 8; ++v)
                    acc[u][v] = fmaf(a[u], bv[v], acc[u][v]);
        }
        __syncthreads();
    }

    const float* xxb = xx + (size_t)b * Nn;
    float xi[8], xj[8];
#pragma unroll
    for (int u = 0; u < 8; ++u) xi[u] = xxb[i0 + ty * 8 + u];
#pragma unroll
    for (int v = 0; v < 8; ++v) xj[v] = xxb[j0 + tx * 8 + v];
    float* db = dist + (size_t)blockIdx.z * dstride;
#pragma unroll
    for (int u = 0; u < 8; ++u) {
        float* row = db + (size_t)(i0 + ty * 8 + u) * Nn + (j0 + tx * 8);
        float4 o0, o1;
        o0.x = xi[u] + xj[0] - 2.f * acc[u][0];
        o0.y = xi[u] + xj[1] - 2.f * acc[u][1];
        o0.z = xi[u] + xj[2] - 2.f * acc[u][2];
        o0.w = xi[u] + xj[3] - 2.f * acc[u][3];
        o1.x = xi[u] + xj[4] - 2.f * acc[u][4];
        o1.y = xi[u] + xj[5] - 2.f * acc[u][5];
        o1.z = xi[u] + xj[6] - 2.f * acc[u][6];
        o1.w = xi[u] + xj[7] - 2.f * acc[u][7];
        *(float4*)row = o0;
        *(float4*)(row + 4) = o1;
    }

    if (cblk > rblk) {
        // mirror tile (j0.., i0..): value(row=j0+tx*8+v, col=i0+ty*8+u)
        //   = xj[v] + xi[u] - 2*acc[u][v]  (bitwise equal to main tile)
        // 4 chunks of 32 rows; 64 writer-threads per chunk, 8 barriers total.
        const int rr = tid >> 3;            // 0..31 row within 32-row chunk
        const int c4 = (tid & 7) * 4;       // col base (float4 granularity)
#pragma unroll 1
        for (int m = 0; m < 4; ++m) {
            if ((tx >> 2) == m) {
                const int lr = (tx & 3) * 8;
#pragma unroll
                for (int v = 0; v < 8; ++v)
#pragma unroll
                    for (int u = 0; u < 8; ++u)
                        T[lr + v][ty * 8 + u] = xj[v] + xi[u] - 2.f * acc[u][v];
            }
            __syncthreads();
            float* orow = db + (size_t)(j0 + m * 32 + rr) * Nn + i0;
#pragma unroll
            for (int s = 0; s < 4; ++s)
                *(float4*)(orow + c4 + s * 32) = *(const float4*)&T[rr][c4 + s * 32];
            __syncthreads();
        }
    }
}

// ------------------------------------------------------- top-k (k=20 smallest)

__device__ __forceinline__ bool lex_less(float v1, int j1, float v2, int j2) {
    return v1 < v2 || (v1 == v2 && j1 < j2);
}

#define TOP4_INSERT(v, j, s)                                                      \
    if (lex_less(v, j, tv3, tj3)) {                                               \
        tv3 = v; tj3 = j; ts3 = s;                                                \
        if (lex_less(tv3, tj3, tv2, tj2)) {                                       \
            float fv = tv2; int fj = tj2, fs = ts2;                               \
            tv2 = tv3; tj2 = tj3; ts2 = ts3; tv3 = fv; tj3 = fj; ts3 = fs;        \
        }                                                                         \
        if (lex_less(tv2, tj2, tv1, tj1)) {                                       \
            float fv = tv1; int fj = tj1, fs = ts1;                               \
            tv1 = tv2; tj1 = tj2; ts1 = ts2; tv2 = fv; tj2 = fj; ts2 = fs;        \
        }                                                                         \
        if (lex_less(tv1, tj1, tv0, tj0)) {                                       \
            float fv = tv0; int fj = tj0, fs = ts0;                               \
            tv0 = tv1; tj0 = tj1; ts0 = ts1; tv1 = fv; tj1 = fj; ts1 = fs;        \
        }                                                                         \
    }

__device__ __forceinline__ void top4_build(const float4* __restrict__ dr4, int lane,
                                           unsigned xmask,
                                           float& tv0, int& tj0, int& ts0,
                                           float& tv1, int& tj1, int& ts1,
                                           float& tv2, int& tj2, int& ts2,
                                           float& tv3, int& tj3, int& ts3) {
    tv0 = tv1 = tv2 = tv3 = 3e38f;
    tj0 = tj1 = tj2 = tj3 = 1 << 30;
    ts0 = ts1 = ts2 = ts3 = 0;
#pragma unroll
    for (int q = 0; q < 8; ++q) {
        float4 f = dr4[q * 64 + lane];
        float vv[4] = {f.x, f.y, f.z, f.w};
#pragma unroll
        for (int c = 0; c < 4; ++c) {
            int s = q * 4 + c;
            if ((xmask >> s) & 1u) continue;
            int j = (q * 64 + lane) * 4 + c;
            float v = vv[c];
            TOP4_INSERT(v, j, s)
        }
    }
}

__global__ void topk_kernel(const float* __restrict__ dist, int* __restrict__ idxo,
                            int b0, size_t dstride, int rows_per_batch_only) {
    const int w = threadIdx.x >> 6;
    const int lane = threadIdx.x & 63;
    const int lin = blockIdx.x * 4 + w;
    int bz, i;
    if (rows_per_batch_only) { bz = 0; i = lin; }
    else { bz = lin >> 11; i = lin & (Nn - 1); }
    const int b = b0 + bz;
    const float4* dr4 = (const float4*)(dist + (size_t)bz * dstride + (size_t)i * Nn);

    float tv0, tv1, tv2, tv3;
    int tj0, tj1, tj2, tj3, ts0, ts1, ts2, ts3;
    unsigned xmask = 0;
    top4_build(dr4, lane, 0u, tv0, tj0, ts0, tv1, tj1, ts1, tv2, tj2, ts2, tv3, tj3, ts3);
    int cnt = 0;

    int* orow = idxo + ((size_t)b * Nn + i) * Kn;
    for (int t = 0; t < Kn; ++t) {
        float bv = tv0; int bj = tj0;
#pragma unroll
        for (int off = 1; off < 64; off <<= 1) {
            float ov = __shfl_xor(bv, off);
            int oj = __shfl_xor(bj, off);
            if (lex_less(ov, oj, bv, bj)) { bv = ov; bj = oj; }
        }
        if (lane == 0) orow[t] = bj;
        if (tj0 == bj) {
            xmask |= 1u << ts0;
            tv0 = tv1; tj0 = tj1; ts0 = ts1;
            tv1 = tv2; tj1 = tj2; ts1 = ts2;
            tv2 = tv3; tj2 = tj3; ts2 = ts3;
            tv3 = 3e38f; tj3 = 1 << 30; ts3 = 0;
            if (++cnt == 4) {
                top4_build(dr4, lane, xmask, tv0, tj0, ts0, tv1, tj1, ts1,
                           tv2, tj2, ts2, tv3, tj3, ts3);
                cnt = 0;
            }
        }
    }
}

// -------- layer-1 fused top-k: dist computed inline from packed (x,xx) float4.
// Candidate mapping j = m*64 + lane -> lane-adjacent candidates are consecutive
// float4s => one fully-coalesced 1KB wave load per step (R11's 4 scattered
// scalar loads were the 97us bottleneck). FMA chain shape matches gram's CT=3
// path exactly (acc=fmaf(a,b,acc) over increasing c, then xx_i+xx_j-2.f*acc)
// -> same values, same selection.

__device__ __forceinline__ void top4_build_c3(const float4* __restrict__ xpb,
                                              float xi0, float xi1, float xi2, float xxi,
                                              int lane, unsigned xmask,
                                              float& tv0, int& tj0, int& ts0,
                                              float& tv1, int& tj1, int& ts1,
                                              float& tv2, int& tj2, int& ts2,
                                              float& tv3, int& tj3, int& ts3) {
    tv0 = tv1 = tv2 = tv3 = 3e38f;
    tj0 = tj1 = tj2 = tj3 = 1 << 30;
    ts0 = ts1 = ts2 = ts3 = 0;
#pragma unroll
    for (int m = 0; m < 32; ++m) {
        if ((xmask >> m) & 1u) continue;
        int j = m * 64 + lane;
        float4 f = xpb[j];
        float acc = 0.f;
        acc = fmaf(xi0, f.x, acc);
        acc = fmaf(xi1, f.y, acc);
        acc = fmaf(xi2, f.z, acc);
        float v = xxi + f.w - 2.f * acc;
        TOP4_INSERT(v, j, m)
    }
}

__global__ void topk_c3_kernel(const float4* __restrict__ xp, int* __restrict__ idxo,
                               int b0, int rows_per_batch_only) {
    const int w = threadIdx.x >> 6;
    const int lane = threadIdx.x & 63;
    const int lin = blockIdx.x * 4 + w;
    int bz, i;
    if (rows_per_batch_only) { bz = 0; i = lin; }
    else { bz = lin >> 11; i = lin & (Nn - 1); }
    const int b = b0 + bz;
    const float4* xpb = xp + (size_t)b * Nn;
    const float4 fi = xpb[i];
    const float xi0 = fi.x, xi1 = fi.y, xi2 = fi.z, xxi = fi.w;

    float tv0, tv1, tv2, tv3;
    int tj0, tj1, tj2, tj3, ts0, ts1, ts2, ts3;
    unsigned xmask = 0;
    top4_build_c3(xpb, xi0, xi1, xi2, xxi, lane, 0u,
                  tv0, tj0, ts0, tv1, tj1, ts1, tv2, tj2, ts2, tv3, tj3, ts3);
    int cnt = 0;

    int* orow = idxo + ((size_t)b * Nn + i) * Kn;
    for (int t = 0; t < Kn; ++t) {
        float bv = tv0; int bj = tj0;
#pragma unroll
        for (int off = 1; off < 64; off <<= 1) {
            float ov = __shfl_xor(bv, off);
            int oj = __shfl_xor(bj, off);
            if (lex_less(ov, oj, bv, bj)) { bv = ov; bj = oj; }
        }
        if (lane == 0) orow[t] = bj;
        if (tj0 == bj) {
            xmask |= 1u << ts0;
            tv0 = tv1; tj0 = tj1; ts0 = ts1;
            tv1 = tv2; tj1 = tj2; ts1 = ts2;
            tv2 = tv3; tj2 = tj3; ts2 = ts3;
            tv3 = 3e38f; tj3 = 1 << 30; ts3 = 0;
            if (++cnt == 4) {
                top4_build_c3(xpb, xi0, xi1, xi2, xxi, lane, xmask,
                              tv0, tj0, ts0, tv1, tj1, ts1, tv2, tj2, ts2, tv3, tj3, ts3);
                cnt = 0;
            }
        }
    }
}

// ------------------------------------- per-point projections Z1=X Wl^T, Z2=X Wr^T

template<int C, int O>
__global__ void z_kernel(const float* __restrict__ x, const float* __restrict__ wt,
                         float* __restrict__ z1, float* __restrict__ z2) {
    constexpr int TP = 16;
    constexpr int G = 256 / O;
    constexpr int PP = TP / G;
    const int p0 = blockIdx.x * TP;
    const int tid = threadIdx.x;
    const int oo = tid % O;
    const int g = tid / O;
    __shared__ float xs[TP][(C < 4) ? 4 : C];
    for (int e = tid; e < TP * C; e += 256) {
        int p = e / C, c = e % C;
        xs[p][c] = x[(size_t)(p0 + p) * C + c];
    }
    __syncthreads();
    float a1[PP], a2[PP];
#pragma unroll
    for (int p = 0; p < PP; ++p) { a1[p] = 0.f; a2[p] = 0.f; }
    if constexpr (C % 4 == 0) {
        for (int c = 0; c < C; c += 4) {
            float w1[4], w2[4];
#pragma unroll
            for (int q = 0; q < 4; ++q) {
                w1[q] = wt[(size_t)(c + q) * O + oo];
                w2[q] = wt[(size_t)(C + c + q) * O + oo];
            }
#pragma unroll
            for (int p = 0; p < PP; ++p) {
                const float4 xv = *(const float4*)(&xs[g * PP + p][c]);
                a1[p] = fmaf(xv.w, w1[3], fmaf(xv.z, w1[2], fmaf(xv.y, w1[1], fmaf(xv.x, w1[0], a1[p]))));
                a2[p] = fmaf(xv.w, w2[3], fmaf(xv.z, w2[2], fmaf(xv.y, w2[1], fmaf(xv.x, w2[0], a2[p]))));
            }
        }
    } else {
        for (int c = 0; c < C; ++c) {
            float w1 = wt[(size_t)c * O + oo];
            float w2 = wt[(size_t)(C + c) * O + oo];
#pragma unroll
            for (int p = 0; p < PP; ++p) {
                float xv = xs[g * PP + p][c];
                a1[p] = fmaf(xv, w1, a1[p]);
                a2[p] = fmaf(xv, w2, a2[p]);
            }
        }
    }
#pragma unroll
    for (int p = 0; p < PP; ++p) {
        size_t row = (size_t)(p0 + g * PP + p) * O + oo;
        z1[row] = a1[p];
        z2[row] = a2[p];
    }
}

// -------------------- gather edges, max/min over k + BN partial sums
// float4 per thread; each gathered row = one coalesced wave transaction.

template<int O>
__global__ void edge_stats_kernel(const float* __restrict__ z1, const float* __restrict__ z2,
                                  const int* __restrict__ idx,
                                  float* __restrict__ vmax, float* __restrict__ vmin,
                                  float* __restrict__ ssum, float* __restrict__ ssq) {
    constexpr int TPP = O / 4;           // threads per point
    constexpr int PPB = 256 / TPP;       // points per block
    const int p0 = blockIdx.x * PPB;
    const int tid = threadIdx.x;
    const int q = tid % TPP;
    const int p = tid / TPP;
    const int oo = q * 4;
    __shared__ int jl[PPB][Kn];
    for (int e = tid; e < PPB * Kn; e += 256)
        jl[e / Kn][e % Kn] = idx[(size_t)(p0 + e / Kn) * Kn + (e % Kn)];
    __syncthreads();
    const int bi = p0 + p;
    const int b = bi >> 11;
    const float4 zi1 = *(const float4*)(z1 + (size_t)bi * O + oo);
    const float4 zi2 = *(const float4*)(z2 + (size_t)bi * O + oo);
    float ax = zi2.x - zi1.x, ay = zi2.y - zi1.y, az = zi2.z - zi1.z, aw = zi2.w - zi1.w;
    float mxx = -3e38f, mxy = -3e38f, mxz = -3e38f, mxw = -3e38f;
    float mnx = 3e38f, mny = 3e38f, mnz = 3e38f, mnw = 3e38f;
    float sx = 0.f, sy = 0.f, sz = 0.f, sw = 0.f;
    float qx = 0.f, qy = 0.f, qz = 0.f, qw = 0.f;
    const float* zbase = z1 + ((size_t)b * Nn) * O + oo;
#pragma unroll
    for (int kk = 0; kk < Kn; ++kk) {
        int j = jl[p][kk];
        float4 v = *(const float4*)(zbase + (size_t)j * O);
        v.x += ax; v.y += ay; v.z += az; v.w += aw;
        mxx = fmaxf(mxx, v.x); mxy = fmaxf(mxy, v.y); mxz = fmaxf(mxz, v.z); mxw = fmaxf(mxw, v.w);
        mnx = fminf(mnx, v.x); mny = fminf(mny, v.y); mnz = fminf(mnz, v.z); mnw = fminf(mnw, v.w);
        sx += v.x; sy += v.y; sz += v.z; sw += v.w;
        qx = fmaf(v.x, v.x, qx); qy = fmaf(v.y, v.y, qy);
        qz = fmaf(v.z, v.z, qz); qw = fmaf(v.w, v.w, qw);
    }
    float4 mx4 = make_float4(mxx, mxy, mxz, mxw);
    float4 mn4 = make_float4(mnx, mny, mnz, mnw);
    *(float4*)(vmax + (size_t)bi * O + oo) = mx4;
    *(float4*)(vmin + (size_t)bi * O + oo) = mn4;
    __shared__ float4 ssm[256], sqq[256];
    ssm[tid] = make_float4(sx, sy, sz, sw);
    sqq[tid] = make_float4(qx, qy, qz, qw);
    __syncthreads();
    if (p == 0) {
#pragma unroll 4
        for (int pp = 1; pp < PPB; ++pp) {
            float4 s4 = ssm[pp * TPP + q];
            float4 q4 = sqq[pp * TPP + q];
            sx += s4.x; sy += s4.y; sz += s4.z; sw += s4.w;
            qx += q4.x; qy += q4.y; qz += q4.z; qw += q4.w;
        }
        int slot = blockIdx.x & 63;
        atomicAdd(&ssum[slot * O + oo + 0], sx);
        atomicAdd(&ssum[slot * O + oo + 1], sy);
        atomicAdd(&ssum[slot * O + oo + 2], sz);
        atomicAdd(&ssum[slot * O + oo + 3], sw);
        atomicAdd(&ssq[slot * O + oo + 0], qx);
        atomicAdd(&ssq[slot * O + oo + 1], qy);
        atomicAdd(&ssq[slot * O + oo + 2], qz);
        atomicAdd(&ssq[slot * O + oo + 3], qw);
    }
}

__global__ void bn_finalize_kernel(const float* __restrict__ ssum, const float* __restrict__ ssq,
                                   const float* __restrict__ gamma, const float* __restrict__ beta,
                                   float* __restrict__ scale, float* __restrict__ shift, int O) {
    int o = threadIdx.x;
    if (o >= O) return;
    float s = 0.f, q = 0.f;
    for (int sl = 0; sl < 64; ++sl) { s += ssum[sl * O + o]; q += ssq[sl * O + o]; }
    const float cnt = (float)Bb * (float)Nn * (float)Kn;
    float mu = s / cnt;
    float var = q / cnt - mu * mu;
    float sc = gamma[o] / sqrtf(var + EPSV);
    scale[o] = sc;
    shift[o] = beta[o] - mu * sc;
}

// ---------------- BN-apply + relu + per-chunk pooling partials (float4)

template<int O>
__global__ void apply_pool_kernel(const float* __restrict__ vmax, const float* __restrict__ vmin,
                                  const float* __restrict__ scale, const float* __restrict__ shift,
                                  float* __restrict__ xout,
                                  float* __restrict__ pmax, float* __restrict__ psum, int obase) {
    constexpr int TPP = O / 4;
    constexpr int PP2 = 256 / TPP;      // points concurrent
    constexpr int S = 128 / PP2;        // iterations
    const int chunk = blockIdx.x;
    const int b = blockIdx.y;
    const int tid = threadIdx.x;
    const int q = tid % TPP;
    const int g = tid / TPP;
    const int oo = q * 4;
    const float4 sc = *(const float4*)(scale + oo);
    const float4 sh = *(const float4*)(shift + oo);
    float pmx = -3e38f, pmy = -3e38f, pmz = -3e38f, pmw = -3e38f;
    float psx = 0.f, psy = 0.f, psz = 0.f, psw = 0.f;
    const int n0 = chunk * 128;
    for (int s = 0; s < S; ++s) {
        int n = n0 + g + s * PP2;
        size_t ix = ((size_t)b * Nn + n) * O + oo;
        float4 vx = *(const float4*)(vmax + ix);
        float4 vn = *(const float4*)(vmin + ix);
        float4 r;
        r.x = fmaxf(fmaf(sc.x >= 0.f ? vx.x : vn.x, sc.x, sh.x), 0.f);
        r.y = fmaxf(fmaf(sc.y >= 0.f ? vx.y : vn.y, sc.y, sh.y), 0.f);
        r.z = fmaxf(fmaf(sc.z >= 0.f ? vx.z : vn.z, sc.z, sh.z), 0.f);
        r.w = fmaxf(fmaf(sc.w >= 0.f ? vx.w : vn.w, sc.w, sh.w), 0.f);
        *(float4*)(xout + ix) = r;
        pmx = fmaxf(pmx, r.x); pmy = fmaxf(pmy, r.y);
        pmz = fmaxf(pmz, r.z); pmw = fmaxf(pmw, r.w);
        psx += r.x; psy += r.y; psz += r.z; psw += r.w;
    }
    __shared__ float4 sm[256], ss2[256];
    sm[tid] = make_float4(pmx, pmy, pmz, pmw);
    ss2[tid] = make_float4(psx, psy, psz, psw);
    __syncthreads();
    if (g == 0) {
#pragma unroll 4
        for (int gg = 1; gg < PP2; ++gg) {
            float4 m4 = sm[gg * TPP + q];
            float4 s4 = ss2[gg * TPP + q];
            pmx = fmaxf(pmx, m4.x); pmy = fmaxf(pmy, m4.y);
            pmz = fmaxf(pmz, m4.z); pmw = fmaxf(pmw, m4.w);
            psx += s4.x; psy += s4.y; psz += s4.z; psw += s4.w;
        }
        size_t pb = ((size_t)b * 16 + chunk) * 512 + obase + oo;
        *(float4*)(pmax + pb) = make_float4(pmx, pmy, pmz, pmw);
        *(float4*)(psum + pb) = make_float4(psx, psy, psz, psw);
    }
}

__global__ void pool_finalize_kernel(const float* __restrict__ pmax, const float* __restrict__ psum,
                                     float* __restrict__ gv) {
    const int b = blockIdx.x;
    const int c = threadIdx.x;          // 512 threads
    float mx = -3e38f, s = 0.f;
    for (int ch = 0; ch < 16; ++ch) {
        size_t p = ((size_t)b * 16 + ch) * 512 + c;
        mx = fmaxf(mx, pmax[p]);
        s += psum[p];
    }
    gv[b * 1024 + c] = mx;
    gv[b * 1024 + 512 + c] = s * (1.f / (float)Nn);
}

// ------------------------------------------------------------------- MLP head

__global__ void head_kernel(const float* __restrict__ gv,
                            const float* __restrict__ fct1, const float* __restrict__ fc1b,
                            const float* __restrict__ ln1g, const float* __restrict__ ln1b,
                            const float* __restrict__ fct2, const float* __restrict__ fc2b,
                            const float* __restrict__ ln2g, const float* __restrict__ ln2b,
                            float* __restrict__ out) {
    const int b = blockIdx.x;
    const int tid = threadIdx.x;
    __shared__ float gx[1024];
    __shared__ float hh[512];
    __shared__ float red[256];
    for (int e = tid; e < 1024; e += 256) gx[e] = gv[b * 1024 + e];
    __syncthreads();
    float h0 = fc1b[tid], h1 = fc1b[tid + 256];
    for (int c = 0; c < 1024; ++c) {
        float gc = gx[c];
        h0 = fmaf(gc, fct1[(size_t)c * 512 + tid], h0);
        h1 = fmaf(gc, fct1[(size_t)c * 512 + tid + 256], h1);
    }
    red[tid] = h0 + h1;
    __syncthreads();
    for (int st = 128; st > 0; st >>= 1) { if (tid < st) red[tid] += red[tid + st]; __syncthreads(); }
    float mu = red[0] * (1.f / 512.f);
    __syncthreads();
    float d0 = h0 - mu, d1 = h1 - mu;
    red[tid] = d0 * d0 + d1 * d1;
    __syncthreads();
    for (int st = 128; st > 0; st >>= 1) { if (tid < st) red[tid] += red[tid + st]; __syncthreads(); }
    float rs = 1.f / sqrtf(red[0] * (1.f / 512.f) + EPSV);
    __syncthreads();
    hh[tid]       = fmaxf(d0 * rs * ln1g[tid] + ln1b[tid], 0.f);
    hh[tid + 256] = fmaxf(d1 * rs * ln1g[tid + 256] + ln1b[tid + 256], 0.f);
    __syncthreads();
    float z = fc2b[tid];
    for (int c = 0; c < 512; ++c) z = fmaf(hh[c], fct2[(size_t)c * 256 + tid], z);
    red[tid] = z;
    __syncthreads();
    for (int st = 128; st > 0; st >>= 1) { if (tid < st) red[tid] += red[tid + st]; __syncthreads(); }
    float mu2 = red[0] * (1.f / 256.f);
    __syncthreads();
    float dz = z - mu2;
    red[tid] = dz * dz;
    __syncthreads();
    for (int st = 128; st > 0; st >>= 1) { if (tid < st) red[tid] += red[tid + st]; __syncthreads(); }
    float rs2 = 1.f / sqrtf(red[0] * (1.f / 256.f) + EPSV);
    out[b * 256 + tid] = dz * rs2 * ln2g[tid] + ln2b[tid];
}

// --------------------------------------------------------------- layer driver

template<int C, int O>
static void run_layer(const float* x, const float* gamma, const float* beta,
                      float* xout, float* DIST, float* XX, float4* XP, int* IDX,
                      float* Z1, float* Z2,
                      float* VMX, float* VMN, float* SSUM, float* SSQ, float* BNS, float* BNB,
                      const float* WT, float* PMAX, float* PSUM, int obase, bool big,
                      hipStream_t stream) {
    sqnorm_zero_kernel<<<192, 256, 0, stream>>>(x, XX, C, SSUM, (C == 3) ? XP : nullptr);
    z_kernel<C, O><<<Bb * Nn / 16, 256, 0, stream>>>(x, WT, Z1, Z2);
    if constexpr (C == 3) {
        // layer 1: packed (x,xx) is L1-resident (32 KB/batch) -> fused
        // inline-dist top-k, no gram dispatch, no DIST write+read.
        if (big) {
            topk_c3_kernel<<<Bb * Nn / 4, 256, 0, stream>>>(XP, IDX, 0, 0);
        } else {
            for (int b = 0; b < Bb; ++b)
                topk_c3_kernel<<<Nn / 4, 256, 0, stream>>>(XP, IDX, b, 1);
        }
    } else {
        if (big) {
            gram_dist_kernel<C><<<dim3(136, 1, Bb), 256, 0, stream>>>(x, XX, DIST, 0, (size_t)Nn * Nn);
            topk_kernel<<<Bb * Nn / 4, 256, 0, stream>>>(DIST, IDX, 0, (size_t)Nn * Nn, 0);
        } else {
            for (int b = 0; b < Bb; ++b) {
                gram_dist_kernel<C><<<dim3(136, 1, 1), 256, 0, stream>>>(x, XX, DIST, b, 0);
                topk_kernel<<<Nn / 4, 256, 0, stream>>>(DIST, IDX, b, 0, 1);
            }
        }
    }
    edge_stats_kernel<O><<<Bb * Nn / (1024 / O), 256, 0, stream>>>(Z1, Z2, IDX, VMX, VMN, SSUM, SSQ);
    bn_finalize_kernel<<<1, 256, 0, stream>>>(SSUM, SSQ, gamma, beta, BNS, BNB, O);
    apply_pool_kernel<O><<<dim3(16, 8), 256, 0, stream>>>(VMX, VMN, BNS, BNB, xout, PMAX, PSUM, obase);
}

extern "C" void kernel_launch(void* const* d_in, const int* in_sizes, int n_in,
                              void* d_out, int out_size, void* d_ws, size_t ws_size,
                              hipStream_t stream) {
    const float* points = (const float*)d_in[0];
    const float* W1 = (const float*)d_in[1];
    const float* g1 = (const float*)d_in[2];
    const float* b1 = (const float*)d_in[3];
    const float* W2 = (const float*)d_in[4];
    const float* g2 = (const float*)d_in[5];
    const float* b2 = (const float*)d_in[6];
    const float* W3 = (const float*)d_in[7];
    const float* g3 = (const float*)d_in[8];
    const float* b3 = (const float*)d_in[9];
    const float* W4 = (const float*)d_in[10];
    const float* g4 = (const float*)d_in[11];
    const float* b4 = (const float*)d_in[12];
    const float* fc1_w = (const float*)d_in[13];
    const float* fc1_b = (const float*)d_in[14];
    const float* ln1g = (const float*)d_in[15];
    const float* ln1b = (const float*)d_in[16];
    const float* fc2_w = (const float*)d_in[17];
    const float* fc2_b = (const float*)d_in[18];
    const float* ln2g = (const float*)d_in[19];
    const float* ln2b = (const float*)d_in[20];

    float* ws = (float*)d_ws;
    const size_t BN = (size_t)Bb * Nn;
    const bool big = ws_size >= (size_t)59826688 * 4;

    size_t off = 0;
    auto take = [&](size_t n) { size_t o = off; off += n; return o; };
    float* DIST = ws + take(big ? (size_t)Bb * Nn * Nn : (size_t)Nn * Nn);
    float* XX   = ws + take(BN);
    float4* XP  = (float4*)(ws + take(BN * 4));
    int*   IDX  = (int*)(ws + take(BN * Kn));
    float* Z1   = ws + take(BN * 256);
    float* Z2   = ws + take(BN * 256);
    float* VMX  = ws + take(BN * 256);
    float* VMN  = ws + take(BN * 256);
    float* SSUM = ws + take(64 * 256);
    float* SSQ  = ws + take(64 * 256);
    float* BNS  = ws + take(256);
    float* BNB  = ws + take(256);
    float* WT1  = ws + take(384);
    float* WT2  = ws + take(8192);
    float* WT3  = ws + take(16384);
    float* WT4  = ws + take(65536);
    float* FCT1 = ws + take(524288);
    float* FCT2 = ws + take(131072);
    float* X1   = ws + take(BN * 64);
    float* X2   = ws + take(BN * 64);
    float* X3   = ws + take(BN * 128);
    float* X4   = ws + take(BN * 256);
    float* GV   = ws + take((size_t)Bb * 1024);
    float* PMAX = ws + take((size_t)Bb * 16 * 512);
    float* PSUM = ws + take((size_t)Bb * 16 * 512);

    // All weight transposes in one launch (independent of layer outputs).
    TransJobs tj;
    tj.in[0] = W1;    tj.out[0] = WT1;  tj.R[0] = 64;  tj.Cc[0] = 6;
    tj.in[1] = W2;    tj.out[1] = WT2;  tj.R[1] = 64;  tj.Cc[1] = 128;
    tj.in[2] = W3;    tj.out[2] = WT3;  tj.R[2] = 128; tj.Cc[2] = 128;
    tj.in[3] = W4;    tj.out[3] = WT4;  tj.R[3] = 256; tj.Cc[3] = 256;
    tj.in[4] = fc1_w; tj.out[4] = FCT1; tj.R[4] = 512; tj.Cc[4] = 1024;
    tj.in[5] = fc2_w; tj.out[5] = FCT2; tj.R[5] = 256; tj.Cc[5] = 512;
    transpose_all_kernel<<<dim3(2048, 6), 256, 0, stream>>>(tj);

    run_layer<3, 64>(points, g1, b1, X1, DIST, XX, XP, IDX, Z1, Z2, VMX, VMN, SSUM, SSQ, BNS, BNB, WT1, PMAX, PSUM, 0, big, stream);
    run_layer<64, 64>(X1, g2, b2, X2, DIST, XX, XP, IDX, Z1, Z2, VMX, VMN, SSUM, SSQ, BNS, BNB, WT2, PMAX, PSUM, 64, big, stream);
    run_layer<64, 128>(X2, g3, b3, X3, DIST, XX, XP, IDX, Z1, Z2, VMX, VMN, SSUM, SSQ, BNS, BNB, WT3, PMAX, PSUM, 128, big, stream);
    run_layer<128, 256>(X3, g4, b4, X4, DIST, XX, XP, IDX, Z1, Z2, VMX, VMN, SSUM, SSQ, BNS, BNB, WT4, PMAX, PSUM, 256, big, stream);

    pool_finalize_kernel<<<Bb, 512, 0, stream>>>(PMAX, PSUM, GV);
    head_kernel<<<Bb, 256, 0, stream>>>(GV, FCT1, fc1_b, ln1g, ln1b, FCT2, fc2_b, ln2g, ln2b,
                                        (float*)d_out);
}

// Round 13
// 837.920 us; speedup vs baseline: 1.7628x; 1.0567x over previous
//
#include <hip/hip_runtime.h>
#include <cstdint>
#include <cstddef>

static constexpr int Bb = 8;
static constexpr int Nn = 2048;
static constexpr int Kn = 20;
static constexpr float EPSV = 1e-5f;
static constexpr int JSENT = 1 << 30;

// ---------------------------------------------------------------- utilities

// blocks 0..63: xx[i] = ||x_i||^2 (and packed (x,xx) float4 if xp != null);
// blocks 64..191: zero 32K floats of zp
__global__ void sqnorm_zero_kernel(const float* __restrict__ x, float* __restrict__ xx, int C,
                                   float* __restrict__ zp, float4* __restrict__ xp) {
    int blk = blockIdx.x;
    if (blk < 64) {
        int i = blk * 256 + threadIdx.x;
        const float* xr = x + (size_t)i * C;
        float s = 0.f;
        for (int c = 0; c < C; ++c) { float v = xr[c]; s += v * v; }
        xx[i] = s;
        if (xp) xp[i] = make_float4(xr[0], xr[1], xr[2], s);   // only used for C==3
    } else {
        zp[(blk - 64) * 256 + threadIdx.x] = 0.f;
    }
}

// all weight transposes in one launch: out[c*R + r] = in[r*Cc + c]
struct TransJobs {
    const float* in[6];
    float* out[6];
    int R[6];
    int Cc[6];
};

__global__ void transpose_all_kernel(TransJobs tj) {
    int m = blockIdx.y;
    int i = blockIdx.x * 256 + threadIdx.x;
    int total = tj.R[m] * tj.Cc[m];
    if (i < total) {
        int r = i / tj.Cc[m], c = i % tj.Cc[m];
        tj.out[m][(size_t)c * tj.R[m] + r] = tj.in[m][i];
    }
}

// ------------------------------------------------ pairwise sq-dist (tiled gram)
// SYMMETRIC: only the 136 upper-triangular 128x128 block-pairs are computed;
// off-diagonal blocks emit the mirrored tile through a 32-row LDS transpose
// buffer (bitwise-identical values; 4 chunks x 2 barriers).
// LDS UNION: staging (CT*272 floats) and the T mirror buffer (32*136) are
// never live at the same time -> one 17.4 KB buffer.
// Main loop is the R8 single-buffer form — FROZEN. History:
//   (256,3)/(256,4)  -> accumulator spills to scratch (R5 18x traffic, R6 +270MB)
//   reg prefetch     -> +32 VGPR, occupancy 27->20%, net loss (R7)
//   LDS double-buffer-> VGPR 128, spill, 1.49 GB traffic, 350 us (R9)
// launch_bounds(256,2), plain k-loop, VGPR~68, WRITE exactly 131 MB is the
// verified spill-free optimum. DO NOT add register pressure to this loop.

template<int C>
__global__ __launch_bounds__(256, 2)
void gram_dist_kernel(const float* __restrict__ x, const float* __restrict__ xx,
                      float* __restrict__ dist, int b0, size_t dstride) {
    constexpr int CT = (C < 16) ? C : 16;
    constexpr int SM_FLOATS = (CT * 272 > 32 * 136) ? CT * 272 : 32 * 136;
    const int b = b0 + blockIdx.z;
    // decode upper-tri pair index -> (rblk, cblk), rblk <= cblk, 16x16 tiles
    int p = blockIdx.x, rblk = 0;
    while (p >= 16 - rblk) { p -= 16 - rblk; ++rblk; }
    const int cblk = rblk + p;
    const int i0 = rblk * 128, j0 = cblk * 128;
    const int tid = threadIdx.x;
    const int tx = tid & 15, ty = tid >> 4;
    __shared__ float smem[SM_FLOATS];
    float (*As)[136] = (float (*)[136])smem;
    float (*BsA)[68] = (float (*)[68])(smem + (size_t)CT * 136);
    float (*BsB)[68] = (float (*)[68])(smem + (size_t)CT * 136 + (size_t)CT * 68);
    float (*T)[136]  = (float (*)[136])smem;   // aliases staging; used post-loop only
    float acc[8][8] = {};
    const float* xb = x + (size_t)b * Nn * C;

    const int si = tid & 127;         // staging row
    const int half = tid >> 7;        // 0..1
    float* bbase = ((si & 4) ? &BsB[0][0] : &BsA[0][0]) + (((si >> 3) << 2) | (si & 3));

    for (int c0 = 0; c0 < C; c0 += CT) {
        if constexpr (CT == 16) {
            const float* ra = xb + (size_t)(i0 + si) * C + c0 + half * 8;
            const float* rb = xb + (size_t)(j0 + si) * C + c0 + half * 8;
            float4 a0 = *(const float4*)ra;
            float4 a1 = *(const float4*)(ra + 4);
            float4 bq0 = *(const float4*)rb;
            float4 bq1 = *(const float4*)(rb + 4);
            const int cb = half * 8;
            As[cb + 0][si] = a0.x; As[cb + 1][si] = a0.y;
            As[cb + 2][si] = a0.z; As[cb + 3][si] = a0.w;
            As[cb + 4][si] = a1.x; As[cb + 5][si] = a1.y;
            As[cb + 6][si] = a1.z; As[cb + 7][si] = a1.w;
            bbase[(cb + 0) * 68] = bq0.x; bbase[(cb + 1) * 68] = bq0.y;
            bbase[(cb + 2) * 68] = bq0.z; bbase[(cb + 3) * 68] = bq0.w;
            bbase[(cb + 4) * 68] = bq1.x; bbase[(cb + 5) * 68] = bq1.y;
            bbase[(cb + 6) * 68] = bq1.z; bbase[(cb + 7) * 68] = bq1.w;
        } else {
            if (half == 0) {
                const float* r0 = xb + (size_t)(i0 + si) * C + c0;
#pragma unroll
                for (int c = 0; c < CT; ++c) As[c][si] = r0[c];
            } else {
                const float* r1 = xb + (size_t)(j0 + si) * C + c0;
#pragma unroll
                for (int c = 0; c < CT; ++c) bbase[c * 68] = r1[c];
            }
        }
        __syncthreads();
#pragma unroll
        for (int cc = 0; cc < CT; ++cc) {
            float a[8], bv[8];
            *(float4*)&a[0]  = *(const float4*)&As[cc][ty * 8];
            *(float4*)&a[4]  = *(const float4*)&As[cc][ty * 8 + 4];
            *(float4*)&bv[0] = *(const float4*)&BsA[cc][tx * 4];
            *(float4*)&bv[4] = *(const float4*)&BsB[cc][tx * 4];
#pragma unroll
            for (int u = 0; u < 8; ++u)
#pragma unroll
                for (int v = 0; v < 8; ++v)
                    acc[u][v] = fmaf(a[u], bv[v], acc[u][v]);
        }
        __syncthreads();
    }

    const float* xxb = xx + (size_t)b * Nn;
    float xi[8], xj[8];
#pragma unroll
    for (int u = 0; u < 8; ++u) xi[u] = xxb[i0 + ty * 8 + u];
#pragma unroll
    for (int v = 0; v < 8; ++v) xj[v] = xxb[j0 + tx * 8 + v];
    float* db = dist + (size_t)blockIdx.z * dstride;
#pragma unroll
    for (int u = 0; u < 8; ++u) {
        float* row = db + (size_t)(i0 + ty * 8 + u) * Nn + (j0 + tx * 8);
        float4 o0, o1;
        o0.x = xi[u] + xj[0] - 2.f * acc[u][0];
        o0.y = xi[u] + xj[1] - 2.f * acc[u][1];
        o0.z = xi[u] + xj[2] - 2.f * acc[u][2];
        o0.w = xi[u] + xj[3] - 2.f * acc[u][3];
        o1.x = xi[u] + xj[4] - 2.f * acc[u][4];
        o1.y = xi[u] + xj[5] - 2.f * acc[u][5];
        o1.z = xi[u] + xj[6] - 2.f * acc[u][6];
        o1.w = xi[u] + xj[7] - 2.f * acc[u][7];
        *(float4*)row = o0;
        *(float4*)(row + 4) = o1;
    }

    if (cblk > rblk) {
        // mirror tile (j0.., i0..): value(row=j0+tx*8+v, col=i0+ty*8+u)
        //   = xj[v] + xi[u] - 2*acc[u][v]  (bitwise equal to main tile)
        // 4 chunks of 32 rows; 64 writer-threads per chunk, 8 barriers total.
        const int rr = tid >> 3;            // 0..31 row within 32-row chunk
        const int c4 = (tid & 7) * 4;       // col base (float4 granularity)
#pragma unroll 1
        for (int m = 0; m < 4; ++m) {
            if ((tx >> 2) == m) {
                const int lr = (tx & 3) * 8;
#pragma unroll
                for (int v = 0; v < 8; ++v)
#pragma unroll
                    for (int u = 0; u < 8; ++u)
                        T[lr + v][ty * 8 + u] = xj[v] + xi[u] - 2.f * acc[u][v];
            }
            __syncthreads();
            float* orow = db + (size_t)(j0 + m * 32 + rr) * Nn + i0;
#pragma unroll
            for (int s = 0; s < 4; ++s)
                *(float4*)(orow + c4 + s * 32) = *(const float4*)&T[rr][c4 + s * 32];
            __syncthreads();
        }
    }
}

// ------------------------------------------------------- top-k (k=20 smallest)
// Selection set is exact lex-(v,j) order. Per-lane sorted top-4 with
// "greater-than-last-pop" refill (no consumed-slot mask needed: a lane's
// consumed candidates are exactly its popped global winners, all lex <= the
// last pop). Rounds use a value-only fminf butterfly + ballot winner pick;
// exact float ties (rare) fall back to a lex butterfly.

__device__ __forceinline__ bool lex_less(float v1, int j1, float v2, int j2) {
    return v1 < v2 || (v1 == v2 && j1 < j2);
}

// insert candidate (v,j) into sorted 4-list via select ladder
#define TOP4_INS(v, j)                                                            \
    {                                                                             \
        bool l3 = lex_less(v, j, tv3, tj3);                                       \
        if (l3) {                                                                 \
            bool l2 = lex_less(v, j, tv2, tj2);                                   \
            bool l1 = lex_less(v, j, tv1, tj1);                                   \
            bool l0 = lex_less(v, j, tv0, tj0);                                   \
            tv3 = l2 ? tv2 : v;  tj3 = l2 ? tj2 : j;                              \
            tv2 = l2 ? (l1 ? tv1 : v) : tv2;  tj2 = l2 ? (l1 ? tj1 : j) : tj2;    \
            tv1 = l1 ? (l0 ? tv0 : v) : tv1;  tj1 = l1 ? (l0 ? tj0 : j) : tj1;    \
            tv0 = l0 ? v : tv0;  tj0 = l0 ? j : tj0;                              \
        }                                                                         \
    }

// rebuild sorted top-4 among candidates with (v,j) lex-greater than (lv,lj)
__device__ __forceinline__ void top4_build(const float4* __restrict__ dr4, int lane,
                                           float lv, int lj,
                                           float& tv0, int& tj0, float& tv1, int& tj1,
                                           float& tv2, int& tj2, float& tv3, int& tj3) {
    tv0 = tv1 = tv2 = tv3 = 3e38f;
    tj0 = tj1 = tj2 = tj3 = JSENT;
#pragma unroll
    for (int q = 0; q < 8; ++q) {
        float4 f = dr4[q * 64 + lane];
        float vv[4] = {f.x, f.y, f.z, f.w};
#pragma unroll
        for (int c = 0; c < 4; ++c) {
            int j = (q * 64 + lane) * 4 + c;
            float v = vv[c];
            if (lex_less(lv, lj, v, j)) TOP4_INS(v, j)
        }
    }
}

// shared 20-round selection loop (macro so both kernels reuse it verbatim;
// REBUILD is an expression rebuilding the top-4 with filter (bv,bj))
#define TOPK_ROUNDS(REBUILD)                                                      \
    for (int t = 0; t < Kn; ++t) {                                                \
        float bv = tv0;                                                           \
        _Pragma("unroll")                                                         \
        for (int off = 1; off < 64; off <<= 1)                                    \
            bv = fminf(bv, __shfl_xor(bv, off));                                  \
        unsigned long long tied = __ballot(tv0 == bv);                            \
        int bj;                                                                   \
        if (__popcll(tied) == 1) {                                                \
            int winner = (int)(__ffsll(tied) - 1);                                \
            bj = __shfl(tj0, winner);                                             \
        } else {                                                                  \
            float fv = (tv0 == bv) ? bv : 3e38f;                                  \
            int fj = (tv0 == bv) ? tj0 : JSENT;                                   \
            _Pragma("unroll")                                                     \
            for (int off = 1; off < 64; off <<= 1) {                              \
                float ov = __shfl_xor(fv, off);                                   \
                int oj = __shfl_xor(fj, off);                                     \
                if (lex_less(ov, oj, fv, fj)) { fv = ov; fj = oj; }               \
            }                                                                     \
            bj = fj;                                                              \
        }                                                                         \
        if (lane == 0) orow[t] = bj;                                              \
        if (tv0 == bv && tj0 == bj) {                                             \
            tv0 = tv1; tj0 = tj1; tv1 = tv2; tj1 = tj2;                           \
            tv2 = tv3; tj2 = tj3; tv3 = 3e38f; tj3 = JSENT;                       \
            if (tj0 == JSENT) { REBUILD; }                                        \
        }                                                                         \
    }

__global__ void topk_kernel(const float* __restrict__ dist, int* __restrict__ idxo,
                            int b0, size_t dstride, int rows_per_batch_only) {
    const int w = threadIdx.x >> 6;
    const int lane = threadIdx.x & 63;
    const int lin = blockIdx.x * 4 + w;
    int bz, i;
    if (rows_per_batch_only) { bz = 0; i = lin; }
    else { bz = lin >> 11; i = lin & (Nn - 1); }
    const int b = b0 + bz;
    const float4* dr4 = (const float4*)(dist + (size_t)bz * dstride + (size_t)i * Nn);

    float tv0, tv1, tv2, tv3;
    int tj0, tj1, tj2, tj3;
    top4_build(dr4, lane, -3e38f, -1, tv0, tj0, tv1, tj1, tv2, tj2, tv3, tj3);

    int* orow = idxo + ((size_t)b * Nn + i) * Kn;
    TOPK_ROUNDS(top4_build(dr4, lane, bv, bj, tv0, tj0, tv1, tj1, tv2, tj2, tv3, tj3))
}

// -------- layer-1 fused top-k: dist computed inline from packed (x,xx) float4.
// Candidate mapping j = m*64 + lane -> lane-adjacent candidates are consecutive
// float4s => coalesced 1KB wave loads. FMA chain shape matches gram's CT=3
// path exactly (acc=fmaf(a,b,acc) over increasing c, then xx_i+xx_j-2.f*acc)
// -> same values, same selection.

__device__ __forceinline__ void top4_build_c3(const float4* __restrict__ xpb,
                                              float xi0, float xi1, float xi2, float xxi,
                                              int lane, float lv, int lj,
                                              float& tv0, int& tj0, float& tv1, int& tj1,
                                              float& tv2, int& tj2, float& tv3, int& tj3) {
    tv0 = tv1 = tv2 = tv3 = 3e38f;
    tj0 = tj1 = tj2 = tj3 = JSENT;
#pragma unroll
    for (int m = 0; m < 32; ++m) {
        int j = m * 64 + lane;
        float4 f = xpb[j];
        float acc = 0.f;
        acc = fmaf(xi0, f.x, acc);
        acc = fmaf(xi1, f.y, acc);
        acc = fmaf(xi2, f.z, acc);
        float v = xxi + f.w - 2.f * acc;
        if (lex_less(lv, lj, v, j)) TOP4_INS(v, j)
    }
}

__global__ void topk_c3_kernel(const float4* __restrict__ xp, int* __restrict__ idxo,
                               int b0, int rows_per_batch_only) {
    const int w = threadIdx.x >> 6;
    const int lane = threadIdx.x & 63;
    const int lin = blockIdx.x * 4 + w;
    int bz, i;
    if (rows_per_batch_only) { bz = 0; i = lin; }
    else { bz = lin >> 11; i = lin & (Nn - 1); }
    const int b = b0 + bz;
    const float4* xpb = xp + (size_t)b * Nn;
    const float4 fi = xpb[i];
    const float xi0 = fi.x, xi1 = fi.y, xi2 = fi.z, xxi = fi.w;

    float tv0, tv1, tv2, tv3;
    int tj0, tj1, tj2, tj3;
    top4_build_c3(xpb, xi0, xi1, xi2, xxi, lane, -3e38f, -1,
                  tv0, tj0, tv1, tj1, tv2, tj2, tv3, tj3);

    int* orow = idxo + ((size_t)b * Nn + i) * Kn;
    TOPK_ROUNDS(top4_build_c3(xpb, xi0, xi1, xi2, xxi, lane, bv, bj, \
                              tv0, tj0, tv1, tj1, tv2, tj2, tv3, tj3))
}

// ------------------------------------- per-point projections Z1=X Wl^T, Z2=X Wr^T

template<int C, int O>
__global__ void z_kernel(const float* __restrict__ x, const float* __restrict__ wt,
                         float* __restrict__ z1, float* __restrict__ z2) {
    constexpr int TP = 16;
    constexpr int G = 256 / O;
    constexpr int PP = TP / G;
    const int p0 = blockIdx.x * TP;
    const int tid = threadIdx.x;
    const int oo = tid % O;
    const int g = tid / O;
    __shared__ float xs[TP][(C < 4) ? 4 : C];
    for (int e = tid; e < TP * C; e += 256) {
        int p = e / C, c = e % C;
        xs[p][c] = x[(size_t)(p0 + p) * C + c];
    }
    __syncthreads();
    float a1[PP], a2[PP];
#pragma unroll
    for (int p = 0; p < PP; ++p) { a1[p] = 0.f; a2[p] = 0.f; }
    if constexpr (C % 4 == 0) {
        for (int c = 0; c < C; c += 4) {
            float w1[4], w2[4];
#pragma unroll
            for (int q = 0; q < 4; ++q) {
                w1[q] = wt[(size_t)(c + q) * O + oo];
                w2[q] = wt[(size_t)(C + c + q) * O + oo];
            }
#pragma unroll
            for (int p = 0; p < PP; ++p) {
                const float4 xv = *(const float4*)(&xs[g * PP + p][c]);
                a1[p] = fmaf(xv.w, w1[3], fmaf(xv.z, w1[2], fmaf(xv.y, w1[1], fmaf(xv.x, w1[0], a1[p]))));
                a2[p] = fmaf(xv.w, w2[3], fmaf(xv.z, w2[2], fmaf(xv.y, w2[1], fmaf(xv.x, w2[0], a2[p]))));
            }
        }
    } else {
        for (int c = 0; c < C; ++c) {
            float w1 = wt[(size_t)c * O + oo];
            float w2 = wt[(size_t)(C + c) * O + oo];
#pragma unroll
            for (int p = 0; p < PP; ++p) {
                float xv = xs[g * PP + p][c];
                a1[p] = fmaf(xv, w1, a1[p]);
                a2[p] = fmaf(xv, w2, a2[p]);
            }
        }
    }
#pragma unroll
    for (int p = 0; p < PP; ++p) {
        size_t row = (size_t)(p0 + g * PP + p) * O + oo;
        z1[row] = a1[p];
        z2[row] = a2[p];
    }
}

// -------------------- gather edges, max/min over k + BN partial sums
// float4 per thread; each gathered row = one coalesced wave transaction.

template<int O>
__global__ void edge_stats_kernel(const float* __restrict__ z1, const float* __restrict__ z2,
                                  const int* __restrict__ idx,
                                  float* __restrict__ vmax, float* __restrict__ vmin,
                                  float* __restrict__ ssum, float* __restrict__ ssq) {
    constexpr int TPP = O / 4;           // threads per point
    constexpr int PPB = 256 / TPP;       // points per block
    const int p0 = blockIdx.x * PPB;
    const int tid = threadIdx.x;
    const int q = tid % TPP;
    const int p = tid / TPP;
    const int oo = q * 4;
    __shared__ int jl[PPB][Kn];
    for (int e = tid; e < PPB * Kn; e += 256)
        jl[e / Kn][e % Kn] = idx[(size_t)(p0 + e / Kn) * Kn + (e % Kn)];
    __syncthreads();
    const int bi = p0 + p;
    const int b = bi >> 11;
    const float4 zi1 = *(const float4*)(z1 + (size_t)bi * O + oo);
    const float4 zi2 = *(const float4*)(z2 + (size_t)bi * O + oo);
    float ax = zi2.x - zi1.x, ay = zi2.y - zi1.y, az = zi2.z - zi1.z, aw = zi2.w - zi1.w;
    float mxx = -3e38f, mxy = -3e38f, mxz = -3e38f, mxw = -3e38f;
    float mnx = 3e38f, mny = 3e38f, mnz = 3e38f, mnw = 3e38f;
    float sx = 0.f, sy = 0.f, sz = 0.f, sw = 0.f;
    float qx = 0.f, qy = 0.f, qz = 0.f, qw = 0.f;
    const float* zbase = z1 + ((size_t)b * Nn) * O + oo;
#pragma unroll
    for (int kk = 0; kk < Kn; ++kk) {
        int j = jl[p][kk];
        float4 v = *(const float4*)(zbase + (size_t)j * O);
        v.x += ax; v.y += ay; v.z += az; v.w += aw;
        mxx = fmaxf(mxx, v.x); mxy = fmaxf(mxy, v.y); mxz = fmaxf(mxz, v.z); mxw = fmaxf(mxw, v.w);
        mnx = fminf(mnx, v.x); mny = fminf(mny, v.y); mnz = fminf(mnz, v.z); mnw = fminf(mnw, v.w);
        sx += v.x; sy += v.y; sz += v.z; sw += v.w;
        qx = fmaf(v.x, v.x, qx); qy = fmaf(v.y, v.y, qy);
        qz = fmaf(v.z, v.z, qz); qw = fmaf(v.w, v.w, qw);
    }
    float4 mx4 = make_float4(mxx, mxy, mxz, mxw);
    float4 mn4 = make_float4(mnx, mny, mnz, mnw);
    *(float4*)(vmax + (size_t)bi * O + oo) = mx4;
    *(float4*)(vmin + (size_t)bi * O + oo) = mn4;
    __shared__ float4 ssm[256], sqq[256];
    ssm[tid] = make_float4(sx, sy, sz, sw);
    sqq[tid] = make_float4(qx, qy, qz, qw);
    __syncthreads();
    if (p == 0) {
#pragma unroll 4
        for (int pp = 1; pp < PPB; ++pp) {
            float4 s4 = ssm[pp * TPP + q];
            float4 q4 = sqq[pp * TPP + q];
            sx += s4.x; sy += s4.y; sz += s4.z; sw += s4.w;
            qx += q4.x; qy += q4.y; qz += q4.z; qw += q4.w;
        }
        int slot = blockIdx.x & 63;
        atomicAdd(&ssum[slot * O + oo + 0], sx);
        atomicAdd(&ssum[slot * O + oo + 1], sy);
        atomicAdd(&ssum[slot * O + oo + 2], sz);
        atomicAdd(&ssum[slot * O + oo + 3], sw);
        atomicAdd(&ssq[slot * O + oo + 0], qx);
        atomicAdd(&ssq[slot * O + oo + 1], qy);
        atomicAdd(&ssq[slot * O + oo + 2], qz);
        atomicAdd(&ssq[slot * O + oo + 3], qw);
    }
}

__global__ void bn_finalize_kernel(const float* __restrict__ ssum, const float* __restrict__ ssq,
                                   const float* __restrict__ gamma, const float* __restrict__ beta,
                                   float* __restrict__ scale, float* __restrict__ shift, int O) {
    int o = threadIdx.x;
    if (o >= O) return;
    float s = 0.f, q = 0.f;
    for (int sl = 0; sl < 64; ++sl) { s += ssum[sl * O + o]; q += ssq[sl * O + o]; }
    const float cnt = (float)Bb * (float)Nn * (float)Kn;
    float mu = s / cnt;
    float var = q / cnt - mu * mu;
    float sc = gamma[o] / sqrtf(var + EPSV);
    scale[o] = sc;
    shift[o] = beta[o] - mu * sc;
}

// ---------------- BN-apply + relu + per-chunk pooling partials (float4)

template<int O>
__global__ void apply_pool_kernel(const float* __restrict__ vmax, const float* __restrict__ vmin,
                                  const float* __restrict__ scale, const float* __restrict__ shift,
                                  float* __restrict__ xout,
                                  float* __restrict__ pmax, float* __restrict__ psum, int obase) {
    constexpr int TPP = O / 4;
    constexpr int PP2 = 256 / TPP;      // points concurrent
    constexpr int S = 128 / PP2;        // iterations
    const int chunk = blockIdx.x;
    const int b = blockIdx.y;
    const int tid = threadIdx.x;
    const int q = tid % TPP;
    const int g = tid / TPP;
    const int oo = q * 4;
    const float4 sc = *(const float4*)(scale + oo);
    const float4 sh = *(const float4*)(shift + oo);
    float pmx = -3e38f, pmy = -3e38f, pmz = -3e38f, pmw = -3e38f;
    float psx = 0.f, psy = 0.f, psz = 0.f, psw = 0.f;
    const int n0 = chunk * 128;
    for (int s = 0; s < S; ++s) {
        int n = n0 + g + s * PP2;
        size_t ix = ((size_t)b * Nn + n) * O + oo;
        float4 vx = *(const float4*)(vmax + ix);
        float4 vn = *(const float4*)(vmin + ix);
        float4 r;
        r.x = fmaxf(fmaf(sc.x >= 0.f ? vx.x : vn.x, sc.x, sh.x), 0.f);
        r.y = fmaxf(fmaf(sc.y >= 0.f ? vx.y : vn.y, sc.y, sh.y), 0.f);
        r.z = fmaxf(fmaf(sc.z >= 0.f ? vx.z : vn.z, sc.z, sh.z), 0.f);
        r.w = fmaxf(fmaf(sc.w >= 0.f ? vx.w : vn.w, sc.w, sh.w), 0.f);
        *(float4*)(xout + ix) = r;
        pmx = fmaxf(pmx, r.x); pmy = fmaxf(pmy, r.y);
        pmz = fmaxf(pmz, r.z); pmw = fmaxf(pmw, r.w);
        psx += r.x; psy += r.y; psz += r.z; psw += r.w;
    }
    __shared__ float4 sm[256], ss2[256];
    sm[tid] = make_float4(pmx, pmy, pmz, pmw);
    ss2[tid] = make_float4(psx, psy, psz, psw);
    __syncthreads();
    if (g == 0) {
#pragma unroll 4
        for (int gg = 1; gg < PP2; ++gg) {
            float4 m4 = sm[gg * TPP + q];
            float4 s4 = ss2[gg * TPP + q];
            pmx = fmaxf(pmx, m4.x); pmy = fmaxf(pmy, m4.y);
            pmz = fmaxf(pmz, m4.z); pmw = fmaxf(pmw, m4.w);
            psx += s4.x; psy += s4.y; psz += s4.z; psw += s4.w;
        }
        size_t pb = ((size_t)b * 16 + chunk) * 512 + obase + oo;
        *(float4*)(pmax + pb) = make_float4(pmx, pmy, pmz, pmw);
        *(float4*)(psum + pb) = make_float4(psx, psy, psz, psw);
    }
}

__global__ void pool_finalize_kernel(const float* __restrict__ pmax, const float* __restrict__ psum,
                                     float* __restrict__ gv) {
    const int b = blockIdx.x;
    const int c = threadIdx.x;          // 512 threads
    float mx = -3e38f, s = 0.f;
    for (int ch = 0; ch < 16; ++ch) {
        size_t p = ((size_t)b * 16 + ch) * 512 + c;
        mx = fmaxf(mx, pmax[p]);
        s += psum[p];
    }
    gv[b * 1024 + c] = mx;
    gv[b * 1024 + 512 + c] = s * (1.f / (float)Nn);
}

// ------------------------------------------------------------------- MLP head

__global__ void head_kernel(const float* __restrict__ gv,
                            const float* __restrict__ fct1, const float* __restrict__ fc1b,
                            const float* __restrict__ ln1g, const float* __restrict__ ln1b,
                            const float* __restrict__ fct2, const float* __restrict__ fc2b,
                            const float* __restrict__ ln2g, const float* __restrict__ ln2b,
                            float* __restrict__ out) {
    const int b = blockIdx.x;
    const int tid = threadIdx.x;
    __shared__ float gx[1024];
    __shared__ float hh[512];
    __shared__ float red[256];
    for (int e = tid; e < 1024; e += 256) gx[e] = gv[b * 1024 + e];
    __syncthreads();
    float h0 = fc1b[tid], h1 = fc1b[tid + 256];
    for (int c = 0; c < 1024; ++c) {
        float gc = gx[c];
        h0 = fmaf(gc, fct1[(size_t)c * 512 + tid], h0);
        h1 = fmaf(gc, fct1[(size_t)c * 512 + tid + 256], h1);
    }
    red[tid] = h0 + h1;
    __syncthreads();
    for (int st = 128; st > 0; st >>= 1) { if (tid < st) red[tid] += red[tid + st]; __syncthreads(); }
    float mu = red[0] * (1.f / 512.f);
    __syncthreads();
    float d0 = h0 - mu, d1 = h1 - mu;
    red[tid] = d0 * d0 + d1 * d1;
    __syncthreads();
    for (int st = 128; st > 0; st >>= 1) { if (tid < st) red[tid] += red[tid + st]; __syncthreads(); }
    float rs = 1.f / sqrtf(red[0] * (1.f / 512.f) + EPSV);
    __syncthreads();
    hh[tid]       = fmaxf(d0 * rs * ln1g[tid] + ln1b[tid], 0.f);
    hh[tid + 256] = fmaxf(d1 * rs * ln1g[tid + 256] + ln1b[tid + 256], 0.f);
    __syncthreads();
    float z = fc2b[tid];
    for (int c = 0; c < 512; ++c) z = fmaf(hh[c], fct2[(size_t)c * 256 + tid], z);
    red[tid] = z;
    __syncthreads();
    for (int st = 128; st > 0; st >>= 1) { if (tid < st) red[tid] += red[tid + st]; __syncthreads(); }
    float mu2 = red[0] * (1.f / 256.f);
    __syncthreads();
    float dz = z - mu2;
    red[tid] = dz * dz;
    __syncthreads();
    for (int st = 128; st > 0; st >>= 1) { if (tid < st) red[tid] += red[tid + st]; __syncthreads(); }
    float rs2 = 1.f / sqrtf(red[0] * (1.f / 256.f) + EPSV);
    out[b * 256 + tid] = dz * rs2 * ln2g[tid] + ln2b[tid];
}

// --------------------------------------------------------------- layer driver

template<int C, int O>
static void run_layer(const float* x, const float* gamma, const float* beta,
                      float* xout, float* DIST, float* XX, float4* XP, int* IDX,
                      float* Z1, float* Z2,
                      float* VMX, float* VMN, float* SSUM, float* SSQ, float* BNS, float* BNB,
                      const float* WT, float* PMAX, float* PSUM, int obase, bool big,
                      hipStream_t stream) {
    sqnorm_zero_kernel<<<192, 256, 0, stream>>>(x, XX, C, SSUM, (C == 3) ? XP : nullptr);
    z_kernel<C, O><<<Bb * Nn / 16, 256, 0, stream>>>(x, WT, Z1, Z2);
    if constexpr (C == 3) {
        // layer 1: packed (x,xx) is L1-resident (32 KB/batch) -> fused
        // inline-dist top-k, no gram dispatch, no DIST write+read.
        if (big) {
            topk_c3_kernel<<<Bb * Nn / 4, 256, 0, stream>>>(XP, IDX, 0, 0);
        } else {
            for (int b = 0; b < Bb; ++b)
                topk_c3_kernel<<<Nn / 4, 256, 0, stream>>>(XP, IDX, b, 1);
        }
    } else {
        if (big) {
            gram_dist_kernel<C><<<dim3(136, 1, Bb), 256, 0, stream>>>(x, XX, DIST, 0, (size_t)Nn * Nn);
            topk_kernel<<<Bb * Nn / 4, 256, 0, stream>>>(DIST, IDX, 0, (size_t)Nn * Nn, 0);
        } else {
            for (int b = 0; b < Bb; ++b) {
                gram_dist_kernel<C><<<dim3(136, 1, 1), 256, 0, stream>>>(x, XX, DIST, b, 0);
                topk_kernel<<<Nn / 4, 256, 0, stream>>>(DIST, IDX, b, 0, 1);
            }
        }
    }
    edge_stats_kernel<O><<<Bb * Nn / (1024 / O), 256, 0, stream>>>(Z1, Z2, IDX, VMX, VMN, SSUM, SSQ);
    bn_finalize_kernel<<<1, 256, 0, stream>>>(SSUM, SSQ, gamma, beta, BNS, BNB, O);
    apply_pool_kernel<O><<<dim3(16, 8), 256, 0, stream>>>(VMX, VMN, BNS, BNB, xout, PMAX, PSUM, obase);
}

extern "C" void kernel_launch(void* const* d_in, const int* in_sizes, int n_in,
                              void* d_out, int out_size, void* d_ws, size_t ws_size,
                              hipStream_t stream) {
    const float* points = (const float*)d_in[0];
    const float* W1 = (const float*)d_in[1];
    const float* g1 = (const float*)d_in[2];
    const float* b1 = (const float*)d_in[3];
    const float* W2 = (const float*)d_in[4];
    const float* g2 = (const float*)d_in[5];
    const float* b2 = (const float*)d_in[6];
    const float* W3 = (const float*)d_in[7];
    const float* g3 = (const float*)d_in[8];
    const float* b3 = (const float*)d_in[9];
    const float* W4 = (const float*)d_in[10];
    const float* g4 = (const float*)d_in[11];
    const float* b4 = (const float*)d_in[12];
    const float* fc1_w = (const float*)d_in[13];
    const float* fc1_b = (const float*)d_in[14];
    const float* ln1g = (const float*)d_in[15];
    const float* ln1b = (const float*)d_in[16];
    const float* fc2_w = (const float*)d_in[17];
    const float* fc2_b = (const float*)d_in[18];
    const float* ln2g = (const float*)d_in[19];
    const float* ln2b = (const float*)d_in[20];

    float* ws = (float*)d_ws;
    const size_t BN = (size_t)Bb * Nn;
    const bool big = ws_size >= (size_t)59826688 * 4;

    size_t off = 0;
    auto take = [&](size_t n) { size_t o = off; off += n; return o; };
    float* DIST = ws + take(big ? (size_t)Bb * Nn * Nn : (size_t)Nn * Nn);
    float* XX   = ws + take(BN);
    float4* XP  = (float4*)(ws + take(BN * 4));
    int*   IDX  = (int*)(ws + take(BN * Kn));
    float* Z1   = ws + take(BN * 256);
    float* Z2   = ws + take(BN * 256);
    float* VMX  = ws + take(BN * 256);
    float* VMN  = ws + take(BN * 256);
    float* SSUM = ws + take(64 * 256);
    float* SSQ  = ws + take(64 * 256);
    float* BNS  = ws + take(256);
    float* BNB  = ws + take(256);
    float* WT1  = ws + take(384);
    float* WT2  = ws + take(8192);
    float* WT3  = ws + take(16384);
    float* WT4  = ws + take(65536);
    float* FCT1 = ws + take(524288);
    float* FCT2 = ws + take(131072);
    float* X1   = ws + take(BN * 64);
    float* X2   = ws + take(BN * 64);
    float* X3   = ws + take(BN * 128);
    float* X4   = ws + take(BN * 256);
    float* GV   = ws + take((size_t)Bb * 1024);
    float* PMAX = ws + take((size_t)Bb * 16 * 512);
    float* PSUM = ws + take((size_t)Bb * 16 * 512);

    // All weight transposes in one launch (independent of layer outputs).
    TransJobs tj;
    tj.in[0] = W1;    tj.out[0] = WT1;  tj.R[0] = 64;  tj.Cc[0] = 6;
    tj.in[1] = W2;    tj.out[1] = WT2;  tj.R[1] = 64;  tj.Cc[1] = 128;
    tj.in[2] = W3;    tj.out[2] = WT3;  tj.R[2] = 128; tj.Cc[2] = 128;
    tj.in[3] = W4;    tj.out[3] = WT4;  tj.R[3] = 256; tj.Cc[3] = 256;
    tj.in[4] = fc1_w; tj.out[4] = FCT1; tj.R[4] = 512; tj.Cc[4] = 1024;
    tj.in[5] = fc2_w; tj.out[5] = FCT2; tj.R[5] = 256; tj.Cc[5] = 512;
    transpose_all_kernel<<<dim3(2048, 6), 256, 0, stream>>>(tj);

    run_layer<3, 64>(points, g1, b1, X1, DIST, XX, XP, IDX, Z1, Z2, VMX, VMN, SSUM, SSQ, BNS, BNB, WT1, PMAX, PSUM, 0, big, stream);
    run_layer<64, 64>(X1, g2, b2, X2, DIST, XX, XP, IDX, Z1, Z2, VMX, VMN, SSUM, SSQ, BNS, BNB, WT2, PMAX, PSUM, 64, big, stream);
    run_layer<64, 128>(X2, g3, b3, X3, DIST, XX, XP, IDX, Z1, Z2, VMX, VMN, SSUM, SSQ, BNS, BNB, WT3, PMAX, PSUM, 128, big, stream);
    run_layer<128, 256>(X3, g4, b4, X4, DIST, XX, XP, IDX, Z1, Z2, VMX, VMN, SSUM, SSQ, BNS, BNB, WT4, PMAX, PSUM, 256, big, stream);

    pool_finalize_kernel<<<Bb, 512, 0, stream>>>(PMAX, PSUM, GV);
    head_kernel<<<Bb, 256, 0, stream>>>(GV, FCT1, fc1_b, ln1g, ln1b, FCT2, fc2_b, ln2g, ln2b,
                                        (float*)d_out);
}

// Round 14
// 807.617 us; speedup vs baseline: 1.8289x; 1.0375x over previous
//
#include <hip/hip_runtime.h>
#include <cstdint>
#include <cstddef>

static constexpr int Bb = 8;
static constexpr int Nn = 2048;
static constexpr int Kn = 20;
static constexpr float EPSV = 1e-5f;
static constexpr int JSENT = 1 << 30;

// ---------------------------------------------------------------- utilities

// blocks 0..63: xx[i] = ||x_i||^2 (and packed (x,xx) float4 if xp != null);
// blocks 64..191: zero 32K floats of zp
__global__ void sqnorm_zero_kernel(const float* __restrict__ x, float* __restrict__ xx, int C,
                                   float* __restrict__ zp, float4* __restrict__ xp) {
    int blk = blockIdx.x;
    if (blk < 64) {
        int i = blk * 256 + threadIdx.x;
        const float* xr = x + (size_t)i * C;
        float s = 0.f;
        for (int c = 0; c < C; ++c) { float v = xr[c]; s += v * v; }
        xx[i] = s;
        if (xp) xp[i] = make_float4(xr[0], xr[1], xr[2], s);   // only used for C==3
    } else {
        zp[(blk - 64) * 256 + threadIdx.x] = 0.f;
    }
}

// all weight transposes in one launch: out[c*R + r] = in[r*Cc + c]
struct TransJobs {
    const float* in[6];
    float* out[6];
    int R[6];
    int Cc[6];
};

__global__ void transpose_all_kernel(TransJobs tj) {
    int m = blockIdx.y;
    int i = blockIdx.x * 256 + threadIdx.x;
    int total = tj.R[m] * tj.Cc[m];
    if (i < total) {
        int r = i / tj.Cc[m], c = i % tj.Cc[m];
        tj.out[m][(size_t)c * tj.R[m] + r] = tj.in[m][i];
    }
}

// ------------------------------------------------ pairwise sq-dist (tiled gram)
// SYMMETRIC: only the 136 upper-triangular 128x128 block-pairs are computed;
// off-diagonal blocks emit the mirrored tile through a 32-row LDS transpose
// buffer (bitwise-identical values; 4 chunks x 2 barriers).
// LDS UNION: staging (CT*272 floats) and the T mirror buffer (32*136) are
// never live at the same time -> one 17.4 KB buffer.
// Main loop is the R8 single-buffer form — FROZEN. History:
//   (256,3)/(256,4)  -> accumulator spills to scratch (R5 18x traffic, R6 +270MB)
//   reg prefetch     -> +32 VGPR, occupancy 27->20%, net loss (R7)
//   LDS double-buffer-> VGPR 128, spill, 1.49 GB traffic, 350 us (R9)
// launch_bounds(256,2), plain k-loop, VGPR~68, WRITE exactly 131 MB is the
// verified spill-free optimum. DO NOT add register pressure to this loop.

template<int C>
__global__ __launch_bounds__(256, 2)
void gram_dist_kernel(const float* __restrict__ x, const float* __restrict__ xx,
                      float* __restrict__ dist, int b0, size_t dstride) {
    constexpr int CT = (C < 16) ? C : 16;
    constexpr int SM_FLOATS = (CT * 272 > 32 * 136) ? CT * 272 : 32 * 136;
    const int b = b0 + blockIdx.z;
    // decode upper-tri pair index -> (rblk, cblk), rblk <= cblk, 16x16 tiles
    int p = blockIdx.x, rblk = 0;
    while (p >= 16 - rblk) { p -= 16 - rblk; ++rblk; }
    const int cblk = rblk + p;
    const int i0 = rblk * 128, j0 = cblk * 128;
    const int tid = threadIdx.x;
    const int tx = tid & 15, ty = tid >> 4;
    __shared__ float smem[SM_FLOATS];
    float (*As)[136] = (float (*)[136])smem;
    float (*BsA)[68] = (float (*)[68])(smem + (size_t)CT * 136);
    float (*BsB)[68] = (float (*)[68])(smem + (size_t)CT * 136 + (size_t)CT * 68);
    float (*T)[136]  = (float (*)[136])smem;   // aliases staging; used post-loop only
    float acc[8][8] = {};
    const float* xb = x + (size_t)b * Nn * C;

    const int si = tid & 127;         // staging row
    const int half = tid >> 7;        // 0..1
    float* bbase = ((si & 4) ? &BsB[0][0] : &BsA[0][0]) + (((si >> 3) << 2) | (si & 3));

    for (int c0 = 0; c0 < C; c0 += CT) {
        if constexpr (CT == 16) {
            const float* ra = xb + (size_t)(i0 + si) * C + c0 + half * 8;
            const float* rb = xb + (size_t)(j0 + si) * C + c0 + half * 8;
            float4 a0 = *(const float4*)ra;
            float4 a1 = *(const float4*)(ra + 4);
            float4 bq0 = *(const float4*)rb;
            float4 bq1 = *(const float4*)(rb + 4);
            const int cb = half * 8;
            As[cb + 0][si] = a0.x; As[cb + 1][si] = a0.y;
            As[cb + 2][si] = a0.z; As[cb + 3][si] = a0.w;
            As[cb + 4][si] = a1.x; As[cb + 5][si] = a1.y;
            As[cb + 6][si] = a1.z; As[cb + 7][si] = a1.w;
            bbase[(cb + 0) * 68] = bq0.x; bbase[(cb + 1) * 68] = bq0.y;
            bbase[(cb + 2) * 68] = bq0.z; bbase[(cb + 3) * 68] = bq0.w;
            bbase[(cb + 4) * 68] = bq1.x; bbase[(cb + 5) * 68] = bq1.y;
            bbase[(cb + 6) * 68] = bq1.z; bbase[(cb + 7) * 68] = bq1.w;
        } else {
            if (half == 0) {
                const float* r0 = xb + (size_t)(i0 + si) * C + c0;
#pragma unroll
                for (int c = 0; c < CT; ++c) As[c][si] = r0[c];
            } else {
                const float* r1 = xb + (size_t)(j0 + si) * C + c0;
#pragma unroll
                for (int c = 0; c < CT; ++c) bbase[c * 68] = r1[c];
            }
        }
        __syncthreads();
#pragma unroll
        for (int cc = 0; cc < CT; ++cc) {
            float a[8], bv[8];
            *(float4*)&a[0]  = *(const float4*)&As[cc][ty * 8];
            *(float4*)&a[4]  = *(const float4*)&As[cc][ty * 8 + 4];
            *(float4*)&bv[0] = *(const float4*)&BsA[cc][tx * 4];
            *(float4*)&bv[4] = *(const float4*)&BsB[cc][tx * 4];
#pragma unroll
            for (int u = 0; u < 8; ++u)
#pragma unroll
                for (int v = 0; v < 8; ++v)
                    acc[u][v] = fmaf(a[u], bv[v], acc[u][v]);
        }
        __syncthreads();
    }

    const float* xxb = xx + (size_t)b * Nn;
    float xi[8], xj[8];
#pragma unroll
    for (int u = 0; u < 8; ++u) xi[u] = xxb[i0 + ty * 8 + u];
#pragma unroll
    for (int v = 0; v < 8; ++v) xj[v] = xxb[j0 + tx * 8 + v];
    float* db = dist + (size_t)blockIdx.z * dstride;
#pragma unroll
    for (int u = 0; u < 8; ++u) {
        float* row = db + (size_t)(i0 + ty * 8 + u) * Nn + (j0 + tx * 8);
        float4 o0, o1;
        o0.x = xi[u] + xj[0] - 2.f * acc[u][0];
        o0.y = xi[u] + xj[1] - 2.f * acc[u][1];
        o0.z = xi[u] + xj[2] - 2.f * acc[u][2];
        o0.w = xi[u] + xj[3] - 2.f * acc[u][3];
        o1.x = xi[u] + xj[4] - 2.f * acc[u][4];
        o1.y = xi[u] + xj[5] - 2.f * acc[u][5];
        o1.z = xi[u] + xj[6] - 2.f * acc[u][6];
        o1.w = xi[u] + xj[7] - 2.f * acc[u][7];
        *(float4*)row = o0;
        *(float4*)(row + 4) = o1;
    }

    if (cblk > rblk) {
        // mirror tile (j0.., i0..): value(row=j0+tx*8+v, col=i0+ty*8+u)
        //   = xj[v] + xi[u] - 2*acc[u][v]  (bitwise equal to main tile)
        // 4 chunks of 32 rows; 64 writer-threads per chunk, 8 barriers total.
        const int rr = tid >> 3;            // 0..31 row within 32-row chunk
        const int c4 = (tid & 7) * 4;       // col base (float4 granularity)
#pragma unroll 1
        for (int m = 0; m < 4; ++m) {
            if ((tx >> 2) == m) {
                const int lr = (tx & 3) * 8;
#pragma unroll
                for (int v = 0; v < 8; ++v)
#pragma unroll
                    for (int u = 0; u < 8; ++u)
                        T[lr + v][ty * 8 + u] = xj[v] + xi[u] - 2.f * acc[u][v];
            }
            __syncthreads();
            float* orow = db + (size_t)(j0 + m * 32 + rr) * Nn + i0;
#pragma unroll
            for (int s = 0; s < 4; ++s)
                *(float4*)(orow + c4 + s * 32) = *(const float4*)&T[rr][c4 + s * 32];
            __syncthreads();
        }
    }
}

// ------------------------------------------------------- top-k (k=20 smallest)
// Selection set is exact lex-(v,j) order. Per-lane sorted top-4 with
// "greater-than-last-pop" refill. Rounds: wave64 min via DPP (6 VALU steps,
// no DS latency) + ballot winner pick + SALU readlane broadcast; exact float
// ties (rare) fall back to a DS lex butterfly.

__device__ __forceinline__ bool lex_less(float v1, int j1, float v2, int j2) {
    return v1 < v2 || (v1 == v2 && j1 < j2);
}

template<int CTRL>
__device__ __forceinline__ float dpp_min_step(float v) {
    int x = __float_as_int(v);
    int y = __builtin_amdgcn_update_dpp(x, x, CTRL, 0xf, 0xf, false);
    return fminf(v, __int_as_float(y));
}

// full-wave (64-lane) min; returns the min broadcast to all lanes (SGPR).
__device__ __forceinline__ float wave_min64(float v) {
    v = dpp_min_step<0x111>(v);   // row_shr:1
    v = dpp_min_step<0x112>(v);   // row_shr:2
    v = dpp_min_step<0x114>(v);   // row_shr:4
    v = dpp_min_step<0x118>(v);   // row_shr:8
    v = dpp_min_step<0x142>(v);   // row_bcast:15
    v = dpp_min_step<0x143>(v);   // row_bcast:31
    return __int_as_float(__builtin_amdgcn_readlane(__float_as_int(v), 63));
}

// insert candidate (v,j) into sorted 4-list via select ladder
#define TOP4_INS(v, j)                                                            \
    {                                                                             \
        bool l3 = lex_less(v, j, tv3, tj3);                                       \
        if (l3) {                                                                 \
            bool l2 = lex_less(v, j, tv2, tj2);                                   \
            bool l1 = lex_less(v, j, tv1, tj1);                                   \
            bool l0 = lex_less(v, j, tv0, tj0);                                   \
            tv3 = l2 ? tv2 : v;  tj3 = l2 ? tj2 : j;                              \
            tv2 = l2 ? (l1 ? tv1 : v) : tv2;  tj2 = l2 ? (l1 ? tj1 : j) : tj2;    \
            tv1 = l1 ? (l0 ? tv0 : v) : tv1;  tj1 = l1 ? (l0 ? tj0 : j) : tj1;    \
            tv0 = l0 ? v : tv0;  tj0 = l0 ? j : tj0;                              \
        }                                                                         \
    }

// rebuild sorted top-4 among candidates with (v,j) lex-greater than (lv,lj)
__device__ __forceinline__ void top4_build(const float4* __restrict__ dr4, int lane,
                                           float lv, int lj,
                                           float& tv0, int& tj0, float& tv1, int& tj1,
                                           float& tv2, int& tj2, float& tv3, int& tj3) {
    tv0 = tv1 = tv2 = tv3 = 3e38f;
    tj0 = tj1 = tj2 = tj3 = JSENT;
#pragma unroll
    for (int q = 0; q < 8; ++q) {
        float4 f = dr4[q * 64 + lane];
        float vv[4] = {f.x, f.y, f.z, f.w};
#pragma unroll
        for (int c = 0; c < 4; ++c) {
            int j = (q * 64 + lane) * 4 + c;
            float v = vv[c];
            if (lex_less(lv, lj, v, j)) TOP4_INS(v, j)
        }
    }
}

// shared 20-round selection loop (macro so both kernels reuse it verbatim;
// REBUILD is an expression rebuilding the top-4 with filter (bv,bj)).
// Winners accumulate in per-lane regs -> one coalesced 20-lane store.
#define TOPK_ROUNDS(REBUILD)                                                      \
    int myj = 0;                                                                  \
    for (int t = 0; t < Kn; ++t) {                                                \
        float bv = wave_min64(tv0);                                               \
        unsigned long long tied = __ballot(tv0 == bv);                            \
        int bj;                                                                   \
        if (__popcll(tied) == 1) {                                                \
            int winner = (int)(__ffsll(tied) - 1);                                \
            bj = __builtin_amdgcn_readlane(tj0, winner);                          \
        } else {                                                                  \
            float fv = (tv0 == bv) ? bv : 3e38f;                                  \
            int fj = (tv0 == bv) ? tj0 : JSENT;                                   \
            _Pragma("unroll")                                                     \
            for (int off = 1; off < 64; off <<= 1) {                              \
                float ov = __shfl_xor(fv, off);                                   \
                int oj = __shfl_xor(fj, off);                                     \
                if (lex_less(ov, oj, fv, fj)) { fv = ov; fj = oj; }               \
            }                                                                     \
            bj = fj;                                                              \
        }                                                                         \
        if (lane == t) myj = bj;                                                  \
        if (tv0 == bv && tj0 == bj) {                                             \
            tv0 = tv1; tj0 = tj1; tv1 = tv2; tj1 = tj2;                           \
            tv2 = tv3; tj2 = tj3; tv3 = 3e38f; tj3 = JSENT;                       \
            if (tj0 == JSENT) { REBUILD; }                                        \
        }                                                                         \
    }                                                                             \
    if (lane < Kn) orow[lane] = myj;

__global__ void topk_kernel(const float* __restrict__ dist, int* __restrict__ idxo,
                            int b0, size_t dstride, int rows_per_batch_only) {
    const int w = threadIdx.x >> 6;
    const int lane = threadIdx.x & 63;
    const int lin = blockIdx.x * 4 + w;
    int bz, i;
    if (rows_per_batch_only) { bz = 0; i = lin; }
    else { bz = lin >> 11; i = lin & (Nn - 1); }
    const int b = b0 + bz;
    const float4* dr4 = (const float4*)(dist + (size_t)bz * dstride + (size_t)i * Nn);

    float tv0, tv1, tv2, tv3;
    int tj0, tj1, tj2, tj3;
    top4_build(dr4, lane, -3e38f, -1, tv0, tj0, tv1, tj1, tv2, tj2, tv3, tj3);

    int* orow = idxo + ((size_t)b * Nn + i) * Kn;
    TOPK_ROUNDS(top4_build(dr4, lane, bv, bj, tv0, tj0, tv1, tj1, tv2, tj2, tv3, tj3))
}

// -------- layer-1 fused top-k: dist computed inline from packed (x,xx) float4.
// Candidate mapping j = m*64 + lane -> lane-adjacent candidates are consecutive
// float4s => coalesced 1KB wave loads. FMA chain shape matches gram's CT=3
// path exactly (acc=fmaf(a,b,acc) over increasing c, then xx_i+xx_j-2.f*acc)
// -> same values, same selection.

__device__ __forceinline__ void top4_build_c3(const float4* __restrict__ xpb,
                                              float xi0, float xi1, float xi2, float xxi,
                                              int lane, float lv, int lj,
                                              float& tv0, int& tj0, float& tv1, int& tj1,
                                              float& tv2, int& tj2, float& tv3, int& tj3) {
    tv0 = tv1 = tv2 = tv3 = 3e38f;
    tj0 = tj1 = tj2 = tj3 = JSENT;
#pragma unroll
    for (int m = 0; m < 32; ++m) {
        int j = m * 64 + lane;
        float4 f = xpb[j];
        float acc = 0.f;
        acc = fmaf(xi0, f.x, acc);
        acc = fmaf(xi1, f.y, acc);
        acc = fmaf(xi2, f.z, acc);
        float v = xxi + f.w - 2.f * acc;
        if (lex_less(lv, lj, v, j)) TOP4_INS(v, j)
    }
}

__global__ void topk_c3_kernel(const float4* __restrict__ xp, int* __restrict__ idxo,
                               int b0, int rows_per_batch_only) {
    const int w = threadIdx.x >> 6;
    const int lane = threadIdx.x & 63;
    const int lin = blockIdx.x * 4 + w;
    int bz, i;
    if (rows_per_batch_only) { bz = 0; i = lin; }
    else { bz = lin >> 11; i = lin & (Nn - 1); }
    const int b = b0 + bz;
    const float4* xpb = xp + (size_t)b * Nn;
    const float4 fi = xpb[i];
    const float xi0 = fi.x, xi1 = fi.y, xi2 = fi.z, xxi = fi.w;

    float tv0, tv1, tv2, tv3;
    int tj0, tj1, tj2, tj3;
    top4_build_c3(xpb, xi0, xi1, xi2, xxi, lane, -3e38f, -1,
                  tv0, tj0, tv1, tj1, tv2, tj2, tv3, tj3);

    int* orow = idxo + ((size_t)b * Nn + i) * Kn;
    TOPK_ROUNDS(top4_build_c3(xpb, xi0, xi1, xi2, xxi, lane, bv, bj, \
                              tv0, tj0, tv1, tj1, tv2, tj2, tv3, tj3))
}

// ------------------------------------- per-point projections Z1=X Wl^T, Z2=X Wr^T

template<int C, int O>
__global__ void z_kernel(const float* __restrict__ x, const float* __restrict__ wt,
                         float* __restrict__ z1, float* __restrict__ z2) {
    constexpr int TP = 16;
    constexpr int G = 256 / O;
    constexpr int PP = TP / G;
    const int p0 = blockIdx.x * TP;
    const int tid = threadIdx.x;
    const int oo = tid % O;
    const int g = tid / O;
    __shared__ float xs[TP][(C < 4) ? 4 : C];
    for (int e = tid; e < TP * C; e += 256) {
        int p = e / C, c = e % C;
        xs[p][c] = x[(size_t)(p0 + p) * C + c];
    }
    __syncthreads();
    float a1[PP], a2[PP];
#pragma unroll
    for (int p = 0; p < PP; ++p) { a1[p] = 0.f; a2[p] = 0.f; }
    if constexpr (C % 4 == 0) {
        for (int c = 0; c < C; c += 4) {
            float w1[4], w2[4];
#pragma unroll
            for (int q = 0; q < 4; ++q) {
                w1[q] = wt[(size_t)(c + q) * O + oo];
                w2[q] = wt[(size_t)(C + c + q) * O + oo];
            }
#pragma unroll
            for (int p = 0; p < PP; ++p) {
                const float4 xv = *(const float4*)(&xs[g * PP + p][c]);
                a1[p] = fmaf(xv.w, w1[3], fmaf(xv.z, w1[2], fmaf(xv.y, w1[1], fmaf(xv.x, w1[0], a1[p]))));
                a2[p] = fmaf(xv.w, w2[3], fmaf(xv.z, w2[2], fmaf(xv.y, w2[1], fmaf(xv.x, w2[0], a2[p]))));
            }
        }
    } else {
        for (int c = 0; c < C; ++c) {
            float w1 = wt[(size_t)c * O + oo];
            float w2 = wt[(size_t)(C + c) * O + oo];
#pragma unroll
            for (int p = 0; p < PP; ++p) {
                float xv = xs[g * PP + p][c];
                a1[p] = fmaf(xv, w1, a1[p]);
                a2[p] = fmaf(xv, w2, a2[p]);
            }
        }
    }
#pragma unroll
    for (int p = 0; p < PP; ++p) {
        size_t row = (size_t)(p0 + g * PP + p) * O + oo;
        z1[row] = a1[p];
        z2[row] = a2[p];
    }
}

// -------------------- gather edges, max/min over k + BN partial sums
// float4 per thread; each gathered row = one coalesced wave transaction.

template<int O>
__global__ void edge_stats_kernel(const float* __restrict__ z1, const float* __restrict__ z2,
                                  const int* __restrict__ idx,
                                  float* __restrict__ vmax, float* __restrict__ vmin,
                                  float* __restrict__ ssum, float* __restrict__ ssq) {
    constexpr int TPP = O / 4;           // threads per point
    constexpr int PPB = 256 / TPP;       // points per block
    const int p0 = blockIdx.x * PPB;
    const int tid = threadIdx.x;
    const int q = tid % TPP;
    const int p = tid / TPP;
    const int oo = q * 4;
    __shared__ int jl[PPB][Kn];
    for (int e = tid; e < PPB * Kn; e += 256)
        jl[e / Kn][e % Kn] = idx[(size_t)(p0 + e / Kn) * Kn + (e % Kn)];
    __syncthreads();
    const int bi = p0 + p;
    const int b = bi >> 11;
    const float4 zi1 = *(const float4*)(z1 + (size_t)bi * O + oo);
    const float4 zi2 = *(const float4*)(z2 + (size_t)bi * O + oo);
    float ax = zi2.x - zi1.x, ay = zi2.y - zi1.y, az = zi2.z - zi1.z, aw = zi2.w - zi1.w;
    float mxx = -3e38f, mxy = -3e38f, mxz = -3e38f, mxw = -3e38f;
    float mnx = 3e38f, mny = 3e38f, mnz = 3e38f, mnw = 3e38f;
    float sx = 0.f, sy = 0.f, sz = 0.f, sw = 0.f;
    float qx = 0.f, qy = 0.f, qz = 0.f, qw = 0.f;
    const float* zbase = z1 + ((size_t)b * Nn) * O + oo;
#pragma unroll
    for (int kk = 0; kk < Kn; ++kk) {
        int j = jl[p][kk];
        float4 v = *(const float4*)(zbase + (size_t)j * O);
        v.x += ax; v.y += ay; v.z += az; v.w += aw;
        mxx = fmaxf(mxx, v.x); mxy = fmaxf(mxy, v.y); mxz = fmaxf(mxz, v.z); mxw = fmaxf(mxw, v.w);
        mnx = fminf(mnx, v.x); mny = fminf(mny, v.y); mnz = fminf(mnz, v.z); mnw = fminf(mnw, v.w);
        sx += v.x; sy += v.y; sz += v.z; sw += v.w;
        qx = fmaf(v.x, v.x, qx); qy = fmaf(v.y, v.y, qy);
        qz = fmaf(v.z, v.z, qz); qw = fmaf(v.w, v.w, qw);
    }
    float4 mx4 = make_float4(mxx, mxy, mxz, mxw);
    float4 mn4 = make_float4(mnx, mny, mnz, mnw);
    *(float4*)(vmax + (size_t)bi * O + oo) = mx4;
    *(float4*)(vmin + (size_t)bi * O + oo) = mn4;
    __shared__ float4 ssm[256], sqq[256];
    ssm[tid] = make_float4(sx, sy, sz, sw);
    sqq[tid] = make_float4(qx, qy, qz, qw);
    __syncthreads();
    if (p == 0) {
#pragma unroll 4
        for (int pp = 1; pp < PPB; ++pp) {
            float4 s4 = ssm[pp * TPP + q];
            float4 q4 = sqq[pp * TPP + q];
            sx += s4.x; sy += s4.y; sz += s4.z; sw += s4.w;
            qx += q4.x; qy += q4.y; qz += q4.z; qw += q4.w;
        }
        int slot = blockIdx.x & 63;
        atomicAdd(&ssum[slot * O + oo + 0], sx);
        atomicAdd(&ssum[slot * O + oo + 1], sy);
        atomicAdd(&ssum[slot * O + oo + 2], sz);
        atomicAdd(&ssum[slot * O + oo + 3], sw);
        atomicAdd(&ssq[slot * O + oo + 0], qx);
        atomicAdd(&ssq[slot * O + oo + 1], qy);
        atomicAdd(&ssq[slot * O + oo + 2], qz);
        atomicAdd(&ssq[slot * O + oo + 3], qw);
    }
}

__global__ void bn_finalize_kernel(const float* __restrict__ ssum, const float* __restrict__ ssq,
                                   const float* __restrict__ gamma, const float* __restrict__ beta,
                                   float* __restrict__ scale, float* __restrict__ shift, int O) {
    int o = threadIdx.x;
    if (o >= O) return;
    float s = 0.f, q = 0.f;
    for (int sl = 0; sl < 64; ++sl) { s += ssum[sl * O + o]; q += ssq[sl * O + o]; }
    const float cnt = (float)Bb * (float)Nn * (float)Kn;
    float mu = s / cnt;
    float var = q / cnt - mu * mu;
    float sc = gamma[o] / sqrtf(var + EPSV);
    scale[o] = sc;
    shift[o] = beta[o] - mu * sc;
}

// ---------------- BN-apply + relu + per-chunk pooling partials (float4)

template<int O>
__global__ void apply_pool_kernel(const float* __restrict__ vmax, const float* __restrict__ vmin,
                                  const float* __restrict__ scale, const float* __restrict__ shift,
                                  float* __restrict__ xout,
                                  float* __restrict__ pmax, float* __restrict__ psum, int obase) {
    constexpr int TPP = O / 4;
    constexpr int PP2 = 256 / TPP;      // points concurrent
    constexpr int S = 128 / PP2;        // iterations
    const int chunk = blockIdx.x;
    const int b = blockIdx.y;
    const int tid = threadIdx.x;
    const int q = tid % TPP;
    const int g = tid / TPP;
    const int oo = q * 4;
    const float4 sc = *(const float4*)(scale + oo);
    const float4 sh = *(const float4*)(shift + oo);
    float pmx = -3e38f, pmy = -3e38f, pmz = -3e38f, pmw = -3e38f;
    float psx = 0.f, psy = 0.f, psz = 0.f, psw = 0.f;
    const int n0 = chunk * 128;
    for (int s = 0; s < S; ++s) {
        int n = n0 + g + s * PP2;
        size_t ix = ((size_t)b * Nn + n) * O + oo;
        float4 vx = *(const float4*)(vmax + ix);
        float4 vn = *(const float4*)(vmin + ix);
        float4 r;
        r.x = fmaxf(fmaf(sc.x >= 0.f ? vx.x : vn.x, sc.x, sh.x), 0.f);
        r.y = fmaxf(fmaf(sc.y >= 0.f ? vx.y : vn.y, sc.y, sh.y), 0.f);
        r.z = fmaxf(fmaf(sc.z >= 0.f ? vx.z : vn.z, sc.z, sh.z), 0.f);
        r.w = fmaxf(fmaf(sc.w >= 0.f ? vx.w : vn.w, sc.w, sh.w), 0.f);
        *(float4*)(xout + ix) = r;
        pmx = fmaxf(pmx, r.x); pmy = fmaxf(pmy, r.y);
        pmz = fmaxf(pmz, r.z); pmw = fmaxf(pmw, r.w);
        psx += r.x; psy += r.y; psz += r.z; psw += r.w;
    }
    __shared__ float4 sm[256], ss2[256];
    sm[tid] = make_float4(pmx, pmy, pmz, pmw);
    ss2[tid] = make_float4(psx, psy, psz, psw);
    __syncthreads();
    if (g == 0) {
#pragma unroll 4
        for (int gg = 1; gg < PP2; ++gg) {
            float4 m4 = sm[gg * TPP + q];
            float4 s4 = ss2[gg * TPP + q];
            pmx = fmaxf(pmx, m4.x); pmy = fmaxf(pmy, m4.y);
            pmz = fmaxf(pmz, m4.z); pmw = fmaxf(pmw, m4.w);
            psx += s4.x; psy += s4.y; psz += s4.z; psw += s4.w;
        }
        size_t pb = ((size_t)b * 16 + chunk) * 512 + obase + oo;
        *(float4*)(pmax + pb) = make_float4(pmx, pmy, pmz, pmw);
        *(float4*)(psum + pb) = make_float4(psx, psy, psz, psw);
    }
}

__global__ void pool_finalize_kernel(const float* __restrict__ pmax, const float* __restrict__ psum,
                                     float* __restrict__ gv) {
    const int b = blockIdx.x;
    const int c = threadIdx.x;          // 512 threads
    float mx = -3e38f, s = 0.f;
    for (int ch = 0; ch < 16; ++ch) {
        size_t p = ((size_t)b * 16 + ch) * 512 + c;
        mx = fmaxf(mx, pmax[p]);
        s += psum[p];
    }
    gv[b * 1024 + c] = mx;
    gv[b * 1024 + 512 + c] = s * (1.f / (float)Nn);
}

// ------------------------------------------------------------------- MLP head

__global__ void head_kernel(const float* __restrict__ gv,
                            const float* __restrict__ fct1, const float* __restrict__ fc1b,
                            const float* __restrict__ ln1g, const float* __restrict__ ln1b,
                            const float* __restrict__ fct2, const float* __restrict__ fc2b,
                            const float* __restrict__ ln2g, const float* __restrict__ ln2b,
                            float* __restrict__ out) {
    const int b = blockIdx.x;
    const int tid = threadIdx.x;
    __shared__ float gx[1024];
    __shared__ float hh[512];
    __shared__ float red[256];
    for (int e = tid; e < 1024; e += 256) gx[e] = gv[b * 1024 + e];
    __syncthreads();
    float h0 = fc1b[tid], h1 = fc1b[tid + 256];
    for (int c = 0; c < 1024; ++c) {
        float gc = gx[c];
        h0 = fmaf(gc, fct1[(size_t)c * 512 + tid], h0);
        h1 = fmaf(gc, fct1[(size_t)c * 512 + tid + 256], h1);
    }
    red[tid] = h0 + h1;
    __syncthreads();
    for (int st = 128; st > 0; st >>= 1) { if (tid < st) red[tid] += red[tid + st]; __syncthreads(); }
    float mu = red[0] * (1.f / 512.f);
    __syncthreads();
    float d0 = h0 - mu, d1 = h1 - mu;
    red[tid] = d0 * d0 + d1 * d1;
    __syncthreads();
    for (int st = 128; st > 0; st >>= 1) { if (tid < st) red[tid] += red[tid + st]; __syncthreads(); }
    float rs = 1.f / sqrtf(red[0] * (1.f / 512.f) + EPSV);
    __syncthreads();
    hh[tid]       = fmaxf(d0 * rs * ln1g[tid] + ln1b[tid], 0.f);
    hh[tid + 256] = fmaxf(d1 * rs * ln1g[tid + 256] + ln1b[tid + 256], 0.f);
    __syncthreads();
    float z = fc2b[tid];
    for (int c = 0; c < 512; ++c) z = fmaf(hh[c], fct2[(size_t)c * 256 + tid], z);
    red[tid] = z;
    __syncthreads();
    for (int st = 128; st > 0; st >>= 1) { if (tid < st) red[tid] += red[tid + st]; __syncthreads(); }
    float mu2 = red[0] * (1.f / 256.f);
    __syncthreads();
    float dz = z - mu2;
    red[tid] = dz * dz;
    __syncthreads();
    for (int st = 128; st > 0; st >>= 1) { if (tid < st) red[tid] += red[tid + st]; __syncthreads(); }
    float rs2 = 1.f / sqrtf(red[0] * (1.f / 256.f) + EPSV);
    out[b * 256 + tid] = dz * rs2 * ln2g[tid] + ln2b[tid];
}

// --------------------------------------------------------------- layer driver

template<int C, int O>
static void run_layer(const float* x, const float* gamma, const float* beta,
                      float* xout, float* DIST, float* XX, float4* XP, int* IDX,
                      float* Z1, float* Z2,
                      float* VMX, float* VMN, float* SSUM, float* SSQ, float* BNS, float* BNB,
                      const float* WT, float* PMAX, float* PSUM, int obase, bool big,
                      hipStream_t stream) {
    sqnorm_zero_kernel<<<192, 256, 0, stream>>>(x, XX, C, SSUM, (C == 3) ? XP : nullptr);
    z_kernel<C, O><<<Bb * Nn / 16, 256, 0, stream>>>(x, WT, Z1, Z2);
    if constexpr (C == 3) {
        // layer 1: packed (x,xx) is L1-resident (32 KB/batch) -> fused
        // inline-dist top-k, no gram dispatch, no DIST write+read.
        if (big) {
            topk_c3_kernel<<<Bb * Nn / 4, 256, 0, stream>>>(XP, IDX, 0, 0);
        } else {
            for (int b = 0; b < Bb; ++b)
                topk_c3_kernel<<<Nn / 4, 256, 0, stream>>>(XP, IDX, b, 1);
        }
    } else {
        if (big) {
            gram_dist_kernel<C><<<dim3(136, 1, Bb), 256, 0, stream>>>(x, XX, DIST, 0, (size_t)Nn * Nn);
            topk_kernel<<<Bb * Nn / 4, 256, 0, stream>>>(DIST, IDX, 0, (size_t)Nn * Nn, 0);
        } else {
            for (int b = 0; b < Bb; ++b) {
                gram_dist_kernel<C><<<dim3(136, 1, 1), 256, 0, stream>>>(x, XX, DIST, b, 0);
                topk_kernel<<<Nn / 4, 256, 0, stream>>>(DIST, IDX, b, 0, 1);
            }
        }
    }
    edge_stats_kernel<O><<<Bb * Nn / (1024 / O), 256, 0, stream>>>(Z1, Z2, IDX, VMX, VMN, SSUM, SSQ);
    bn_finalize_kernel<<<1, 256, 0, stream>>>(SSUM, SSQ, gamma, beta, BNS, BNB, O);
    apply_pool_kernel<O><<<dim3(16, 8), 256, 0, stream>>>(VMX, VMN, BNS, BNB, xout, PMAX, PSUM, obase);
}

extern "C" void kernel_launch(void* const* d_in, const int* in_sizes, int n_in,
                              void* d_out, int out_size, void* d_ws, size_t ws_size,
                              hipStream_t stream) {
    const float* points = (const float*)d_in[0];
    const float* W1 = (const float*)d_in[1];
    const float* g1 = (const float*)d_in[2];
    const float* b1 = (const float*)d_in[3];
    const float* W2 = (const float*)d_in[4];
    const float* g2 = (const float*)d_in[5];
    const float* b2 = (const float*)d_in[6];
    const float* W3 = (const float*)d_in[7];
    const float* g3 = (const float*)d_in[8];
    const float* b3 = (const float*)d_in[9];
    const float* W4 = (const float*)d_in[10];
    const float* g4 = (const float*)d_in[11];
    const float* b4 = (const float*)d_in[12];
    const float* fc1_w = (const float*)d_in[13];
    const float* fc1_b = (const float*)d_in[14];
    const float* ln1g = (const float*)d_in[15];
    const float* ln1b = (const float*)d_in[16];
    const float* fc2_w = (const float*)d_in[17];
    const float* fc2_b = (const float*)d_in[18];
    const float* ln2g = (const float*)d_in[19];
    const float* ln2b = (const float*)d_in[20];

    float* ws = (float*)d_ws;
    const size_t BN = (size_t)Bb * Nn;
    const bool big = ws_size >= (size_t)59826688 * 4;

    size_t off = 0;
    auto take = [&](size_t n) { size_t o = off; off += n; return o; };
    float* DIST = ws + take(big ? (size_t)Bb * Nn * Nn : (size_t)Nn * Nn);
    float* XX   = ws + take(BN);
    float4* XP  = (float4*)(ws + take(BN * 4));
    int*   IDX  = (int*)(ws + take(BN * Kn));
    float* Z1   = ws + take(BN * 256);
    float* Z2   = ws + take(BN * 256);
    float* VMX  = ws + take(BN * 256);
    float* VMN  = ws + take(BN * 256);
    float* SSUM = ws + take(64 * 256);
    float* SSQ  = ws + take(64 * 256);
    float* BNS  = ws + take(256);
    float* BNB  = ws + take(256);
    float* WT1  = ws + take(384);
    float* WT2  = ws + take(8192);
    float* WT3  = ws + take(16384);
    float* WT4  = ws + take(65536);
    float* FCT1 = ws + take(524288);
    float* FCT2 = ws + take(131072);
    float* X1   = ws + take(BN * 64);
    float* X2   = ws + take(BN * 64);
    float* X3   = ws + take(BN * 128);
    float* X4   = ws + take(BN * 256);
    float* GV   = ws + take((size_t)Bb * 1024);
    float* PMAX = ws + take((size_t)Bb * 16 * 512);
    float* PSUM = ws + take((size_t)Bb * 16 * 512);

    // All weight transposes in one launch (independent of layer outputs).
    TransJobs tj;
    tj.in[0] = W1;    tj.out[0] = WT1;  tj.R[0] = 64;  tj.Cc[0] = 6;
    tj.in[1] = W2;    tj.out[1] = WT2;  tj.R[1] = 64;  tj.Cc[1] = 128;
    tj.in[2] = W3;    tj.out[2] = WT3;  tj.R[2] = 128; tj.Cc[2] = 128;
    tj.in[3] = W4;    tj.out[3] = WT4;  tj.R[3] = 256; tj.Cc[3] = 256;
    tj.in[4] = fc1_w; tj.out[4] = FCT1; tj.R[4] = 512; tj.Cc[4] = 1024;
    tj.in[5] = fc2_w; tj.out[5] = FCT2; tj.R[5] = 256; tj.Cc[5] = 512;
    transpose_all_kernel<<<dim3(2048, 6), 256, 0, stream>>>(tj);

    run_layer<3, 64>(points, g1, b1, X1, DIST, XX, XP, IDX, Z1, Z2, VMX, VMN, SSUM, SSQ, BNS, BNB, WT1, PMAX, PSUM, 0, big, stream);
    run_layer<64, 64>(X1, g2, b2, X2, DIST, XX, XP, IDX, Z1, Z2, VMX, VMN, SSUM, SSQ, BNS, BNB, WT2, PMAX, PSUM, 64, big, stream);
    run_layer<64, 128>(X2, g3, b3, X3, DIST, XX, XP, IDX, Z1, Z2, VMX, VMN, SSUM, SSQ, BNS, BNB, WT3, PMAX, PSUM, 128, big, stream);
    run_layer<128, 256>(X3, g4, b4, X4, DIST, XX, XP, IDX, Z1, Z2, VMX, VMN, SSUM, SSQ, BNS, BNB, WT4, PMAX, PSUM, 256, big, stream);

    pool_finalize_kernel<<<Bb, 512, 0, stream>>>(PMAX, PSUM, GV);
    head_kernel<<<Bb, 256, 0, stream>>>(GV, FCT1, fc1_b, ln1g, ln1b, FCT2, fc2_b, ln2g, ln2b,
                                        (float*)d_out);
}

// Round 15
// 767.786 us; speedup vs baseline: 1.9238x; 1.0519x over previous
//
#include <hip/hip_runtime.h>
#include <cstdint>
#include <cstddef>

static constexpr int Bb = 8;
static constexpr int Nn = 2048;
static constexpr int Kn = 20;
static constexpr float EPSV = 1e-5f;
static constexpr int JSENT = 1 << 30;

// ---------------------------------------------------------------- utilities

// all weight transposes in one launch: out[c*R + r] = in[r*Cc + c]
struct TransJobs {
    const float* in[6];
    float* out[6];
    int R[6];
    int Cc[6];
};

__global__ void transpose_all_kernel(TransJobs tj) {
    int m = blockIdx.y;
    int i = blockIdx.x * 256 + threadIdx.x;
    int total = tj.R[m] * tj.Cc[m];
    if (i < total) {
        int r = i / tj.Cc[m], c = i % tj.Cc[m];
        tj.out[m][(size_t)c * tj.R[m] + r] = tj.in[m][i];
    }
}

// ------------------- fused per-layer prep: z-projection + sqnorm + stat-zero
// blocks [0,1024): Z1/Z2 projection for a 16-point tile
// blocks [1024,1088): xx[i] (+ packed (x,xx) float4 when C==3)
// blocks [1088,1216): zero the 32K-float SSUM+SSQ region

template<int C, int O>
__global__ void prep_kernel(const float* __restrict__ x, const float* __restrict__ wt,
                            float* __restrict__ z1, float* __restrict__ z2,
                            float* __restrict__ xx, float4* __restrict__ xp,
                            float* __restrict__ zp) {
    const int blk = blockIdx.x;
    const int tid = threadIdx.x;
    if (blk >= 1088) {
        zp[(blk - 1088) * 256 + tid] = 0.f;
        return;
    }
    if (blk >= 1024) {
        int i = (blk - 1024) * 256 + tid;
        const float* xr = x + (size_t)i * C;
        float s = 0.f;
        for (int c = 0; c < C; ++c) { float v = xr[c]; s += v * v; }
        xx[i] = s;
        if (C == 3) xp[i] = make_float4(xr[0], xr[1], xr[2], s);
        return;
    }
    // z projection
    constexpr int TP = 16;
    constexpr int G = 256 / O;
    constexpr int PP = TP / G;
    const int p0 = blk * TP;
    const int oo = tid % O;
    const int g = tid / O;
    __shared__ float xs[TP][(C < 4) ? 4 : C];
    for (int e = tid; e < TP * C; e += 256) {
        int p = e / C, c = e % C;
        xs[p][c] = x[(size_t)(p0 + p) * C + c];
    }
    __syncthreads();
    float a1[PP], a2[PP];
#pragma unroll
    for (int p = 0; p < PP; ++p) { a1[p] = 0.f; a2[p] = 0.f; }
    if constexpr (C % 4 == 0) {
        for (int c = 0; c < C; c += 4) {
            float w1[4], w2[4];
#pragma unroll
            for (int q = 0; q < 4; ++q) {
                w1[q] = wt[(size_t)(c + q) * O + oo];
                w2[q] = wt[(size_t)(C + c + q) * O + oo];
            }
#pragma unroll
            for (int p = 0; p < PP; ++p) {
                const float4 xv = *(const float4*)(&xs[g * PP + p][c]);
                a1[p] = fmaf(xv.w, w1[3], fmaf(xv.z, w1[2], fmaf(xv.y, w1[1], fmaf(xv.x, w1[0], a1[p]))));
                a2[p] = fmaf(xv.w, w2[3], fmaf(xv.z, w2[2], fmaf(xv.y, w2[1], fmaf(xv.x, w2[0], a2[p]))));
            }
        }
    } else {
        for (int c = 0; c < C; ++c) {
            float w1 = wt[(size_t)c * O + oo];
            float w2 = wt[(size_t)(C + c) * O + oo];
#pragma unroll
            for (int p = 0; p < PP; ++p) {
                float xv = xs[g * PP + p][c];
                a1[p] = fmaf(xv, w1, a1[p]);
                a2[p] = fmaf(xv, w2, a2[p]);
            }
        }
    }
#pragma unroll
    for (int p = 0; p < PP; ++p) {
        size_t row = (size_t)(p0 + g * PP + p) * O + oo;
        z1[row] = a1[p];
        z2[row] = a2[p];
    }
}

// ------------------------------------------------ pairwise sq-dist (tiled gram)
// SYMMETRIC: only the 136 upper-triangular 128x128 block-pairs are computed;
// off-diagonal blocks emit the mirrored tile through a 32-row LDS transpose
// buffer (bitwise-identical values; 4 chunks x 2 barriers).
// LDS UNION: staging (CT*272 floats) and the T mirror buffer (32*136) are
// never live at the same time -> one 17.4 KB buffer.
// Main loop is the R8 single-buffer form — FROZEN. History:
//   (256,3)/(256,4)  -> accumulator spills to scratch (R5 18x traffic, R6 +270MB)
//   reg prefetch     -> +32 VGPR, occupancy 27->20%, net loss (R7)
//   LDS double-buffer-> VGPR 128, spill, 1.49 GB traffic, 350 us (R9)
// launch_bounds(256,2), plain k-loop, VGPR~72, WRITE exactly 131 MB is the
// verified spill-free optimum. DO NOT add register pressure to this loop.

template<int C>
__global__ __launch_bounds__(256, 2)
void gram_dist_kernel(const float* __restrict__ x, const float* __restrict__ xx,
                      float* __restrict__ dist, int b0, size_t dstride) {
    constexpr int CT = (C < 16) ? C : 16;
    constexpr int SM_FLOATS = (CT * 272 > 32 * 136) ? CT * 272 : 32 * 136;
    const int b = b0 + blockIdx.z;
    // decode upper-tri pair index -> (rblk, cblk), rblk <= cblk, 16x16 tiles
    int p = blockIdx.x, rblk = 0;
    while (p >= 16 - rblk) { p -= 16 - rblk; ++rblk; }
    const int cblk = rblk + p;
    const int i0 = rblk * 128, j0 = cblk * 128;
    const int tid = threadIdx.x;
    const int tx = tid & 15, ty = tid >> 4;
    __shared__ float smem[SM_FLOATS];
    float (*As)[136] = (float (*)[136])smem;
    float (*BsA)[68] = (float (*)[68])(smem + (size_t)CT * 136);
    float (*BsB)[68] = (float (*)[68])(smem + (size_t)CT * 136 + (size_t)CT * 68);
    float (*T)[136]  = (float (*)[136])smem;   // aliases staging; used post-loop only
    float acc[8][8] = {};
    const float* xb = x + (size_t)b * Nn * C;

    const int si = tid & 127;         // staging row
    const int half = tid >> 7;        // 0..1
    float* bbase = ((si & 4) ? &BsB[0][0] : &BsA[0][0]) + (((si >> 3) << 2) | (si & 3));

    for (int c0 = 0; c0 < C; c0 += CT) {
        if constexpr (CT == 16) {
            const float* ra = xb + (size_t)(i0 + si) * C + c0 + half * 8;
            const float* rb = xb + (size_t)(j0 + si) * C + c0 + half * 8;
            float4 a0 = *(const float4*)ra;
            float4 a1 = *(const float4*)(ra + 4);
            float4 bq0 = *(const float4*)rb;
            float4 bq1 = *(const float4*)(rb + 4);
            const int cb = half * 8;
            As[cb + 0][si] = a0.x; As[cb + 1][si] = a0.y;
            As[cb + 2][si] = a0.z; As[cb + 3][si] = a0.w;
            As[cb + 4][si] = a1.x; As[cb + 5][si] = a1.y;
            As[cb + 6][si] = a1.z; As[cb + 7][si] = a1.w;
            bbase[(cb + 0) * 68] = bq0.x; bbase[(cb + 1) * 68] = bq0.y;
            bbase[(cb + 2) * 68] = bq0.z; bbase[(cb + 3) * 68] = bq0.w;
            bbase[(cb + 4) * 68] = bq1.x; bbase[(cb + 5) * 68] = bq1.y;
            bbase[(cb + 6) * 68] = bq1.z; bbase[(cb + 7) * 68] = bq1.w;
        } else {
            if (half == 0) {
                const float* r0 = xb + (size_t)(i0 + si) * C + c0;
#pragma unroll
                for (int c = 0; c < CT; ++c) As[c][si] = r0[c];
            } else {
                const float* r1 = xb + (size_t)(j0 + si) * C + c0;
#pragma unroll
                for (int c = 0; c < CT; ++c) bbase[c * 68] = r1[c];
            }
        }
        __syncthreads();
#pragma unroll
        for (int cc = 0; cc < CT; ++cc) {
            float a[8], bv[8];
            *(float4*)&a[0]  = *(const float4*)&As[cc][ty * 8];
            *(float4*)&a[4]  = *(const float4*)&As[cc][ty * 8 + 4];
            *(float4*)&bv[0] = *(const float4*)&BsA[cc][tx * 4];
            *(float4*)&bv[4] = *(const float4*)&BsB[cc][tx * 4];
#pragma unroll
            for (int u = 0; u < 8; ++u)
#pragma unroll
                for (int v = 0; v < 8; ++v)
                    acc[u][v] = fmaf(a[u], bv[v], acc[u][v]);
        }
        __syncthreads();
    }

    const float* xxb = xx + (size_t)b * Nn;
    float xi[8], xj[8];
#pragma unroll
    for (int u = 0; u < 8; ++u) xi[u] = xxb[i0 + ty * 8 + u];
#pragma unroll
    for (int v = 0; v < 8; ++v) xj[v] = xxb[j0 + tx * 8 + v];
    float* db = dist + (size_t)blockIdx.z * dstride;
#pragma unroll
    for (int u = 0; u < 8; ++u) {
        float* row = db + (size_t)(i0 + ty * 8 + u) * Nn + (j0 + tx * 8);
        float4 o0, o1;
        o0.x = xi[u] + xj[0] - 2.f * acc[u][0];
        o0.y = xi[u] + xj[1] - 2.f * acc[u][1];
        o0.z = xi[u] + xj[2] - 2.f * acc[u][2];
        o0.w = xi[u] + xj[3] - 2.f * acc[u][3];
        o1.x = xi[u] + xj[4] - 2.f * acc[u][4];
        o1.y = xi[u] + xj[5] - 2.f * acc[u][5];
        o1.z = xi[u] + xj[6] - 2.f * acc[u][6];
        o1.w = xi[u] + xj[7] - 2.f * acc[u][7];
        *(float4*)row = o0;
        *(float4*)(row + 4) = o1;
    }

    if (cblk > rblk) {
        // mirror tile (j0.., i0..): value(row=j0+tx*8+v, col=i0+ty*8+u)
        //   = xj[v] + xi[u] - 2*acc[u][v]  (bitwise equal to main tile)
        // 4 chunks of 32 rows; 64 writer-threads per chunk, 8 barriers total.
        const int rr = tid >> 3;            // 0..31 row within 32-row chunk
        const int c4 = (tid & 7) * 4;       // col base (float4 granularity)
#pragma unroll 1
        for (int m = 0; m < 4; ++m) {
            if ((tx >> 2) == m) {
                const int lr = (tx & 3) * 8;
#pragma unroll
                for (int v = 0; v < 8; ++v)
#pragma unroll
                    for (int u = 0; u < 8; ++u)
                        T[lr + v][ty * 8 + u] = xj[v] + xi[u] - 2.f * acc[u][v];
            }
            __syncthreads();
            float* orow = db + (size_t)(j0 + m * 32 + rr) * Nn + i0;
#pragma unroll
            for (int s = 0; s < 4; ++s)
                *(float4*)(orow + c4 + s * 32) = *(const float4*)&T[rr][c4 + s * 32];
            __syncthreads();
        }
    }
}

// ------------------------------------------------------- top-k (k=20 smallest)
// Selection set is exact lex-(v,j) order. Per-lane sorted top-4 with
// "greater-than-last-pop" refill. Rounds: wave64 min via DPP (6 VALU steps,
// no DS latency) + ballot winner pick + SALU readlane broadcast; exact float
// ties (rare) fall back to a DS lex butterfly.

__device__ __forceinline__ bool lex_less(float v1, int j1, float v2, int j2) {
    return v1 < v2 || (v1 == v2 && j1 < j2);
}

template<int CTRL>
__device__ __forceinline__ float dpp_min_step(float v) {
    int x = __float_as_int(v);
    int y = __builtin_amdgcn_update_dpp(x, x, CTRL, 0xf, 0xf, false);
    return fminf(v, __int_as_float(y));
}

// full-wave (64-lane) min; returns the min broadcast to all lanes (SGPR).
__device__ __forceinline__ float wave_min64(float v) {
    v = dpp_min_step<0x111>(v);   // row_shr:1
    v = dpp_min_step<0x112>(v);   // row_shr:2
    v = dpp_min_step<0x114>(v);   // row_shr:4
    v = dpp_min_step<0x118>(v);   // row_shr:8
    v = dpp_min_step<0x142>(v);   // row_bcast:15
    v = dpp_min_step<0x143>(v);   // row_bcast:31
    return __int_as_float(__builtin_amdgcn_readlane(__float_as_int(v), 63));
}

// insert candidate (v,j) into sorted 4-list via select ladder
#define TOP4_INS(v, j)                                                            \
    {                                                                             \
        bool l3 = lex_less(v, j, tv3, tj3);                                       \
        if (l3) {                                                                 \
            bool l2 = lex_less(v, j, tv2, tj2);                                   \
            bool l1 = lex_less(v, j, tv1, tj1);                                   \
            bool l0 = lex_less(v, j, tv0, tj0);                                   \
            tv3 = l2 ? tv2 : v;  tj3 = l2 ? tj2 : j;                              \
            tv2 = l2 ? (l1 ? tv1 : v) : tv2;  tj2 = l2 ? (l1 ? tj1 : j) : tj2;    \
            tv1 = l1 ? (l0 ? tv0 : v) : tv1;  tj1 = l1 ? (l0 ? tj0 : j) : tj1;    \
            tv0 = l0 ? v : tv0;  tj0 = l0 ? j : tj0;                              \
        }                                                                         \
    }

// rebuild sorted top-4 among candidates with (v,j) lex-greater than (lv,lj)
__device__ __forceinline__ void top4_build(const float4* __restrict__ dr4, int lane,
                                           float lv, int lj,
                                           float& tv0, int& tj0, float& tv1, int& tj1,
                                           float& tv2, int& tj2, float& tv3, int& tj3) {
    tv0 = tv1 = tv2 = tv3 = 3e38f;
    tj0 = tj1 = tj2 = tj3 = JSENT;
#pragma unroll
    for (int q = 0; q < 8; ++q) {
        float4 f = dr4[q * 64 + lane];
        float vv[4] = {f.x, f.y, f.z, f.w};
#pragma unroll
        for (int c = 0; c < 4; ++c) {
            int j = (q * 64 + lane) * 4 + c;
            float v = vv[c];
            if (lex_less(lv, lj, v, j)) TOP4_INS(v, j)
        }
    }
}

// shared 20-round selection loop (macro so both kernels reuse it verbatim;
// REBUILD is an expression rebuilding the top-4 with filter (bv,bj)).
// Winners accumulate in per-lane regs -> one coalesced 20-lane store.
#define TOPK_ROUNDS(REBUILD)                                                      \
    int myj = 0;                                                                  \
    for (int t = 0; t < Kn; ++t) {                                                \
        float bv = wave_min64(tv0);                                               \
        unsigned long long tied = __ballot(tv0 == bv);                            \
        int bj;                                                                   \
        if (__popcll(tied) == 1) {                                                \
            int winner = (int)(__ffsll(tied) - 1);                                \
            bj = __builtin_amdgcn_readlane(tj0, winner);                          \
        } else {                                                                  \
            float fv = (tv0 == bv) ? bv : 3e38f;                                  \
            int fj = (tv0 == bv) ? tj0 : JSENT;                                   \
            _Pragma("unroll")                                                     \
            for (int off = 1; off < 64; off <<= 1) {                              \
                float ov = __shfl_xor(fv, off);                                   \
                int oj = __shfl_xor(fj, off);                                     \
                if (lex_less(ov, oj, fv, fj)) { fv = ov; fj = oj; }               \
            }                                                                     \
            bj = fj;                                                              \
        }                                                                         \
        if (lane == t) myj = bj;                                                  \
        if (tv0 == bv && tj0 == bj) {                                             \
            tv0 = tv1; tj0 = tj1; tv1 = tv2; tj1 = tj2;                           \
            tv2 = tv3; tj2 = tj3; tv3 = 3e38f; tj3 = JSENT;                       \
            if (tj0 == JSENT) { REBUILD; }                                        \
        }                                                                         \
    }                                                                             \
    if (lane < Kn) orow[lane] = myj;

__global__ void topk_kernel(const float* __restrict__ dist, int* __restrict__ idxo,
                            int b0, size_t dstride, int rows_per_batch_only) {
    const int w = threadIdx.x >> 6;
    const int lane = threadIdx.x & 63;
    const int lin = blockIdx.x * 4 + w;
    int bz, i;
    if (rows_per_batch_only) { bz = 0; i = lin; }
    else { bz = lin >> 11; i = lin & (Nn - 1); }
    const int b = b0 + bz;
    const float4* dr4 = (const float4*)(dist + (size_t)bz * dstride + (size_t)i * Nn);

    float tv0, tv1, tv2, tv3;
    int tj0, tj1, tj2, tj3;
    top4_build(dr4, lane, -3e38f, -1, tv0, tj0, tv1, tj1, tv2, tj2, tv3, tj3);

    int* orow = idxo + ((size_t)b * Nn + i) * Kn;
    TOPK_ROUNDS(top4_build(dr4, lane, bv, bj, tv0, tj0, tv1, tj1, tv2, tj2, tv3, tj3))
}

// -------- layer-1 fused top-k: dist computed inline from packed (x,xx) float4.
// Candidate mapping j = m*64 + lane -> lane-adjacent candidates are consecutive
// float4s => coalesced 1KB wave loads. FMA chain shape matches gram's CT=3
// path exactly (acc=fmaf(a,b,acc) over increasing c, then xx_i+xx_j-2.f*acc)
// -> same values, same selection.

__device__ __forceinline__ void top4_build_c3(const float4* __restrict__ xpb,
                                              float xi0, float xi1, float xi2, float xxi,
                                              int lane, float lv, int lj,
                                              float& tv0, int& tj0, float& tv1, int& tj1,
                                              float& tv2, int& tj2, float& tv3, int& tj3) {
    tv0 = tv1 = tv2 = tv3 = 3e38f;
    tj0 = tj1 = tj2 = tj3 = JSENT;
#pragma unroll
    for (int m = 0; m < 32; ++m) {
        int j = m * 64 + lane;
        float4 f = xpb[j];
        float acc = 0.f;
        acc = fmaf(xi0, f.x, acc);
        acc = fmaf(xi1, f.y, acc);
        acc = fmaf(xi2, f.z, acc);
        float v = xxi + f.w - 2.f * acc;
        if (lex_less(lv, lj, v, j)) TOP4_INS(v, j)
    }
}

__global__ void topk_c3_kernel(const float4* __restrict__ xp, int* __restrict__ idxo,
                               int b0, int rows_per_batch_only) {
    const int w = threadIdx.x >> 6;
    const int lane = threadIdx.x & 63;
    const int lin = blockIdx.x * 4 + w;
    int bz, i;
    if (rows_per_batch_only) { bz = 0; i = lin; }
    else { bz = lin >> 11; i = lin & (Nn - 1); }
    const int b = b0 + bz;
    const float4* xpb = xp + (size_t)b * Nn;
    const float4 fi = xpb[i];
    const float xi0 = fi.x, xi1 = fi.y, xi2 = fi.z, xxi = fi.w;

    float tv0, tv1, tv2, tv3;
    int tj0, tj1, tj2, tj3;
    top4_build_c3(xpb, xi0, xi1, xi2, xxi, lane, -3e38f, -1,
                  tv0, tj0, tv1, tj1, tv2, tj2, tv3, tj3);

    int* orow = idxo + ((size_t)b * Nn + i) * Kn;
    TOPK_ROUNDS(top4_build_c3(xpb, xi0, xi1, xi2, xxi, lane, bv, bj, \
                              tv0, tj0, tv1, tj1, tv2, tj2, tv3, tj3))
}

// -------------------- gather edges, max/min over k + BN partial sums
// float4 per thread; each gathered row = one coalesced wave transaction.

template<int O>
__global__ void edge_stats_kernel(const float* __restrict__ z1, const float* __restrict__ z2,
                                  const int* __restrict__ idx,
                                  float* __restrict__ vmax, float* __restrict__ vmin,
                                  float* __restrict__ ssum, float* __restrict__ ssq) {
    constexpr int TPP = O / 4;           // threads per point
    constexpr int PPB = 256 / TPP;       // points per block
    const int p0 = blockIdx.x * PPB;
    const int tid = threadIdx.x;
    const int q = tid % TPP;
    const int p = tid / TPP;
    const int oo = q * 4;
    __shared__ int jl[PPB][Kn];
    for (int e = tid; e < PPB * Kn; e += 256)
        jl[e / Kn][e % Kn] = idx[(size_t)(p0 + e / Kn) * Kn + (e % Kn)];
    __syncthreads();
    const int bi = p0 + p;
    const int b = bi >> 11;
    const float4 zi1 = *(const float4*)(z1 + (size_t)bi * O + oo);
    const float4 zi2 = *(const float4*)(z2 + (size_t)bi * O + oo);
    float ax = zi2.x - zi1.x, ay = zi2.y - zi1.y, az = zi2.z - zi1.z, aw = zi2.w - zi1.w;
    float mxx = -3e38f, mxy = -3e38f, mxz = -3e38f, mxw = -3e38f;
    float mnx = 3e38f, mny = 3e38f, mnz = 3e38f, mnw = 3e38f;
    float sx = 0.f, sy = 0.f, sz = 0.f, sw = 0.f;
    float qx = 0.f, qy = 0.f, qz = 0.f, qw = 0.f;
    const float* zbase = z1 + ((size_t)b * Nn) * O + oo;
#pragma unroll
    for (int kk = 0; kk < Kn; ++kk) {
        int j = jl[p][kk];
        float4 v = *(const float4*)(zbase + (size_t)j * O);
        v.x += ax; v.y += ay; v.z += az; v.w += aw;
        mxx = fmaxf(mxx, v.x); mxy = fmaxf(mxy, v.y); mxz = fmaxf(mxz, v.z); mxw = fmaxf(mxw, v.w);
        mnx = fminf(mnx, v.x); mny = fminf(mny, v.y); mnz = fminf(mnz, v.z); mnw = fminf(mnw, v.w);
        sx += v.x; sy += v.y; sz += v.z; sw += v.w;
        qx = fmaf(v.x, v.x, qx); qy = fmaf(v.y, v.y, qy);
        qz = fmaf(v.z, v.z, qz); qw = fmaf(v.w, v.w, qw);
    }
    float4 mx4 = make_float4(mxx, mxy, mxz, mxw);
    float4 mn4 = make_float4(mnx, mny, mnz, mnw);
    *(float4*)(vmax + (size_t)bi * O + oo) = mx4;
    *(float4*)(vmin + (size_t)bi * O + oo) = mn4;
    __shared__ float4 ssm[256], sqq[256];
    ssm[tid] = make_float4(sx, sy, sz, sw);
    sqq[tid] = make_float4(qx, qy, qz, qw);
    __syncthreads();
    if (p == 0) {
#pragma unroll 4
        for (int pp = 1; pp < PPB; ++pp) {
            float4 s4 = ssm[pp * TPP + q];
            float4 q4 = sqq[pp * TPP + q];
            sx += s4.x; sy += s4.y; sz += s4.z; sw += s4.w;
            qx += q4.x; qy += q4.y; qz += q4.z; qw += q4.w;
        }
        int slot = blockIdx.x & 63;
        atomicAdd(&ssum[slot * O + oo + 0], sx);
        atomicAdd(&ssum[slot * O + oo + 1], sy);
        atomicAdd(&ssum[slot * O + oo + 2], sz);
        atomicAdd(&ssum[slot * O + oo + 3], sw);
        atomicAdd(&ssq[slot * O + oo + 0], qx);
        atomicAdd(&ssq[slot * O + oo + 1], qy);
        atomicAdd(&ssq[slot * O + oo + 2], qz);
        atomicAdd(&ssq[slot * O + oo + 3], qw);
    }
}

// ---------------- BN finalize (in-block) + apply + relu + pooling partials
// Each block recomputes scale/shift for its O columns from the 64-slot
// partials (same summation order as the old bn_finalize -> bit-identical).

template<int O>
__global__ void apply_pool_kernel(const float* __restrict__ vmax, const float* __restrict__ vmin,
                                  const float* __restrict__ ssum, const float* __restrict__ ssq,
                                  const float* __restrict__ gamma, const float* __restrict__ beta,
                                  float* __restrict__ xout,
                                  float* __restrict__ pmax, float* __restrict__ psum, int obase) {
    constexpr int TPP = O / 4;
    constexpr int PP2 = 256 / TPP;      // points concurrent
    constexpr int S = 128 / PP2;        // iterations
    const int chunk = blockIdx.x;
    const int b = blockIdx.y;
    const int tid = threadIdx.x;
    const int q = tid % TPP;
    const int g = tid / TPP;
    const int oo = q * 4;
    __shared__ __align__(16) float lsc[O], lsh[O];
    for (int o = tid; o < O; o += 256) {
        float s = 0.f, qq = 0.f;
        for (int sl = 0; sl < 64; ++sl) { s += ssum[sl * O + o]; qq += ssq[sl * O + o]; }
        const float cnt = (float)Bb * (float)Nn * (float)Kn;
        float mu = s / cnt;
        float var = qq / cnt - mu * mu;
        float sc_ = gamma[o] / sqrtf(var + EPSV);
        lsc[o] = sc_;
        lsh[o] = beta[o] - mu * sc_;
    }
    __syncthreads();
    const float4 sc = *(const float4*)(lsc + oo);
    const float4 sh = *(const float4*)(lsh + oo);
    float pmx = -3e38f, pmy = -3e38f, pmz = -3e38f, pmw = -3e38f;
    float psx = 0.f, psy = 0.f, psz = 0.f, psw = 0.f;
    const int n0 = chunk * 128;
    for (int s = 0; s < S; ++s) {
        int n = n0 + g + s * PP2;
        size_t ix = ((size_t)b * Nn + n) * O + oo;
        float4 vx = *(const float4*)(vmax + ix);
        float4 vn = *(const float4*)(vmin + ix);
        float4 r;
        r.x = fmaxf(fmaf(sc.x >= 0.f ? vx.x : vn.x, sc.x, sh.x), 0.f);
        r.y = fmaxf(fmaf(sc.y >= 0.f ? vx.y : vn.y, sc.y, sh.y), 0.f);
        r.z = fmaxf(fmaf(sc.z >= 0.f ? vx.z : vn.z, sc.z, sh.z), 0.f);
        r.w = fmaxf(fmaf(sc.w >= 0.f ? vx.w : vn.w, sc.w, sh.w), 0.f);
        *(float4*)(xout + ix) = r;
        pmx = fmaxf(pmx, r.x); pmy = fmaxf(pmy, r.y);
        pmz = fmaxf(pmz, r.z); pmw = fmaxf(pmw, r.w);
        psx += r.x; psy += r.y; psz += r.z; psw += r.w;
    }
    __shared__ float4 sm[256], ss2[256];
    sm[tid] = make_float4(pmx, pmy, pmz, pmw);
    ss2[tid] = make_float4(psx, psy, psz, psw);
    __syncthreads();
    if (g == 0) {
#pragma unroll 4
        for (int gg = 1; gg < PP2; ++gg) {
            float4 m4 = sm[gg * TPP + q];
            float4 s4 = ss2[gg * TPP + q];
            pmx = fmaxf(pmx, m4.x); pmy = fmaxf(pmy, m4.y);
            pmz = fmaxf(pmz, m4.z); pmw = fmaxf(pmw, m4.w);
            psx += s4.x; psy += s4.y; psz += s4.z; psw += s4.w;
        }
        size_t pb = ((size_t)b * 16 + chunk) * 512 + obase + oo;
        *(float4*)(pmax + pb) = make_float4(pmx, pmy, pmz, pmw);
        *(float4*)(psum + pb) = make_float4(psx, psy, psz, psw);
    }
}

// ------------------------------------------- MLP head (fused global pooling)

__global__ void head_kernel(const float* __restrict__ pmax, const float* __restrict__ psum,
                            const float* __restrict__ fct1, const float* __restrict__ fc1b,
                            const float* __restrict__ ln1g, const float* __restrict__ ln1b,
                            const float* __restrict__ fct2, const float* __restrict__ fc2b,
                            const float* __restrict__ ln2g, const float* __restrict__ ln2b,
                            float* __restrict__ out) {
    const int b = blockIdx.x;
    const int tid = threadIdx.x;
    __shared__ float gx[1024];
    __shared__ float hh[512];
    __shared__ float red[256];
    for (int e = tid; e < 512; e += 256) {      // fused pool_finalize
        float mx = -3e38f, s = 0.f;
        for (int ch = 0; ch < 16; ++ch) {
            size_t p = ((size_t)b * 16 + ch) * 512 + e;
            mx = fmaxf(mx, pmax[p]);
            s += psum[p];
        }
        gx[e] = mx;
        gx[512 + e] = s * (1.f / (float)Nn);
    }
    __syncthreads();
    float h0 = fc1b[tid], h1 = fc1b[tid + 256];
    for (int c = 0; c < 1024; ++c) {
        float gc = gx[c];
        h0 = fmaf(gc, fct1[(size_t)c * 512 + tid], h0);
        h1 = fmaf(gc, fct1[(size_t)c * 512 + tid + 256], h1);
    }
    red[tid] = h0 + h1;
    __syncthreads();
    for (int st = 128; st > 0; st >>= 1) { if (tid < st) red[tid] += red[tid + st]; __syncthreads(); }
    float mu = red[0] * (1.f / 512.f);
    __syncthreads();
    float d0 = h0 - mu, d1 = h1 - mu;
    red[tid] = d0 * d0 + d1 * d1;
    __syncthreads();
    for (int st = 128; st > 0; st >>= 1) { if (tid < st) red[tid] += red[tid + st]; __syncthreads(); }
    float rs = 1.f / sqrtf(red[0] * (1.f / 512.f) + EPSV);
    __syncthreads();
    hh[tid]       = fmaxf(d0 * rs * ln1g[tid] + ln1b[tid], 0.f);
    hh[tid + 256] = fmaxf(d1 * rs * ln1g[tid + 256] + ln1b[tid + 256], 0.f);
    __syncthreads();
    float z = fc2b[tid];
    for (int c = 0; c < 512; ++c) z = fmaf(hh[c], fct2[(size_t)c * 256 + tid], z);
    red[tid] = z;
    __syncthreads();
    for (int st = 128; st > 0; st >>= 1) { if (tid < st) red[tid] += red[tid + st]; __syncthreads(); }
    float mu2 = red[0] * (1.f / 256.f);
    __syncthreads();
    float dz = z - mu2;
    red[tid] = dz * dz;
    __syncthreads();
    for (int st = 128; st > 0; st >>= 1) { if (tid < st) red[tid] += red[tid + st]; __syncthreads(); }
    float rs2 = 1.f / sqrtf(red[0] * (1.f / 256.f) + EPSV);
    out[b * 256 + tid] = dz * rs2 * ln2g[tid] + ln2b[tid];
}

// --------------------------------------------------------------- layer driver

template<int C, int O>
static void run_layer(const float* x, const float* gamma, const float* beta,
                      float* xout, float* DIST, float* XX, float4* XP, int* IDX,
                      float* Z1, float* Z2,
                      float* VMX, float* VMN, float* SSUM, float* SSQ,
                      const float* WT, float* PMAX, float* PSUM, int obase, bool big,
                      hipStream_t stream) {
    prep_kernel<C, O><<<1216, 256, 0, stream>>>(x, WT, Z1, Z2, XX, XP, SSUM);
    if constexpr (C == 3) {
        // layer 1: packed (x,xx) is L1-resident (32 KB/batch) -> fused
        // inline-dist top-k, no gram dispatch, no DIST write+read.
        if (big) {
            topk_c3_kernel<<<Bb * Nn / 4, 256, 0, stream>>>(XP, IDX, 0, 0);
        } else {
            for (int b = 0; b < Bb; ++b)
                topk_c3_kernel<<<Nn / 4, 256, 0, stream>>>(XP, IDX, b, 1);
        }
    } else {
        if (big) {
            gram_dist_kernel<C><<<dim3(136, 1, Bb), 256, 0, stream>>>(x, XX, DIST, 0, (size_t)Nn * Nn);
            topk_kernel<<<Bb * Nn / 4, 256, 0, stream>>>(DIST, IDX, 0, (size_t)Nn * Nn, 0);
        } else {
            for (int b = 0; b < Bb; ++b) {
                gram_dist_kernel<C><<<dim3(136, 1, 1), 256, 0, stream>>>(x, XX, DIST, b, 0);
                topk_kernel<<<Nn / 4, 256, 0, stream>>>(DIST, IDX, b, 0, 1);
            }
        }
    }
    edge_stats_kernel<O><<<Bb * Nn / (1024 / O), 256, 0, stream>>>(Z1, Z2, IDX, VMX, VMN, SSUM, SSQ);
    apply_pool_kernel<O><<<dim3(16, 8), 256, 0, stream>>>(VMX, VMN, SSUM, SSQ, gamma, beta,
                                                          xout, PMAX, PSUM, obase);
}

extern "C" void kernel_launch(void* const* d_in, const int* in_sizes, int n_in,
                              void* d_out, int out_size, void* d_ws, size_t ws_size,
                              hipStream_t stream) {
    const float* points = (const float*)d_in[0];
    const float* W1 = (const float*)d_in[1];
    const float* g1 = (const float*)d_in[2];
    const float* b1 = (const float*)d_in[3];
    const float* W2 = (const float*)d_in[4];
    const float* g2 = (const float*)d_in[5];
    const float* b2 = (const float*)d_in[6];
    const float* W3 = (const float*)d_in[7];
    const float* g3 = (const float*)d_in[8];
    const float* b3 = (const float*)d_in[9];
    const float* W4 = (const float*)d_in[10];
    const float* g4 = (const float*)d_in[11];
    const float* b4 = (const float*)d_in[12];
    const float* fc1_w = (const float*)d_in[13];
    const float* fc1_b = (const float*)d_in[14];
    const float* ln1g = (const float*)d_in[15];
    const float* ln1b = (const float*)d_in[16];
    const float* fc2_w = (const float*)d_in[17];
    const float* fc2_b = (const float*)d_in[18];
    const float* ln2g = (const float*)d_in[19];
    const float* ln2b = (const float*)d_in[20];

    float* ws = (float*)d_ws;
    const size_t BN = (size_t)Bb * Nn;
    const bool big = ws_size >= (size_t)59826688 * 4;

    size_t off = 0;
    auto take = [&](size_t n) { size_t o = off; off += n; return o; };
    float* DIST = ws + take(big ? (size_t)Bb * Nn * Nn : (size_t)Nn * Nn);
    float* XX   = ws + take(BN);
    float4* XP  = (float4*)(ws + take(BN * 4));
    int*   IDX  = (int*)(ws + take(BN * Kn));
    float* Z1   = ws + take(BN * 256);
    float* Z2   = ws + take(BN * 256);
    float* VMX  = ws + take(BN * 256);
    float* VMN  = ws + take(BN * 256);
    float* SSUM = ws + take(64 * 256);
    float* SSQ  = ws + take(64 * 256);
    float* WT1  = ws + take(384);
    float* WT2  = ws + take(8192);
    float* WT3  = ws + take(16384);
    float* WT4  = ws + take(65536);
    float* FCT1 = ws + take(524288);
    float* FCT2 = ws + take(131072);
    float* X1   = ws + take(BN * 64);
    float* X2   = ws + take(BN * 64);
    float* X3   = ws + take(BN * 128);
    float* X4   = ws + take(BN * 256);
    float* PMAX = ws + take((size_t)Bb * 16 * 512);
    float* PSUM = ws + take((size_t)Bb * 16 * 512);

    // All weight transposes in one launch (independent of layer outputs).
    TransJobs tj;
    tj.in[0] = W1;    tj.out[0] = WT1;  tj.R[0] = 64;  tj.Cc[0] = 6;
    tj.in[1] = W2;    tj.out[1] = WT2;  tj.R[1] = 64;  tj.Cc[1] = 128;
    tj.in[2] = W3;    tj.out[2] = WT3;  tj.R[2] = 128; tj.Cc[2] = 128;
    tj.in[3] = W4;    tj.out[3] = WT4;  tj.R[3] = 256; tj.Cc[3] = 256;
    tj.in[4] = fc1_w; tj.out[4] = FCT1; tj.R[4] = 512; tj.Cc[4] = 1024;
    tj.in[5] = fc2_w; tj.out[5] = FCT2; tj.R[5] = 256; tj.Cc[5] = 512;
    transpose_all_kernel<<<dim3(2048, 6), 256, 0, stream>>>(tj);

    run_layer<3, 64>(points, g1, b1, X1, DIST, XX, XP, IDX, Z1, Z2, VMX, VMN, SSUM, SSQ, WT1, PMAX, PSUM, 0, big, stream);
    run_layer<64, 64>(X1, g2, b2, X2, DIST, XX, XP, IDX, Z1, Z2, VMX, VMN, SSUM, SSQ, WT2, PMAX, PSUM, 64, big, stream);
    run_layer<64, 128>(X2, g3, b3, X3, DIST, XX, XP, IDX, Z1, Z2, VMX, VMN, SSUM, SSQ, WT3, PMAX, PSUM, 128, big, stream);
    run_layer<128, 256>(X3, g4, b4, X4, DIST, XX, XP, IDX, Z1, Z2, VMX, VMN, SSUM, SSQ, WT4, PMAX, PSUM, 256, big, stream);

    head_kernel<<<Bb, 256, 0, stream>>>(PMAX, PSUM, FCT1, fc1_b, ln1g, ln1b, FCT2, fc2_b,
                                        ln2g, ln2b, (float*)d_out);
}